// Round 1
// baseline (1378.494 us; speedup 1.0000x reference)
//
#include <hip/hip_runtime.h>
#include <hip/hip_bf16.h>
#include <math.h>

#define B_   16
#define L_   1024
#define DM_  128
#define DK_  32
#define DV_  32
#define NU_  35
#define SCALE_ 0.17677669529663687f   // 1/sqrt(32)

// ---------------------------------------------------------------------------
// MT19937 -> PROB_IDX (35840 draws of genrand_int32() & 1023, seed 0)
// ---------------------------------------------------------------------------
__global__ void mt_kernel(int* __restrict__ pidx) {
  __shared__ unsigned int mt[624];
  int tid = threadIdx.x;
  if (tid == 0) {
    unsigned int s = 0u;
    for (int i = 0; i < 624; ++i) {
      mt[i] = s;
      s = 1812433253u * (s ^ (s >> 30)) + (unsigned)(i + 1);
    }
  }
  __syncthreads();
  for (int blk = 0; blk < 58; ++blk) {
    unsigned int v = 0; bool act = tid < 227;
    // phase 1: kk in [0,227)
    if (act) {
      unsigned int y = (mt[tid] & 0x80000000u) | (mt[tid + 1] & 0x7fffffffu);
      v = mt[tid + 397] ^ (y >> 1) ^ ((y & 1u) ? 0x9908b0dfu : 0u);
    }
    __syncthreads();
    if (act) mt[tid] = v;
    __syncthreads();
    // phase 2: kk in [227,454)
    if (act) {
      int kk = 227 + tid;
      unsigned int y = (mt[kk] & 0x80000000u) | (mt[kk + 1] & 0x7fffffffu);
      v = mt[kk - 227] ^ (y >> 1) ^ ((y & 1u) ? 0x9908b0dfu : 0u);
    }
    __syncthreads();
    if (act) mt[227 + tid] = v;
    __syncthreads();
    // phase 3: kk in [454,623)
    bool act3 = tid < 169;
    if (act3) {
      int kk = 454 + tid;
      unsigned int y = (mt[kk] & 0x80000000u) | (mt[kk + 1] & 0x7fffffffu);
      v = mt[kk - 227] ^ (y >> 1) ^ ((y & 1u) ? 0x9908b0dfu : 0u);
    }
    __syncthreads();
    if (act3) mt[454 + tid] = v;
    __syncthreads();
    if (tid == 0) {
      unsigned int y = (mt[623] & 0x80000000u) | (mt[0] & 0x7fffffffu);
      mt[623] = mt[396] ^ (y >> 1) ^ ((y & 1u) ? 0x9908b0dfu : 0u);
    }
    __syncthreads();
    for (int i = tid; i < 624; i += 256) {
      int g = blk * 624 + i;
      if (g < 35840) {
        unsigned int y = mt[i];
        y ^= y >> 11;
        y ^= (y << 7) & 0x9d2c5680u;
        y ^= (y << 15) & 0xefc60000u;
        y ^= y >> 18;
        pidx[g] = (int)(y & 1023u);
      }
    }
    __syncthreads();
  }
}

// ---------------------------------------------------------------------------
// conv (kernel=3, left pad 2) : out[b,c,t] = bias[c] + sum_{d,k} w[c,d,k] x[b,t-2+k,d]
// out layout (B,64,L) flat -> consumed as Q[b,l,h,dd] = out[b, l*64+h*32+dd]
// ---------------------------------------------------------------------------
__global__ void conv3_kernel(const float* __restrict__ x, const float* __restrict__ w,
                             const float* __restrict__ bias, float* __restrict__ out) {
  __shared__ float xs[34][128];
  __shared__ float ws[64][13];
  int b = blockIdx.y, t0 = blockIdx.x * 32;
  int tid = threadIdx.x;
  for (int i = tid; i < 34 * 128; i += 256) {
    int r = i >> 7, d = i & 127;
    int t = t0 - 2 + r;
    xs[r][d] = (t >= 0) ? x[(size_t)b * 131072 + (size_t)t * 128 + d] : 0.0f;
  }
  int c = tid & 63, tt0 = (tid >> 6) * 8;
  float acc[8];
  float bvv = bias[c];
  #pragma unroll
  for (int j = 0; j < 8; ++j) acc[j] = bvv;
  for (int d0 = 0; d0 < 128; d0 += 4) {
    __syncthreads();
    for (int i = tid; i < 64 * 12; i += 256) {
      int cc = i / 12, j = i % 12;
      ws[cc][j] = w[cc * 384 + d0 * 3 + j];
    }
    __syncthreads();
    float4 xr[10];
    #pragma unroll
    for (int r = 0; r < 10; ++r) xr[r] = *(const float4*)&xs[tt0 + r][d0];
    float wreg[12];
    #pragma unroll
    for (int j = 0; j < 12; ++j) wreg[j] = ws[c][j];
    #pragma unroll
    for (int j = 0; j < 8; ++j) {
      float a = acc[j];
      #pragma unroll
      for (int k = 0; k < 3; ++k) {
        float4 xv = xr[j + k];
        a = fmaf(wreg[0 + k], xv.x, a);
        a = fmaf(wreg[3 + k], xv.y, a);
        a = fmaf(wreg[6 + k], xv.z, a);
        a = fmaf(wreg[9 + k], xv.w, a);
      }
      acc[j] = a;
    }
  }
  float* op = out + (size_t)b * 65536 + (size_t)c * 1024 + t0 + tt0;
  #pragma unroll
  for (int j = 0; j < 8; ++j) op[j] = acc[j];
}

// conv kernel=1
__global__ void conv1_kernel(const float* __restrict__ x, const float* __restrict__ w,
                             const float* __restrict__ bias, float* __restrict__ out) {
  __shared__ float xs[32][128];
  __shared__ float ws[64][129];
  int b = blockIdx.y, t0 = blockIdx.x * 32;
  int tid = threadIdx.x;
  for (int i = tid; i < 32 * 128; i += 256) {
    int r = i >> 7, d = i & 127;
    xs[r][d] = x[(size_t)b * 131072 + (size_t)(t0 + r) * 128 + d];
  }
  for (int i = tid; i < 64 * 128; i += 256) {
    ws[i >> 7][i & 127] = w[i];
  }
  __syncthreads();
  int c = tid & 63, tt0 = (tid >> 6) * 8;
  float acc[8];
  float bvv = bias[c];
  #pragma unroll
  for (int j = 0; j < 8; ++j) acc[j] = bvv;
  for (int d0 = 0; d0 < 128; d0 += 4) {
    float w0 = ws[c][d0], w1 = ws[c][d0 + 1], w2 = ws[c][d0 + 2], w3 = ws[c][d0 + 3];
    #pragma unroll
    for (int j = 0; j < 8; ++j) {
      float4 xv = *(const float4*)&xs[tt0 + j][d0];
      float a = acc[j];
      a = fmaf(w0, xv.x, a);
      a = fmaf(w1, xv.y, a);
      a = fmaf(w2, xv.z, a);
      a = fmaf(w3, xv.w, a);
      acc[j] = a;
    }
  }
  float* op = out + (size_t)b * 65536 + (size_t)c * 1024 + t0 + tt0;
  #pragma unroll
  for (int j = 0; j < 8; ++j) op[j] = acc[j];
}

// ---------------------------------------------------------------------------
// full attention, split-K partials (lane-per-query, K/V tile in LDS)
// ---------------------------------------------------------------------------
__global__ void attn_full_part(const float* __restrict__ Q, const float* __restrict__ K,
                               const float* __restrict__ V, float* __restrict__ part) {
  __shared__ float Ks[256][32];
  __shared__ float Vs[256][32];
  int bh = blockIdx.z, b = bh >> 1, h = bh & 1;
  int l = blockIdx.x * 256 + threadIdx.x;
  int s0 = blockIdx.y * 256;
  const float* Kb = K + (size_t)b * 65536 + h * 32;
  const float* Vb = V + (size_t)b * 65536 + h * 32;
  for (int i = threadIdx.x; i < 2048; i += 256) {
    int r = i >> 3, d4 = i & 7;
    ((float4*)&Ks[r][0])[d4] = *(const float4*)(Kb + (size_t)(s0 + r) * 64 + d4 * 4);
    ((float4*)&Vs[r][0])[d4] = *(const float4*)(Vb + (size_t)(s0 + r) * 64 + d4 * 4);
  }
  __syncthreads();
  const float* Qb = Q + (size_t)b * 65536 + h * 32 + (size_t)l * 64;
  float q[32];
  #pragma unroll
  for (int i = 0; i < 8; ++i) {
    float4 v4 = ((const float4*)Qb)[i];
    q[4*i] = v4.x; q[4*i+1] = v4.y; q[4*i+2] = v4.z; q[4*i+3] = v4.w;
  }
  float o[32];
  #pragma unroll
  for (int d = 0; d < 32; ++d) o[d] = 0.0f;
  float m = -1e30f, ssum = 0.0f;
  for (int s = 0; s < 256; ++s) {
    float a0 = 0, a1 = 0, a2 = 0, a3 = 0;
    const float4* kp = (const float4*)&Ks[s][0];
    #pragma unroll
    for (int i = 0; i < 8; ++i) {
      float4 kv = kp[i];
      a0 = fmaf(q[4*i], kv.x, a0);
      a1 = fmaf(q[4*i+1], kv.y, a1);
      a2 = fmaf(q[4*i+2], kv.z, a2);
      a3 = fmaf(q[4*i+3], kv.w, a3);
    }
    float sv = ((a0 + a1) + (a2 + a3)) * SCALE_;
    float mn = fmaxf(m, sv);
    float rr = __expf(m - mn);
    float p  = __expf(sv - mn);
    ssum = ssum * rr + p;
    m = mn;
    const float4* vp = (const float4*)&Vs[s][0];
    #pragma unroll
    for (int i = 0; i < 8; ++i) {
      float4 vv = vp[i];
      o[4*i]   = fmaf(o[4*i],   rr, p * vv.x);
      o[4*i+1] = fmaf(o[4*i+1], rr, p * vv.y);
      o[4*i+2] = fmaf(o[4*i+2], rr, p * vv.z);
      o[4*i+3] = fmaf(o[4*i+3], rr, p * vv.w);
    }
  }
  float* pp = part + (((size_t)bh * 4 + blockIdx.y) * 1024 + l) * 34;
  #pragma unroll
  for (int d = 0; d < 32; ++d) pp[d] = o[d];
  pp[32] = m; pp[33] = ssum;
}

__global__ void attn_full_comb(const float* __restrict__ part, float* __restrict__ cbuf) {
  int idx = blockIdx.x * 256 + threadIdx.x;
  int bh = idx >> 10, l = idx & 1023;
  int b = bh >> 1, h = bh & 1;
  float m = -1e30f;
  for (int j = 0; j < 4; ++j)
    m = fmaxf(m, part[(((size_t)bh * 4 + j) * 1024 + l) * 34 + 32]);
  float S = 0.0f;
  float o[32];
  #pragma unroll
  for (int d = 0; d < 32; ++d) o[d] = 0.0f;
  for (int j = 0; j < 4; ++j) {
    const float* pp = part + (((size_t)bh * 4 + j) * 1024 + l) * 34;
    float w = __expf(pp[32] - m);
    S += pp[33] * w;
    #pragma unroll
    for (int d = 0; d < 32; ++d) o[d] += pp[d] * w;
  }
  float inv = 1.0f / S;
  float* cc = cbuf + ((size_t)b * 1024 + l) * 352 + 0 + h * 32;
  #pragma unroll
  for (int d = 0; d < 32; ++d) cc[d] = o[d] * inv;
}

// ---------------------------------------------------------------------------
// log-sparse attention: s = l, l-1, l-2, l-4, ..., l-512 (valid only)
// ---------------------------------------------------------------------------
__global__ void attn_log_kernel(const float* __restrict__ Q, const float* __restrict__ K,
                                const float* __restrict__ V, float* __restrict__ cbuf) {
  int idx = blockIdx.x * 256 + threadIdx.x;
  int bh = idx >> 10, l = idx & 1023;
  int b = bh >> 1, h = bh & 1;
  const float* Qb = Q + (size_t)b * 65536 + h * 32;
  const float* Kb = K + (size_t)b * 65536 + h * 32;
  const float* Vb = V + (size_t)b * 65536 + h * 32;
  float q[32];
  #pragma unroll
  for (int i = 0; i < 8; ++i) {
    float4 v4 = ((const float4*)(Qb + (size_t)l * 64))[i];
    q[4*i] = v4.x; q[4*i+1] = v4.y; q[4*i+2] = v4.z; q[4*i+3] = v4.w;
  }
  float sc[11];
  float m = -1e30f;
  #pragma unroll
  for (int j = 0; j < 11; ++j) {
    int off = (j == 0) ? 0 : (1 << (j - 1));
    float sv = -1e30f;
    if (off <= l) {
      const float4* kp = (const float4*)(Kb + (size_t)(l - off) * 64);
      float a0 = 0, a1 = 0, a2 = 0, a3 = 0;
      #pragma unroll
      for (int i = 0; i < 8; ++i) {
        float4 kv = kp[i];
        a0 = fmaf(q[4*i], kv.x, a0);
        a1 = fmaf(q[4*i+1], kv.y, a1);
        a2 = fmaf(q[4*i+2], kv.z, a2);
        a3 = fmaf(q[4*i+3], kv.w, a3);
      }
      sv = ((a0 + a1) + (a2 + a3)) * SCALE_;
    }
    sc[j] = sv;
    m = fmaxf(m, sv);
  }
  float o[32];
  #pragma unroll
  for (int d = 0; d < 32; ++d) o[d] = 0.0f;
  float ssum = 0.0f;
  #pragma unroll
  for (int j = 0; j < 11; ++j) {
    int off = (j == 0) ? 0 : (1 << (j - 1));
    if (off <= l) {
      float p = __expf(sc[j] - m);
      ssum += p;
      const float4* vp = (const float4*)(Vb + (size_t)(l - off) * 64);
      #pragma unroll
      for (int i = 0; i < 8; ++i) {
        float4 vv = vp[i];
        o[4*i]   = fmaf(p, vv.x, o[4*i]);
        o[4*i+1] = fmaf(p, vv.y, o[4*i+1]);
        o[4*i+2] = fmaf(p, vv.z, o[4*i+2]);
        o[4*i+3] = fmaf(p, vv.w, o[4*i+3]);
      }
    }
  }
  float inv = 1.0f / ssum;
  float* cc = cbuf + ((size_t)b * 1024 + l) * 352 + 64 + h * 32;
  #pragma unroll
  for (int d = 0; d < 32; ++d) cc[d] = o[d] * inv;
}

// local-window attention: s in [l-31, l]
__global__ void attn_loc_kernel(const float* __restrict__ Q, const float* __restrict__ K,
                                const float* __restrict__ V, float* __restrict__ cbuf) {
  int idx = blockIdx.x * 256 + threadIdx.x;
  int bh = idx >> 10, l = idx & 1023;
  int b = bh >> 1, h = bh & 1;
  const float* Qb = Q + (size_t)b * 65536 + h * 32;
  const float* Kb = K + (size_t)b * 65536 + h * 32;
  const float* Vb = V + (size_t)b * 65536 + h * 32;
  float q[32];
  #pragma unroll
  for (int i = 0; i < 8; ++i) {
    float4 v4 = ((const float4*)(Qb + (size_t)l * 64))[i];
    q[4*i] = v4.x; q[4*i+1] = v4.y; q[4*i+2] = v4.z; q[4*i+3] = v4.w;
  }
  float sc[32];
  float m = -1e30f;
  #pragma unroll
  for (int j = 0; j < 32; ++j) {
    int s = l - 31 + j;
    float sv = -1e30f;
    if (s >= 0) {
      const float4* kp = (const float4*)(Kb + (size_t)s * 64);
      float a0 = 0, a1 = 0, a2 = 0, a3 = 0;
      #pragma unroll
      for (int i = 0; i < 8; ++i) {
        float4 kv = kp[i];
        a0 = fmaf(q[4*i], kv.x, a0);
        a1 = fmaf(q[4*i+1], kv.y, a1);
        a2 = fmaf(q[4*i+2], kv.z, a2);
        a3 = fmaf(q[4*i+3], kv.w, a3);
      }
      sv = ((a0 + a1) + (a2 + a3)) * SCALE_;
    }
    sc[j] = sv;
    m = fmaxf(m, sv);
  }
  float o[32];
  #pragma unroll
  for (int d = 0; d < 32; ++d) o[d] = 0.0f;
  float ssum = 0.0f;
  #pragma unroll
  for (int j = 0; j < 32; ++j) {
    int s = l - 31 + j;
    if (s >= 0) {
      float p = __expf(sc[j] - m);
      ssum += p;
      const float4* vp = (const float4*)(Vb + (size_t)s * 64);
      #pragma unroll
      for (int i = 0; i < 8; ++i) {
        float4 vv = vp[i];
        o[4*i]   = fmaf(p, vv.x, o[4*i]);
        o[4*i+1] = fmaf(p, vv.y, o[4*i+1]);
        o[4*i+2] = fmaf(p, vv.z, o[4*i+2]);
        o[4*i+3] = fmaf(p, vv.w, o[4*i+3]);
      }
    }
  }
  float inv = 1.0f / ssum;
  float* cc = cbuf + ((size_t)b * 1024 + l) * 352 + 128 + h * 32;
  #pragma unroll
  for (int d = 0; d < 32; ++d) cc[d] = o[d] * inv;
}

// ---------------------------------------------------------------------------
// prob-sparse attention
// ---------------------------------------------------------------------------
__global__ void prob_m_kernel(const float* __restrict__ Q, const float* __restrict__ K,
                              const int* __restrict__ pidx, float* __restrict__ Mbuf) {
  int idx = blockIdx.x * 256 + threadIdx.x;
  int bh = idx >> 10, l = idx & 1023;
  int b = bh >> 1, h = bh & 1;
  const float* Qb = Q + (size_t)b * 65536 + h * 32;
  const float* Kb = K + (size_t)b * 65536 + h * 32;
  float q[32];
  #pragma unroll
  for (int i = 0; i < 8; ++i) {
    float4 v4 = ((const float4*)(Qb + (size_t)l * 64))[i];
    q[4*i] = v4.x; q[4*i+1] = v4.y; q[4*i+2] = v4.z; q[4*i+3] = v4.w;
  }
  float mx = -1e30f, sm = 0.0f;
  for (int u = 0; u < 35; ++u) {
    int ki = pidx[l * 35 + u];
    const float4* kp = (const float4*)(Kb + (size_t)ki * 64);
    float a0 = 0, a1 = 0, a2 = 0, a3 = 0;
    #pragma unroll
    for (int i = 0; i < 8; ++i) {
      float4 kv = kp[i];
      a0 = fmaf(q[4*i], kv.x, a0);
      a1 = fmaf(q[4*i+1], kv.y, a1);
      a2 = fmaf(q[4*i+2], kv.z, a2);
      a3 = fmaf(q[4*i+3], kv.w, a3);
    }
    float s = (a0 + a1) + (a2 + a3);   // no SCALE here (matches reference qk)
    mx = fmaxf(mx, s);
    sm += s;
  }
  Mbuf[(size_t)bh * 1024 + l] = mx - sm * (1.0f / 1024.0f);
}

__global__ void top35_kernel(const float* __restrict__ Mbuf, int* __restrict__ sel) {
  __shared__ float ml[1024];
  __shared__ float rv[256];
  __shared__ int ri[256];
  int bh = blockIdx.x, tid = threadIdx.x;
  for (int i = tid; i < 1024; i += 256) ml[i] = Mbuf[(size_t)bh * 1024 + i];
  __syncthreads();
  for (int it = 0; it < 35; ++it) {
    float bv = -1e30f; int bi = 0;
    #pragma unroll
    for (int k = 0; k < 4; ++k) {
      int i = tid * 4 + k;
      float v = ml[i];
      if (v > bv) { bv = v; bi = i; }
    }
    rv[tid] = bv; ri[tid] = bi;
    __syncthreads();
    for (int sft = 128; sft > 0; sft >>= 1) {
      if (tid < sft) {
        float ov = rv[tid + sft]; int oi = ri[tid + sft];
        if (ov > rv[tid] || (ov == rv[tid] && oi < ri[tid])) { rv[tid] = ov; ri[tid] = oi; }
      }
      __syncthreads();
    }
    if (tid == 0) { sel[bh * 35 + it] = ri[0]; ml[ri[0]] = -1e30f; }
    __syncthreads();
  }
}

__global__ void prob_fill_kernel(const float* __restrict__ V, float* __restrict__ cbuf) {
  __shared__ float red[256];
  __shared__ float vm[32];
  int bh = blockIdx.x, b = bh >> 1, h = bh & 1;
  int tid = threadIdx.x;
  int d = tid & 31, ch = tid >> 5;
  const float* Vb = V + (size_t)b * 65536 + h * 32;
  float s = 0.0f;
  for (int ss = ch * 128; ss < ch * 128 + 128; ++ss) s += Vb[(size_t)ss * 64 + d];
  red[tid] = s;
  __syncthreads();
  if (ch == 0) {
    float t = 0.0f;
    for (int c = 0; c < 8; ++c) t += red[c * 32 + d];
    vm[d] = t * (1.0f / 1024.0f);
  }
  __syncthreads();
  for (int i = tid; i < 1024 * 32; i += 256) {
    int l = i >> 5, dd = i & 31;
    cbuf[((size_t)b * 1024 + l) * 352 + 192 + h * 32 + dd] = vm[dd];
  }
}

__global__ void prob_part_kernel(const float* __restrict__ Q, const float* __restrict__ K,
                                 const float* __restrict__ V, const int* __restrict__ sel,
                                 float* __restrict__ ppart) {
  int bh = blockIdx.y, b = bh >> 1, h = bh & 1;
  int sc0 = blockIdx.x * 64;
  int u = threadIdx.x;
  int uu = (u < 35) ? u : 34;
  int l = sel[bh * 35 + uu];
  const float* Qb = Q + (size_t)b * 65536 + h * 32;
  const float* Kb = K + (size_t)b * 65536 + h * 32;
  const float* Vb = V + (size_t)b * 65536 + h * 32;
  float q[32];
  #pragma unroll
  for (int i = 0; i < 8; ++i) {
    float4 v4 = ((const float4*)(Qb + (size_t)l * 64))[i];
    q[4*i] = v4.x; q[4*i+1] = v4.y; q[4*i+2] = v4.z; q[4*i+3] = v4.w;
  }
  float o[32];
  #pragma unroll
  for (int dd = 0; dd < 32; ++dd) o[dd] = 0.0f;
  float m = -1e30f, ssum = 0.0f;
  for (int s = sc0; s < sc0 + 64; ++s) {
    const float4* kp = (const float4*)(Kb + (size_t)s * 64);
    float a0 = 0, a1 = 0, a2 = 0, a3 = 0;
    #pragma unroll
    for (int i = 0; i < 8; ++i) {
      float4 kv = kp[i];
      a0 = fmaf(q[4*i], kv.x, a0);
      a1 = fmaf(q[4*i+1], kv.y, a1);
      a2 = fmaf(q[4*i+2], kv.z, a2);
      a3 = fmaf(q[4*i+3], kv.w, a3);
    }
    float sv = ((a0 + a1) + (a2 + a3)) * SCALE_;
    float mn = fmaxf(m, sv);
    float rr = __expf(m - mn);
    float p  = __expf(sv - mn);
    ssum = ssum * rr + p;
    m = mn;
    const float4* vp = (const float4*)(Vb + (size_t)s * 64);
    #pragma unroll
    for (int i = 0; i < 8; ++i) {
      float4 vv = vp[i];
      o[4*i]   = fmaf(o[4*i],   rr, p * vv.x);
      o[4*i+1] = fmaf(o[4*i+1], rr, p * vv.y);
      o[4*i+2] = fmaf(o[4*i+2], rr, p * vv.z);
      o[4*i+3] = fmaf(o[4*i+3], rr, p * vv.w);
    }
  }
  if (u < 35) {
    float* pp = ppart + (((size_t)bh * 16 + blockIdx.x) * 35 + u) * 34;
    #pragma unroll
    for (int dd = 0; dd < 32; ++dd) pp[dd] = o[dd];
    pp[32] = m; pp[33] = ssum;
  }
}

__global__ void prob_comb_kernel(const float* __restrict__ ppart, const int* __restrict__ sel,
                                 float* __restrict__ cbuf) {
  int t = blockIdx.x * 64 + threadIdx.x;
  if (t >= 32 * 35) return;
  int bh = t / 35, u = t % 35;
  int b = bh >> 1, h = bh & 1;
  int l = sel[bh * 35 + u];
  float m = -1e30f;
  for (int j = 0; j < 16; ++j)
    m = fmaxf(m, ppart[(((size_t)bh * 16 + j) * 35 + u) * 34 + 32]);
  float S = 0.0f;
  float o[32];
  #pragma unroll
  for (int d = 0; d < 32; ++d) o[d] = 0.0f;
  for (int j = 0; j < 16; ++j) {
    const float* pp = ppart + (((size_t)bh * 16 + j) * 35 + u) * 34;
    float w = __expf(pp[32] - m);
    S += pp[33] * w;
    #pragma unroll
    for (int d = 0; d < 32; ++d) o[d] += pp[d] * w;
  }
  float inv = 1.0f / S;
  float* cc = cbuf + ((size_t)b * 1024 + l) * 352 + 192 + h * 32;
  #pragma unroll
  for (int d = 0; d < 32; ++d) cc[d] = o[d] * inv;
}

// ---------------------------------------------------------------------------
// autocorrelation branch
// mv[b,tau] = (1/64) sum_m Qa[b,m] * Ka[b,(m+64*tau)&65535]
// ---------------------------------------------------------------------------
__global__ void auto_mv_kernel(const float* __restrict__ Qa, const float* __restrict__ Ka,
                               float* __restrict__ mv) {
  __shared__ float Qs[2048];
  __shared__ float Ks[6464];
  __shared__ float red[256];
  int b = blockIdx.y, tau0 = blockIdx.x * 64;
  int tid = threadIdx.x, tau = tid & 63, part = tid >> 6;
  const float* Qb = Qa + (size_t)b * 65536;
  const float* Kb = Ka + (size_t)b * 65536;
  float a0 = 0, a1 = 0, a2 = 0, a3 = 0;
  for (int m0 = 0; m0 < 65536; m0 += 2048) {
    for (int i = tid; i < 2048; i += 256) Qs[i] = Qb[m0 + i];
    int kbase = (m0 + tau0 * 64) & 65535;
    for (int i = tid; i < 6080; i += 256) Ks[i + 4 * (i >> 6)] = Kb[(kbase + i) & 65535];
    __syncthreads();
    int base = part * 512;
    for (int g = 0; g < 8; ++g) {
      int qb = base + g * 64;
      int ar = qb + 4 * (qb >> 6) + 68 * tau;
      #pragma unroll
      for (int n = 0; n < 64; n += 4) {
        float4 qv = *(const float4*)&Qs[qb + n];
        a0 = fmaf(qv.x, Ks[ar + n], a0);
        a1 = fmaf(qv.y, Ks[ar + n + 1], a1);
        a2 = fmaf(qv.z, Ks[ar + n + 2], a2);
        a3 = fmaf(qv.w, Ks[ar + n + 3], a3);
      }
    }
    __syncthreads();
  }
  red[tid] = (a0 + a1) + (a2 + a3);
  __syncthreads();
  if (part == 0)
    mv[(size_t)b * 1024 + tau0 + tau] =
        (red[tau] + red[tau + 64] + red[tau + 128] + red[tau + 192]) * (1.0f / 64.0f);
}

__global__ void auto_top6_kernel(const float* __restrict__ mv, int* __restrict__ idx6,
                                 float* __restrict__ w6) {
  __shared__ float mm[1024];
  __shared__ float rv[256];
  __shared__ int ri[256];
  __shared__ int id6s[6];
  int tid = threadIdx.x;
  for (int i = tid; i < 1024; i += 256) {
    float s = 0.0f;
    for (int b = 0; b < 16; ++b) s += mv[(size_t)b * 1024 + i];
    mm[i] = s;
  }
  __syncthreads();
  for (int it = 0; it < 6; ++it) {
    float bv = -1e30f; int bi = 0;
    #pragma unroll
    for (int k = 0; k < 4; ++k) {
      int i = tid * 4 + k;
      float v = mm[i];
      if (v > bv) { bv = v; bi = i; }
    }
    rv[tid] = bv; ri[tid] = bi;
    __syncthreads();
    for (int sft = 128; sft > 0; sft >>= 1) {
      if (tid < sft) {
        float ov = rv[tid + sft]; int oi = ri[tid + sft];
        if (ov > rv[tid] || (ov == rv[tid] && oi < ri[tid])) { rv[tid] = ov; ri[tid] = oi; }
      }
      __syncthreads();
    }
    if (tid == 0) { idx6[it] = ri[0]; id6s[it] = ri[0]; mm[ri[0]] = -1e30f; }
    __syncthreads();
  }
  if (tid < 16) {
    int b = tid;
    float vals[6]; float mx = -1e30f;
    #pragma unroll
    for (int j = 0; j < 6; ++j) { vals[j] = mv[(size_t)b * 1024 + id6s[j]]; mx = fmaxf(mx, vals[j]); }
    float s = 0.0f;
    #pragma unroll
    for (int j = 0; j < 6; ++j) { vals[j] = __expf(vals[j] - mx); s += vals[j]; }
    #pragma unroll
    for (int j = 0; j < 6; ++j) w6[b * 6 + j] = vals[j] / s;
  }
}

// agg + aproj + residual:  ca[b,t,:] = iq[b,t,:] + b_aproj + agg[b,t,0:64] @ w_aproj
__global__ void auto_agg_kernel(const float* __restrict__ Va, const float* __restrict__ iq,
                                const float* __restrict__ wap, const float* __restrict__ bap,
                                const int* __restrict__ idx6, const float* __restrict__ w6,
                                float* __restrict__ ca) {
  __shared__ float aggs[16][64];
  __shared__ float w6s[6];
  __shared__ int id6[6];
  int b = blockIdx.y, t0 = blockIdx.x * 16;
  int tid = threadIdx.x;
  if (tid < 6) { w6s[tid] = w6[b * 6 + tid]; id6[tid] = idx6[tid]; }
  __syncthreads();
  const float* Vb = Va + (size_t)b * 65536;
  for (int i = tid; i < 1024; i += 256) {
    int tl = i >> 6, c = i & 63;
    int t = t0 + tl;
    float s = 0.0f;
    #pragma unroll
    for (int j = 0; j < 6; ++j)
      s += w6s[j] * Vb[(size_t)((t + id6[j]) & 1023) * 64 + c];
    aggs[tl][c] = s;
  }
  __syncthreads();
  int dm = tid & 127, tp = tid >> 7;
  float acc[8];
  #pragma unroll
  for (int r = 0; r < 8; ++r) {
    int t = t0 + tp * 8 + r;
    acc[r] = bap[dm] + iq[((size_t)b * 1024 + t) * 128 + dm];
  }
  for (int c = 0; c < 64; ++c) {
    float wv = wap[c * 128 + dm];
    #pragma unroll
    for (int r = 0; r < 8; ++r) acc[r] += aggs[tp * 8 + r][c] * wv;
  }
  #pragma unroll
  for (int r = 0; r < 8; ++r)
    ca[((size_t)b * 1024 + t0 + tp * 8 + r) * 128 + dm] = acc[r];
}

// moving-average detrend (k=25, edge-replicate) + asize projection
__global__ void auto_ma_kernel(const float* __restrict__ ca, const float* __restrict__ was,
                               const float* __restrict__ bas, float* __restrict__ cbuf) {
  __shared__ float cas[40][128];
  __shared__ float diff[16][128];
  int b = blockIdx.y, t0 = blockIdx.x * 16;
  int tid = threadIdx.x;
  for (int i = tid; i < 40 * 128; i += 256) {
    int r = i >> 7, d = i & 127;
    int t = t0 - 12 + r;
    t = (t < 0) ? 0 : ((t > 1023) ? 1023 : t);
    cas[r][d] = ca[((size_t)b * 1024 + t) * 128 + d];
  }
  __syncthreads();
  int d = tid & 127, hf = tid >> 7;
  for (int k = 0; k < 8; ++k) {
    int tl = hf * 8 + k;
    float s = 0.0f;
    #pragma unroll
    for (int w = 0; w < 25; ++w) s += cas[tl + w][d];
    diff[tl][d] = cas[tl + 12][d] - s * (1.0f / 25.0f);
  }
  __syncthreads();
  int j = tid & 63, tq = tid >> 6;
  float acc[4];
  #pragma unroll
  for (int r = 0; r < 4; ++r) acc[r] = bas[j];
  for (int dd = 0; dd < 128; ++dd) {
    float wv = was[dd * 64 + j];
    #pragma unroll
    for (int r = 0; r < 4; ++r) acc[r] += diff[tq * 4 + r][dd] * wv;
  }
  #pragma unroll
  for (int r = 0; r < 4; ++r)
    cbuf[((size_t)b * 1024 + t0 + tq * 4 + r) * 352 + 288 + j] = acc[r];
}

// ---------------------------------------------------------------------------
// FFT branch: cf[b,f,d] = sum_t cos(2*pi*f*t/1024) * x[b,t,d]; then @ w_fft
// ---------------------------------------------------------------------------
__global__ void fft_kernel(const float* __restrict__ x, const float* __restrict__ wfft,
                           const float* __restrict__ bfft, float* __restrict__ cbuf) {
  __shared__ float xs[128][128];   // also reused as cfl[64][128]
  int b = blockIdx.y;
  int fbase = blockIdx.x * 64;
  int tid = threadIdx.x;
  int dg = tid & 31, fg = tid >> 5;
  int d0 = dg * 4;
  const float CPH = 6.28318530717958647692f / 1024.0f;
  float4 acc[8];
  int ph[8], fv[8];
  #pragma unroll
  for (int a = 0; a < 8; ++a) {
    acc[a] = make_float4(0.f, 0.f, 0.f, 0.f);
    fv[a] = fbase + fg * 8 + a;
    ph[a] = 0;
  }
  for (int tc = 0; tc < 8; ++tc) {
    __syncthreads();
    for (int i = tid; i < 128 * 128; i += 256) {
      int r = i >> 7, d = i & 127;
      xs[r][d] = x[((size_t)b * 1024 + tc * 128 + r) * 128 + d];
    }
    __syncthreads();
    for (int tt = 0; tt < 128; ++tt) {
      float4 xv = *(const float4*)&xs[tt][d0];
      #pragma unroll
      for (int a = 0; a < 8; ++a) {
        float cv = __cosf((float)ph[a] * CPH);
        acc[a].x = fmaf(cv, xv.x, acc[a].x);
        acc[a].y = fmaf(cv, xv.y, acc[a].y);
        acc[a].z = fmaf(cv, xv.z, acc[a].z);
        acc[a].w = fmaf(cv, xv.w, acc[a].w);
        ph[a] = (ph[a] + fv[a]) & 1023;
      }
    }
  }
  __syncthreads();
  float* cfl = &xs[0][0];
  #pragma unroll
  for (int a = 0; a < 8; ++a)
    *(float4*)&cfl[(fg * 8 + a) * 128 + d0] = acc[a];
  __syncthreads();
  // projection: 64 f x 32 j
  int j = tid & 31, fo = tid >> 5;
  float pacc[8];
  float bj = bfft[j];
  #pragma unroll
  for (int r = 0; r < 8; ++r) pacc[r] = bj;
  for (int dd = 0; dd < 128; ++dd) {
    float wv = wfft[dd * 32 + j];
    #pragma unroll
    for (int r = 0; r < 8; ++r) pacc[r] += cfl[(fo * 8 + r) * 128 + dd] * wv;
  }
  #pragma unroll
  for (int r = 0; r < 8; ++r)
    cbuf[((size_t)b * 1024 + fbase + fo * 8 + r) * 352 + 256 + j] = pacc[r];
}

// ---------------------------------------------------------------------------
// final: out = cbuf @ w_fc + iq, then layernorm over DM
// ---------------------------------------------------------------------------
__global__ void fc_ln_kernel(const float* __restrict__ cbuf, const float* __restrict__ wfc,
                             const float* __restrict__ iq, float* __restrict__ out) {
  __shared__ float cs[16][352];
  __shared__ float os[16][128];
  int b = blockIdx.y, t0 = blockIdx.x * 16;
  int tid = threadIdx.x;
  for (int i = tid; i < 16 * 352; i += 256) {
    int r = i / 352, col = i % 352;
    cs[r][col] = cbuf[((size_t)b * 1024 + t0 + r) * 352 + col];
  }
  __syncthreads();
  int j = tid & 127, half = tid >> 7;
  float acc[8];
  #pragma unroll
  for (int k = 0; k < 8; ++k)
    acc[k] = iq[((size_t)b * 1024 + t0 + half * 8 + k) * 128 + j];
  for (int i = 0; i < 352; ++i) {
    float wv = wfc[i * 128 + j];
    #pragma unroll
    for (int k = 0; k < 8; ++k) acc[k] += cs[half * 8 + k][i] * wv;
  }
  #pragma unroll
  for (int k = 0; k < 8; ++k) os[half * 8 + k][j] = acc[k];
  __syncthreads();
  int wid = tid >> 6, lane = tid & 63;
  for (int rr = 0; rr < 4; ++rr) {
    int r = wid * 4 + rr;
    float x0 = os[r][lane], x1 = os[r][lane + 64];
    float s1 = x0 + x1;
    float s2 = x0 * x0 + x1 * x1;
    #pragma unroll
    for (int k = 32; k > 0; k >>= 1) {
      s1 += __shfl_xor(s1, k, 64);
      s2 += __shfl_xor(s2, k, 64);
    }
    float mean = s1 * (1.0f / 128.0f);
    float var = s2 * (1.0f / 128.0f) - mean * mean;
    float rstd = 1.0f / sqrtf(var + 1e-5f);
    float* op = out + ((size_t)b * 1024 + t0 + r) * 128;
    op[lane] = (x0 - mean) * rstd;
    op[lane + 64] = (x1 - mean) * rstd;
  }
}

// ---------------------------------------------------------------------------
extern "C" void kernel_launch(void* const* d_in, const int* in_sizes, int n_in,
                              void* d_out, int out_size, void* d_ws, size_t ws_size,
                              hipStream_t stream) {
  (void)in_sizes; (void)n_in; (void)out_size; (void)ws_size;
  const float* inQ = (const float*)d_in[0];
  const float* inK = (const float*)d_in[1];
  const float* inV = (const float*)d_in[2];
  const float *wq[5], *bq[5], *wk[5], *bk[5], *wv[5], *bv[5];
  for (int br = 0; br < 5; ++br) {
    wq[br] = (const float*)d_in[3 + br * 6 + 0];
    bq[br] = (const float*)d_in[3 + br * 6 + 1];
    wk[br] = (const float*)d_in[3 + br * 6 + 2];
    bk[br] = (const float*)d_in[3 + br * 6 + 3];
    wv[br] = (const float*)d_in[3 + br * 6 + 4];
    bv[br] = (const float*)d_in[3 + br * 6 + 5];
  }
  const float* wfft = (const float*)d_in[33];
  const float* bfft = (const float*)d_in[34];
  const float* wap  = (const float*)d_in[35];
  const float* bap  = (const float*)d_in[36];
  const float* was  = (const float*)d_in[37];
  const float* bas  = (const float*)d_in[38];
  const float* wfc  = (const float*)d_in[39];
  float* out = (float*)d_out;

  char* wsb = (char*)d_ws;
  size_t off = 0;
  auto alloc = [&](size_t bytes) -> void* {
    void* p = wsb + off;
    off += (bytes + 255) & ~(size_t)255;
    return p;
  };
  int*   pidx = (int*)  alloc((size_t)35840 * 4);
  float* qbuf = (float*)alloc((size_t)16 * 65536 * 4);
  float* kbuf = (float*)alloc((size_t)16 * 65536 * 4);
  float* vbuf = (float*)alloc((size_t)16 * 65536 * 4);
  float* cbuf = (float*)alloc((size_t)16 * 1024 * 352 * 4);
  float* fpart = (float*)alloc((size_t)32 * 4 * 1024 * 34 * 4);  // union: fpart | ppart | ca
  float* Mbuf = (float*)alloc((size_t)32 * 1024 * 4);
  int*   sel  = (int*)  alloc((size_t)32 * 35 * 4);
  float* mvb  = (float*)alloc((size_t)16 * 1024 * 4);
  int*   idx6 = (int*)  alloc(64);
  float* w6   = (float*)alloc((size_t)16 * 6 * 4);
  float* ppart = fpart;
  float* cab   = fpart;

  mt_kernel<<<1, 256, 0, stream>>>(pidx);

  dim3 cgrid(32, 16);
  // branch 0: full attention
  conv3_kernel<<<cgrid, 256, 0, stream>>>(inQ, wq[0], bq[0], qbuf);
  conv3_kernel<<<cgrid, 256, 0, stream>>>(inK, wk[0], bk[0], kbuf);
  conv1_kernel<<<cgrid, 256, 0, stream>>>(inV, wv[0], bv[0], vbuf);
  attn_full_part<<<dim3(4, 4, 32), 256, 0, stream>>>(qbuf, kbuf, vbuf, fpart);
  attn_full_comb<<<128, 256, 0, stream>>>(fpart, cbuf);

  // branch 1: log-sparse
  conv3_kernel<<<cgrid, 256, 0, stream>>>(inQ, wq[1], bq[1], qbuf);
  conv3_kernel<<<cgrid, 256, 0, stream>>>(inK, wk[1], bk[1], kbuf);
  conv1_kernel<<<cgrid, 256, 0, stream>>>(inV, wv[1], bv[1], vbuf);
  attn_log_kernel<<<128, 256, 0, stream>>>(qbuf, kbuf, vbuf, cbuf);

  // branch 2: local window
  conv3_kernel<<<cgrid, 256, 0, stream>>>(inQ, wq[2], bq[2], qbuf);
  conv3_kernel<<<cgrid, 256, 0, stream>>>(inK, wk[2], bk[2], kbuf);
  conv1_kernel<<<cgrid, 256, 0, stream>>>(inV, wv[2], bv[2], vbuf);
  attn_loc_kernel<<<128, 256, 0, stream>>>(qbuf, kbuf, vbuf, cbuf);

  // branch 3: prob-sparse
  conv3_kernel<<<cgrid, 256, 0, stream>>>(inQ, wq[3], bq[3], qbuf);
  conv3_kernel<<<cgrid, 256, 0, stream>>>(inK, wk[3], bk[3], kbuf);
  conv1_kernel<<<cgrid, 256, 0, stream>>>(inV, wv[3], bv[3], vbuf);
  prob_m_kernel<<<128, 256, 0, stream>>>(qbuf, kbuf, pidx, Mbuf);
  top35_kernel<<<32, 256, 0, stream>>>(Mbuf, sel);
  prob_fill_kernel<<<32, 256, 0, stream>>>(vbuf, cbuf);
  prob_part_kernel<<<dim3(16, 32), 64, 0, stream>>>(qbuf, kbuf, vbuf, sel, ppart);
  prob_comb_kernel<<<18, 64, 0, stream>>>(ppart, sel, cbuf);

  // branch 4: autocorrelation
  conv3_kernel<<<cgrid, 256, 0, stream>>>(inQ, wq[4], bq[4], qbuf);
  conv3_kernel<<<cgrid, 256, 0, stream>>>(inK, wk[4], bk[4], kbuf);
  conv1_kernel<<<cgrid, 256, 0, stream>>>(inV, wv[4], bv[4], vbuf);
  auto_mv_kernel<<<dim3(16, 16), 256, 0, stream>>>(qbuf, kbuf, mvb);
  auto_top6_kernel<<<1, 256, 0, stream>>>(mvb, idx6, w6);
  auto_agg_kernel<<<dim3(64, 16), 256, 0, stream>>>(vbuf, inQ, wap, bap, idx6, w6, cab);
  auto_ma_kernel<<<dim3(64, 16), 256, 0, stream>>>(cab, was, bas, cbuf);

  // FFT branch (independent of convs)
  fft_kernel<<<dim3(16, 16), 256, 0, stream>>>(inQ, wfft, bfft, cbuf);

  // final projection + layernorm
  fc_ln_kernel<<<dim3(64, 16), 256, 0, stream>>>(cbuf, wfc, inQ, out);
}

// Round 3
// 1060.986 us; speedup vs baseline: 1.2993x; 1.2993x over previous
//
#include <hip/hip_runtime.h>
#include <hip/hip_bf16.h>
#include <math.h>

#define B_   16
#define L_   1024
#define DM_  128
#define DK_  32
#define DV_  32
#define NU_  35
#define SCALE_ 0.17677669529663687f   // 1/sqrt(32)

// ---------------------------------------------------------------------------
// MT19937 -> PROB_IDX (35840 draws of genrand_int32() & 1023, seed 0)
// ---------------------------------------------------------------------------
__global__ void mt_kernel(int* __restrict__ pidx) {
  __shared__ unsigned int mt[624];
  int tid = threadIdx.x;
  if (tid == 0) {
    unsigned int s = 0u;
    for (int i = 0; i < 624; ++i) {
      mt[i] = s;
      s = 1812433253u * (s ^ (s >> 30)) + (unsigned)(i + 1);
    }
  }
  __syncthreads();
  for (int blk = 0; blk < 58; ++blk) {
    unsigned int v = 0; bool act = tid < 227;
    if (act) {
      unsigned int y = (mt[tid] & 0x80000000u) | (mt[tid + 1] & 0x7fffffffu);
      v = mt[tid + 397] ^ (y >> 1) ^ ((y & 1u) ? 0x9908b0dfu : 0u);
    }
    __syncthreads();
    if (act) mt[tid] = v;
    __syncthreads();
    if (act) {
      int kk = 227 + tid;
      unsigned int y = (mt[kk] & 0x80000000u) | (mt[kk + 1] & 0x7fffffffu);
      v = mt[kk - 227] ^ (y >> 1) ^ ((y & 1u) ? 0x9908b0dfu : 0u);
    }
    __syncthreads();
    if (act) mt[227 + tid] = v;
    __syncthreads();
    bool act3 = tid < 169;
    if (act3) {
      int kk = 454 + tid;
      unsigned int y = (mt[kk] & 0x80000000u) | (mt[kk + 1] & 0x7fffffffu);
      v = mt[kk - 227] ^ (y >> 1) ^ ((y & 1u) ? 0x9908b0dfu : 0u);
    }
    __syncthreads();
    if (act3) mt[454 + tid] = v;
    __syncthreads();
    if (tid == 0) {
      unsigned int y = (mt[623] & 0x80000000u) | (mt[0] & 0x7fffffffu);
      mt[623] = mt[396] ^ (y >> 1) ^ ((y & 1u) ? 0x9908b0dfu : 0u);
    }
    __syncthreads();
    for (int i = tid; i < 624; i += 256) {
      int g = blk * 624 + i;
      if (g < 35840) {
        unsigned int y = mt[i];
        y ^= y >> 11;
        y ^= (y << 7) & 0x9d2c5680u;
        y ^= (y << 15) & 0xefc60000u;
        y ^= y >> 18;
        pidx[g] = (int)(y & 1023u);
      }
    }
    __syncthreads();
  }
}

// ---------------------------------------------------------------------------
// conv k=3, left pad 2. OUTPUT IS CHANNEL-MAJOR: out[b, c*1024 + t]
// (matches reference reshape semantics: Q[b,l,h,dd] = flat[l*64+h*32+dd])
// ---------------------------------------------------------------------------
__global__ void conv3_kernel(const float* __restrict__ x, const float* __restrict__ w,
                             const float* __restrict__ bias, float* __restrict__ out) {
  __shared__ float xs[34][128];
  __shared__ float ws[64][97];
  int b = blockIdx.y, t0 = blockIdx.x * 32;
  int tid = threadIdx.x;
  for (int i = tid; i < 34 * 128; i += 256) {
    int r = i >> 7, d = i & 127;
    int t = t0 - 2 + r;
    xs[r][d] = (t >= 0) ? x[(size_t)b * 131072 + (size_t)t * 128 + d] : 0.0f;
  }
  int c = tid & 63, tt0 = (tid >> 6) * 8;
  float acc[8];
  float bvv = bias[c];
  #pragma unroll
  for (int j = 0; j < 8; ++j) acc[j] = bvv;
  for (int dc = 0; dc < 128; dc += 32) {
    __syncthreads();
    for (int i = tid; i < 64 * 96; i += 256) {
      int cc = i / 96, jj = i % 96;
      ws[cc][jj] = w[cc * 384 + dc * 3 + jj];
    }
    __syncthreads();
    for (int d0 = dc; d0 < dc + 32; d0 += 4) {
      float4 xr[10];
      #pragma unroll
      for (int r = 0; r < 10; ++r) xr[r] = *(const float4*)&xs[tt0 + r][d0];
      float wreg[12];
      #pragma unroll
      for (int jj = 0; jj < 12; ++jj) wreg[jj] = ws[c][(d0 - dc) * 3 + jj];
      #pragma unroll
      for (int j = 0; j < 8; ++j) {
        float a = acc[j];
        #pragma unroll
        for (int k = 0; k < 3; ++k) {
          float4 xv = xr[j + k];
          a = fmaf(wreg[0 + k], xv.x, a);
          a = fmaf(wreg[3 + k], xv.y, a);
          a = fmaf(wreg[6 + k], xv.z, a);
          a = fmaf(wreg[9 + k], xv.w, a);
        }
        acc[j] = a;
      }
    }
  }
  float* op = out + (size_t)b * 65536 + (size_t)c * 1024 + t0 + tt0;
  #pragma unroll
  for (int j = 0; j < 8; ++j) op[j] = acc[j];
}

// conv k=1. OUTPUT IS CHANNEL-MAJOR.
__global__ void conv1_kernel(const float* __restrict__ x, const float* __restrict__ w,
                             const float* __restrict__ bias, float* __restrict__ out) {
  __shared__ float xs[32][128];
  __shared__ float ws[64][129];
  int b = blockIdx.y, t0 = blockIdx.x * 32;
  int tid = threadIdx.x;
  for (int i = tid; i < 32 * 128; i += 256) {
    int r = i >> 7, d = i & 127;
    xs[r][d] = x[(size_t)b * 131072 + (size_t)(t0 + r) * 128 + d];
  }
  for (int i = tid; i < 64 * 128; i += 256) {
    ws[i >> 7][i & 127] = w[i];
  }
  __syncthreads();
  int c = tid & 63, tt0 = (tid >> 6) * 8;
  float acc[8];
  float bvv = bias[c];
  #pragma unroll
  for (int j = 0; j < 8; ++j) acc[j] = bvv;
  for (int d0 = 0; d0 < 128; d0 += 4) {
    float w0 = ws[c][d0], w1 = ws[c][d0 + 1], w2 = ws[c][d0 + 2], w3 = ws[c][d0 + 3];
    #pragma unroll
    for (int j = 0; j < 8; ++j) {
      float4 xv = *(const float4*)&xs[tt0 + j][d0];
      float a = acc[j];
      a = fmaf(w0, xv.x, a);
      a = fmaf(w1, xv.y, a);
      a = fmaf(w2, xv.z, a);
      a = fmaf(w3, xv.w, a);
      acc[j] = a;
    }
  }
  float* op = out + (size_t)b * 65536 + (size_t)c * 1024 + t0 + tt0;
  #pragma unroll
  for (int j = 0; j < 8; ++j) op[j] = acc[j];
}

// ---------------------------------------------------------------------------
// full attention, split-K partials (lane-per-query, K/V tile in LDS)
// consumers read flat offset l*64 + h*32 + dd (reshape semantics)
// ---------------------------------------------------------------------------
__global__ void attn_full_part(const float* __restrict__ Q, const float* __restrict__ K,
                               const float* __restrict__ V, float* __restrict__ part) {
  __shared__ float Ks[256][32];
  __shared__ float Vs[256][32];
  int bh = blockIdx.z, b = bh >> 1, h = bh & 1;
  int l = blockIdx.x * 256 + threadIdx.x;
  int s0 = blockIdx.y * 256;
  const float* Kb = K + (size_t)b * 65536 + h * 32;
  const float* Vb = V + (size_t)b * 65536 + h * 32;
  for (int i = threadIdx.x; i < 2048; i += 256) {
    int r = i >> 3, d4 = i & 7;
    ((float4*)&Ks[r][0])[d4] = *(const float4*)(Kb + (size_t)(s0 + r) * 64 + d4 * 4);
    ((float4*)&Vs[r][0])[d4] = *(const float4*)(Vb + (size_t)(s0 + r) * 64 + d4 * 4);
  }
  __syncthreads();
  const float* Qb = Q + (size_t)b * 65536 + h * 32 + (size_t)l * 64;
  float q[32];
  #pragma unroll
  for (int i = 0; i < 8; ++i) {
    float4 v4 = ((const float4*)Qb)[i];
    q[4*i] = v4.x; q[4*i+1] = v4.y; q[4*i+2] = v4.z; q[4*i+3] = v4.w;
  }
  float o[32];
  #pragma unroll
  for (int d = 0; d < 32; ++d) o[d] = 0.0f;
  float m = -1e30f, ssum = 0.0f;
  for (int s = 0; s < 256; ++s) {
    float a0 = 0, a1 = 0, a2 = 0, a3 = 0;
    const float4* kp = (const float4*)&Ks[s][0];
    #pragma unroll
    for (int i = 0; i < 8; ++i) {
      float4 kv = kp[i];
      a0 = fmaf(q[4*i], kv.x, a0);
      a1 = fmaf(q[4*i+1], kv.y, a1);
      a2 = fmaf(q[4*i+2], kv.z, a2);
      a3 = fmaf(q[4*i+3], kv.w, a3);
    }
    float sv = ((a0 + a1) + (a2 + a3)) * SCALE_;
    float mn = fmaxf(m, sv);
    float rr = __expf(m - mn);
    float p  = __expf(sv - mn);
    ssum = ssum * rr + p;
    m = mn;
    const float4* vp = (const float4*)&Vs[s][0];
    #pragma unroll
    for (int i = 0; i < 8; ++i) {
      float4 vv = vp[i];
      o[4*i]   = fmaf(o[4*i],   rr, p * vv.x);
      o[4*i+1] = fmaf(o[4*i+1], rr, p * vv.y);
      o[4*i+2] = fmaf(o[4*i+2], rr, p * vv.z);
      o[4*i+3] = fmaf(o[4*i+3], rr, p * vv.w);
    }
  }
  float* pp = part + (((size_t)bh * 4 + blockIdx.y) * 1024 + l) * 34;
  #pragma unroll
  for (int d = 0; d < 32; ++d) pp[d] = o[d];
  pp[32] = m; pp[33] = ssum;
}

__global__ void attn_full_comb(const float* __restrict__ part, float* __restrict__ cbuf) {
  int idx = blockIdx.x * 256 + threadIdx.x;
  int bh = idx >> 10, l = idx & 1023;
  int b = bh >> 1, h = bh & 1;
  float m = -1e30f;
  for (int j = 0; j < 4; ++j)
    m = fmaxf(m, part[(((size_t)bh * 4 + j) * 1024 + l) * 34 + 32]);
  float S = 0.0f;
  float o[32];
  #pragma unroll
  for (int d = 0; d < 32; ++d) o[d] = 0.0f;
  for (int j = 0; j < 4; ++j) {
    const float* pp = part + (((size_t)bh * 4 + j) * 1024 + l) * 34;
    float w = __expf(pp[32] - m);
    S += pp[33] * w;
    #pragma unroll
    for (int d = 0; d < 32; ++d) o[d] += pp[d] * w;
  }
  float inv = 1.0f / S;
  float* cc = cbuf + ((size_t)b * 1024 + l) * 352 + 0 + h * 32;
  #pragma unroll
  for (int d = 0; d < 32; ++d) cc[d] = o[d] * inv;
}

// ---------------------------------------------------------------------------
// log-sparse attention
// ---------------------------------------------------------------------------
__global__ void attn_log_kernel(const float* __restrict__ Q, const float* __restrict__ K,
                                const float* __restrict__ V, float* __restrict__ cbuf) {
  int idx = blockIdx.x * 256 + threadIdx.x;
  int bh = idx >> 10, l = idx & 1023;
  int b = bh >> 1, h = bh & 1;
  const float* Qb = Q + (size_t)b * 65536 + h * 32;
  const float* Kb = K + (size_t)b * 65536 + h * 32;
  const float* Vb = V + (size_t)b * 65536 + h * 32;
  float q[32];
  #pragma unroll
  for (int i = 0; i < 8; ++i) {
    float4 v4 = ((const float4*)(Qb + (size_t)l * 64))[i];
    q[4*i] = v4.x; q[4*i+1] = v4.y; q[4*i+2] = v4.z; q[4*i+3] = v4.w;
  }
  float sc[11];
  float m = -1e30f;
  #pragma unroll
  for (int j = 0; j < 11; ++j) {
    int off = (j == 0) ? 0 : (1 << (j - 1));
    float sv = -1e30f;
    if (off <= l) {
      const float4* kp = (const float4*)(Kb + (size_t)(l - off) * 64);
      float a0 = 0, a1 = 0, a2 = 0, a3 = 0;
      #pragma unroll
      for (int i = 0; i < 8; ++i) {
        float4 kv = kp[i];
        a0 = fmaf(q[4*i], kv.x, a0);
        a1 = fmaf(q[4*i+1], kv.y, a1);
        a2 = fmaf(q[4*i+2], kv.z, a2);
        a3 = fmaf(q[4*i+3], kv.w, a3);
      }
      sv = ((a0 + a1) + (a2 + a3)) * SCALE_;
    }
    sc[j] = sv;
    m = fmaxf(m, sv);
  }
  float o[32];
  #pragma unroll
  for (int d = 0; d < 32; ++d) o[d] = 0.0f;
  float ssum = 0.0f;
  #pragma unroll
  for (int j = 0; j < 11; ++j) {
    int off = (j == 0) ? 0 : (1 << (j - 1));
    if (off <= l) {
      float p = __expf(sc[j] - m);
      ssum += p;
      const float4* vp = (const float4*)(Vb + (size_t)(l - off) * 64);
      #pragma unroll
      for (int i = 0; i < 8; ++i) {
        float4 vv = vp[i];
        o[4*i]   = fmaf(p, vv.x, o[4*i]);
        o[4*i+1] = fmaf(p, vv.y, o[4*i+1]);
        o[4*i+2] = fmaf(p, vv.z, o[4*i+2]);
        o[4*i+3] = fmaf(p, vv.w, o[4*i+3]);
      }
    }
  }
  float inv = 1.0f / ssum;
  float* cc = cbuf + ((size_t)b * 1024 + l) * 352 + 64 + h * 32;
  #pragma unroll
  for (int d = 0; d < 32; ++d) cc[d] = o[d] * inv;
}

// local-window attention: s in [l-31, l]
__global__ void attn_loc_kernel(const float* __restrict__ Q, const float* __restrict__ K,
                                const float* __restrict__ V, float* __restrict__ cbuf) {
  int idx = blockIdx.x * 256 + threadIdx.x;
  int bh = idx >> 10, l = idx & 1023;
  int b = bh >> 1, h = bh & 1;
  const float* Qb = Q + (size_t)b * 65536 + h * 32;
  const float* Kb = K + (size_t)b * 65536 + h * 32;
  const float* Vb = V + (size_t)b * 65536 + h * 32;
  float q[32];
  #pragma unroll
  for (int i = 0; i < 8; ++i) {
    float4 v4 = ((const float4*)(Qb + (size_t)l * 64))[i];
    q[4*i] = v4.x; q[4*i+1] = v4.y; q[4*i+2] = v4.z; q[4*i+3] = v4.w;
  }
  float sc[32];
  float m = -1e30f;
  #pragma unroll
  for (int j = 0; j < 32; ++j) {
    int s = l - 31 + j;
    float sv = -1e30f;
    if (s >= 0) {
      const float4* kp = (const float4*)(Kb + (size_t)s * 64);
      float a0 = 0, a1 = 0, a2 = 0, a3 = 0;
      #pragma unroll
      for (int i = 0; i < 8; ++i) {
        float4 kv = kp[i];
        a0 = fmaf(q[4*i], kv.x, a0);
        a1 = fmaf(q[4*i+1], kv.y, a1);
        a2 = fmaf(q[4*i+2], kv.z, a2);
        a3 = fmaf(q[4*i+3], kv.w, a3);
      }
      sv = ((a0 + a1) + (a2 + a3)) * SCALE_;
    }
    sc[j] = sv;
    m = fmaxf(m, sv);
  }
  float o[32];
  #pragma unroll
  for (int d = 0; d < 32; ++d) o[d] = 0.0f;
  float ssum = 0.0f;
  #pragma unroll
  for (int j = 0; j < 32; ++j) {
    int s = l - 31 + j;
    if (s >= 0) {
      float p = __expf(sc[j] - m);
      ssum += p;
      const float4* vp = (const float4*)(Vb + (size_t)s * 64);
      #pragma unroll
      for (int i = 0; i < 8; ++i) {
        float4 vv = vp[i];
        o[4*i]   = fmaf(p, vv.x, o[4*i]);
        o[4*i+1] = fmaf(p, vv.y, o[4*i+1]);
        o[4*i+2] = fmaf(p, vv.z, o[4*i+2]);
        o[4*i+3] = fmaf(p, vv.w, o[4*i+3]);
      }
    }
  }
  float inv = 1.0f / ssum;
  float* cc = cbuf + ((size_t)b * 1024 + l) * 352 + 128 + h * 32;
  #pragma unroll
  for (int d = 0; d < 32; ++d) cc[d] = o[d] * inv;
}

// ---------------------------------------------------------------------------
// prob-sparse attention
// ---------------------------------------------------------------------------
__global__ void prob_m_kernel(const float* __restrict__ Q, const float* __restrict__ K,
                              const int* __restrict__ pidx, float* __restrict__ Mbuf) {
  int idx = blockIdx.x * 256 + threadIdx.x;
  int bh = idx >> 10, l = idx & 1023;
  int b = bh >> 1, h = bh & 1;
  const float* Qb = Q + (size_t)b * 65536 + h * 32;
  const float* Kb = K + (size_t)b * 65536 + h * 32;
  float q[32];
  #pragma unroll
  for (int i = 0; i < 8; ++i) {
    float4 v4 = ((const float4*)(Qb + (size_t)l * 64))[i];
    q[4*i] = v4.x; q[4*i+1] = v4.y; q[4*i+2] = v4.z; q[4*i+3] = v4.w;
  }
  float mx = -1e30f, sm = 0.0f;
  for (int u = 0; u < 35; ++u) {
    int ki = pidx[l * 35 + u];
    const float4* kp = (const float4*)(Kb + (size_t)ki * 64);
    float a0 = 0, a1 = 0, a2 = 0, a3 = 0;
    #pragma unroll
    for (int i = 0; i < 8; ++i) {
      float4 kv = kp[i];
      a0 = fmaf(q[4*i], kv.x, a0);
      a1 = fmaf(q[4*i+1], kv.y, a1);
      a2 = fmaf(q[4*i+2], kv.z, a2);
      a3 = fmaf(q[4*i+3], kv.w, a3);
    }
    float s = (a0 + a1) + (a2 + a3);
    mx = fmaxf(mx, s);
    sm += s;
  }
  Mbuf[(size_t)bh * 1024 + l] = mx - sm * (1.0f / 1024.0f);
}

__global__ void top35_kernel(const float* __restrict__ Mbuf, int* __restrict__ sel) {
  __shared__ float ml[1024];
  __shared__ float rv[256];
  __shared__ int ri[256];
  int bh = blockIdx.x, tid = threadIdx.x;
  for (int i = tid; i < 1024; i += 256) ml[i] = Mbuf[(size_t)bh * 1024 + i];
  __syncthreads();
  for (int it = 0; it < 35; ++it) {
    float bv = -1e30f; int bi = 0;
    #pragma unroll
    for (int k = 0; k < 4; ++k) {
      int i = tid * 4 + k;
      float v = ml[i];
      if (v > bv) { bv = v; bi = i; }
    }
    rv[tid] = bv; ri[tid] = bi;
    __syncthreads();
    for (int sft = 128; sft > 0; sft >>= 1) {
      if (tid < sft) {
        float ov = rv[tid + sft]; int oi = ri[tid + sft];
        if (ov > rv[tid] || (ov == rv[tid] && oi < ri[tid])) { rv[tid] = ov; ri[tid] = oi; }
      }
      __syncthreads();
    }
    if (tid == 0) { sel[bh * 35 + it] = ri[0]; ml[ri[0]] = -1e30f; }
    __syncthreads();
  }
}

__global__ void prob_fill_kernel(const float* __restrict__ V, float* __restrict__ cbuf) {
  __shared__ float red[256];
  __shared__ float vm[32];
  int bh = blockIdx.x, b = bh >> 1, h = bh & 1;
  int tid = threadIdx.x;
  int d = tid & 31, ch = tid >> 5;
  const float* Vb = V + (size_t)b * 65536 + h * 32;
  float s = 0.0f;
  for (int ss = ch * 128; ss < ch * 128 + 128; ++ss) s += Vb[(size_t)ss * 64 + d];
  red[tid] = s;
  __syncthreads();
  if (ch == 0) {
    float t = 0.0f;
    for (int c = 0; c < 8; ++c) t += red[c * 32 + d];
    vm[d] = t * (1.0f / 1024.0f);
  }
  __syncthreads();
  for (int i = tid; i < 1024 * 32; i += 256) {
    int l = i >> 5, dd = i & 31;
    cbuf[((size_t)b * 1024 + l) * 352 + 192 + h * 32 + dd] = vm[dd];
  }
}

__global__ void prob_part_kernel(const float* __restrict__ Q, const float* __restrict__ K,
                                 const float* __restrict__ V, const int* __restrict__ sel,
                                 float* __restrict__ ppart) {
  int bh = blockIdx.y, b = bh >> 1, h = bh & 1;
  int sc0 = blockIdx.x * 64;
  int u = threadIdx.x;
  int uu = (u < 35) ? u : 34;
  int l = sel[bh * 35 + uu];
  const float* Qb = Q + (size_t)b * 65536 + h * 32;
  const float* Kb = K + (size_t)b * 65536 + h * 32;
  const float* Vb = V + (size_t)b * 65536 + h * 32;
  float q[32];
  #pragma unroll
  for (int i = 0; i < 8; ++i) {
    float4 v4 = ((const float4*)(Qb + (size_t)l * 64))[i];
    q[4*i] = v4.x; q[4*i+1] = v4.y; q[4*i+2] = v4.z; q[4*i+3] = v4.w;
  }
  float o[32];
  #pragma unroll
  for (int dd = 0; dd < 32; ++dd) o[dd] = 0.0f;
  float m = -1e30f, ssum = 0.0f;
  for (int s = sc0; s < sc0 + 64; ++s) {
    const float4* kp = (const float4*)(Kb + (size_t)s * 64);
    float a0 = 0, a1 = 0, a2 = 0, a3 = 0;
    #pragma unroll
    for (int i = 0; i < 8; ++i) {
      float4 kv = kp[i];
      a0 = fmaf(q[4*i], kv.x, a0);
      a1 = fmaf(q[4*i+1], kv.y, a1);
      a2 = fmaf(q[4*i+2], kv.z, a2);
      a3 = fmaf(q[4*i+3], kv.w, a3);
    }
    float sv = ((a0 + a1) + (a2 + a3)) * SCALE_;
    float mn = fmaxf(m, sv);
    float rr = __expf(m - mn);
    float p  = __expf(sv - mn);
    ssum = ssum * rr + p;
    m = mn;
    const float4* vp = (const float4*)(Vb + (size_t)s * 64);
    #pragma unroll
    for (int i = 0; i < 8; ++i) {
      float4 vv = vp[i];
      o[4*i]   = fmaf(o[4*i],   rr, p * vv.x);
      o[4*i+1] = fmaf(o[4*i+1], rr, p * vv.y);
      o[4*i+2] = fmaf(o[4*i+2], rr, p * vv.z);
      o[4*i+3] = fmaf(o[4*i+3], rr, p * vv.w);
    }
  }
  if (u < 35) {
    float* pp = ppart + (((size_t)bh * 16 + blockIdx.x) * 35 + u) * 34;
    #pragma unroll
    for (int dd = 0; dd < 32; ++dd) pp[dd] = o[dd];
    pp[32] = m; pp[33] = ssum;
  }
}

__global__ void prob_comb_kernel(const float* __restrict__ ppart, const int* __restrict__ sel,
                                 float* __restrict__ cbuf) {
  int t = blockIdx.x * 64 + threadIdx.x;
  if (t >= 32 * 35) return;
  int bh = t / 35, u = t % 35;
  int b = bh >> 1, h = bh & 1;
  int l = sel[bh * 35 + u];
  float m = -1e30f;
  for (int j = 0; j < 16; ++j)
    m = fmaxf(m, ppart[(((size_t)bh * 16 + j) * 35 + u) * 34 + 32]);
  float S = 0.0f;
  float o[32];
  #pragma unroll
  for (int d = 0; d < 32; ++d) o[d] = 0.0f;
  for (int j = 0; j < 16; ++j) {
    const float* pp = ppart + (((size_t)bh * 16 + j) * 35 + u) * 34;
    float w = __expf(pp[32] - m);
    S += pp[33] * w;
    #pragma unroll
    for (int d = 0; d < 32; ++d) o[d] += pp[d] * w;
  }
  float inv = 1.0f / S;
  float* cc = cbuf + ((size_t)b * 1024 + l) * 352 + 192 + h * 32;
  #pragma unroll
  for (int d = 0; d < 32; ++d) cc[d] = o[d] * inv;
}

// ---------------------------------------------------------------------------
// autocorrelation: mv[b,tau] = (1/64) sum_{c,t} K[b,c,t] * Q[b,c,(t+tau)%1024]
// channel-major layout: channel c is contiguous [c*1024 .. c*1024+1023]
// one block per (b,c); 256 threads x 4 taus; register tile 8t x 4tau
// ---------------------------------------------------------------------------
__global__ void auto_mv_part(const float* __restrict__ Qa, const float* __restrict__ Ka,
                             float* __restrict__ part) {
  __shared__ float ks[1024];    // K channel data
  __shared__ float qs[2048];    // Q channel data, duplicated (wrap)
  int c = blockIdx.x, b = blockIdx.y;
  int tid = threadIdx.x;
  const float* Qb = Qa + (size_t)b * 65536 + (size_t)c * 1024;
  const float* Kb = Ka + (size_t)b * 65536 + (size_t)c * 1024;
  ((float4*)ks)[tid] = ((const float4*)Kb)[tid];
  {
    float4 qv = ((const float4*)Qb)[tid];
    ((float4*)qs)[tid] = qv;
    ((float4*)qs)[tid + 256] = qv;
  }
  __syncthreads();
  int tau0 = tid * 4;
  float a0 = 0, a1 = 0, a2 = 0, a3 = 0;
  for (int t = 0; t < 1024; t += 8) {
    float4 q0 = *(const float4*)&ks[t];
    float4 q1 = *(const float4*)&ks[t + 4];
    const float* kp = &qs[t + tau0];
    float4 k0 = *(const float4*)(kp);
    float4 k1 = *(const float4*)(kp + 4);
    float4 k2 = *(const float4*)(kp + 8);
    a0 = fmaf(q0.x, k0.x, a0); a1 = fmaf(q0.x, k0.y, a1); a2 = fmaf(q0.x, k0.z, a2); a3 = fmaf(q0.x, k0.w, a3);
    a0 = fmaf(q0.y, k0.y, a0); a1 = fmaf(q0.y, k0.z, a1); a2 = fmaf(q0.y, k0.w, a2); a3 = fmaf(q0.y, k1.x, a3);
    a0 = fmaf(q0.z, k0.z, a0); a1 = fmaf(q0.z, k0.w, a1); a2 = fmaf(q0.z, k1.x, a2); a3 = fmaf(q0.z, k1.y, a3);
    a0 = fmaf(q0.w, k0.w, a0); a1 = fmaf(q0.w, k1.x, a1); a2 = fmaf(q0.w, k1.y, a2); a3 = fmaf(q0.w, k1.z, a3);
    a0 = fmaf(q1.x, k1.x, a0); a1 = fmaf(q1.x, k1.y, a1); a2 = fmaf(q1.x, k1.z, a2); a3 = fmaf(q1.x, k1.w, a3);
    a0 = fmaf(q1.y, k1.y, a0); a1 = fmaf(q1.y, k1.z, a1); a2 = fmaf(q1.y, k1.w, a2); a3 = fmaf(q1.y, k2.x, a3);
    a0 = fmaf(q1.z, k1.z, a0); a1 = fmaf(q1.z, k1.w, a1); a2 = fmaf(q1.z, k2.x, a2); a3 = fmaf(q1.z, k2.y, a3);
    a0 = fmaf(q1.w, k1.w, a0); a1 = fmaf(q1.w, k2.x, a1); a2 = fmaf(q1.w, k2.y, a2); a3 = fmaf(q1.w, k2.z, a3);
  }
  *(float4*)&part[(((size_t)b * 64 + c) << 10) + tau0] = make_float4(a0, a1, a2, a3);
}

__global__ void auto_mv_reduce(const float* __restrict__ part, float* __restrict__ mv) {
  int idx = blockIdx.x * 256 + threadIdx.x;   // 16384 = 16b x 1024tau
  int b = idx >> 10, tau = idx & 1023;
  float s = 0.0f;
  for (int c = 0; c < 64; ++c) s += part[(((size_t)b * 64 + c) << 10) + tau];
  mv[(size_t)b * 1024 + tau] = s * (1.0f / 64.0f);
}

__global__ void auto_top6_kernel(const float* __restrict__ mv, int* __restrict__ idx6,
                                 float* __restrict__ w6) {
  __shared__ float mm[1024];
  __shared__ float rv[256];
  __shared__ int ri[256];
  __shared__ int id6s[6];
  int tid = threadIdx.x;
  for (int i = tid; i < 1024; i += 256) {
    float s = 0.0f;
    for (int b = 0; b < 16; ++b) s += mv[(size_t)b * 1024 + i];
    mm[i] = s;
  }
  __syncthreads();
  for (int it = 0; it < 6; ++it) {
    float bv = -1e30f; int bi = 0;
    #pragma unroll
    for (int k = 0; k < 4; ++k) {
      int i = tid * 4 + k;
      float v = mm[i];
      if (v > bv) { bv = v; bi = i; }
    }
    rv[tid] = bv; ri[tid] = bi;
    __syncthreads();
    for (int sft = 128; sft > 0; sft >>= 1) {
      if (tid < sft) {
        float ov = rv[tid + sft]; int oi = ri[tid + sft];
        if (ov > rv[tid] || (ov == rv[tid] && oi < ri[tid])) { rv[tid] = ov; ri[tid] = oi; }
      }
      __syncthreads();
    }
    if (tid == 0) { idx6[it] = ri[0]; id6s[it] = ri[0]; mm[ri[0]] = -1e30f; }
    __syncthreads();
  }
  if (tid < 16) {
    int b = tid;
    float vals[6]; float mx = -1e30f;
    #pragma unroll
    for (int j = 0; j < 6; ++j) { vals[j] = mv[(size_t)b * 1024 + id6s[j]]; mx = fmaxf(mx, vals[j]); }
    float s = 0.0f;
    #pragma unroll
    for (int j = 0; j < 6; ++j) { vals[j] = __expf(vals[j] - mx); s += vals[j]; }
    #pragma unroll
    for (int j = 0; j < 6; ++j) w6[b * 6 + j] = vals[j] / s;
  }
}

// agg + aproj + residual; v[b,h,dd,t'] = Vflat[t'*64 + h*32+dd] (reshape semantics)
__global__ void auto_agg_kernel(const float* __restrict__ Va, const float* __restrict__ iq,
                                const float* __restrict__ wap, const float* __restrict__ bap,
                                const int* __restrict__ idx6, const float* __restrict__ w6,
                                float* __restrict__ ca) {
  __shared__ float aggs[16][64];
  __shared__ float w6s[6];
  __shared__ int id6[6];
  int b = blockIdx.y, t0 = blockIdx.x * 16;
  int tid = threadIdx.x;
  if (tid < 6) { w6s[tid] = w6[b * 6 + tid]; id6[tid] = idx6[tid]; }
  __syncthreads();
  const float* Vb = Va + (size_t)b * 65536;
  for (int i = tid; i < 1024; i += 256) {
    int tl = i >> 6, c = i & 63;
    int t = t0 + tl;
    float s = 0.0f;
    #pragma unroll
    for (int j = 0; j < 6; ++j)
      s += w6s[j] * Vb[(size_t)((t + id6[j]) & 1023) * 64 + c];
    aggs[tl][c] = s;
  }
  __syncthreads();
  int dm = tid & 127, tp = tid >> 7;
  float acc[8];
  #pragma unroll
  for (int r = 0; r < 8; ++r) {
    int t = t0 + tp * 8 + r;
    acc[r] = bap[dm] + iq[((size_t)b * 1024 + t) * 128 + dm];
  }
  for (int c = 0; c < 64; ++c) {
    float wv = wap[c * 128 + dm];
    #pragma unroll
    for (int r = 0; r < 8; ++r) acc[r] += aggs[tp * 8 + r][c] * wv;
  }
  #pragma unroll
  for (int r = 0; r < 8; ++r)
    ca[((size_t)b * 1024 + t0 + tp * 8 + r) * 128 + dm] = acc[r];
}

__global__ void auto_ma_kernel(const float* __restrict__ ca, const float* __restrict__ was,
                               const float* __restrict__ bas, float* __restrict__ cbuf) {
  __shared__ float cas[40][128];
  __shared__ float diff[16][128];
  int b = blockIdx.y, t0 = blockIdx.x * 16;
  int tid = threadIdx.x;
  for (int i = tid; i < 40 * 128; i += 256) {
    int r = i >> 7, d = i & 127;
    int t = t0 - 12 + r;
    t = (t < 0) ? 0 : ((t > 1023) ? 1023 : t);
    cas[r][d] = ca[((size_t)b * 1024 + t) * 128 + d];
  }
  __syncthreads();
  int d = tid & 127, hf = tid >> 7;
  for (int k = 0; k < 8; ++k) {
    int tl = hf * 8 + k;
    float s = 0.0f;
    #pragma unroll
    for (int w = 0; w < 25; ++w) s += cas[tl + w][d];
    diff[tl][d] = cas[tl + 12][d] - s * (1.0f / 25.0f);
  }
  __syncthreads();
  int j = tid & 63, tq = tid >> 6;
  float acc[4];
  #pragma unroll
  for (int r = 0; r < 4; ++r) acc[r] = bas[j];
  for (int dd = 0; dd < 128; ++dd) {
    float wv = was[dd * 64 + j];
    #pragma unroll
    for (int r = 0; r < 4; ++r) acc[r] += diff[tq * 4 + r][dd] * wv;
  }
  #pragma unroll
  for (int r = 0; r < 4; ++r)
    cbuf[((size_t)b * 1024 + t0 + tq * 4 + r) * 352 + 288 + j] = acc[r];
}

// ---------------------------------------------------------------------------
// FFT branch reordered: Y = X @ wfft (67M MAC), then cf_proj = cosM @ Y (537M)
// ---------------------------------------------------------------------------
__global__ void fftY_kernel(const float* __restrict__ x, const float* __restrict__ wfft,
                            float* __restrict__ Y) {
  __shared__ float xs[64][128];
  __shared__ float ws[32][129];
  int b = blockIdx.y, t0 = blockIdx.x * 64;
  int tid = threadIdx.x;
  for (int i = tid; i < 64 * 128; i += 256) {
    int r = i >> 7, d = i & 127;
    xs[r][d] = x[(size_t)b * 131072 + (size_t)(t0 + r) * 128 + d];
  }
  for (int i = tid; i < 4096; i += 256) {
    int d = i >> 5, j = i & 31;
    ws[j][d] = wfft[i];
  }
  __syncthreads();
  int j = tid & 31, tt0 = (tid >> 5) * 8;
  float acc[8];
  #pragma unroll
  for (int r = 0; r < 8; ++r) acc[r] = 0.0f;
  for (int d0 = 0; d0 < 128; d0 += 4) {
    float w0 = ws[j][d0], w1 = ws[j][d0 + 1], w2 = ws[j][d0 + 2], w3 = ws[j][d0 + 3];
    #pragma unroll
    for (int r = 0; r < 8; ++r) {
      float4 xv = *(const float4*)&xs[tt0 + r][d0];
      float a = acc[r];
      a = fmaf(w0, xv.x, a);
      a = fmaf(w1, xv.y, a);
      a = fmaf(w2, xv.z, a);
      a = fmaf(w3, xv.w, a);
      acc[r] = a;
    }
  }
  #pragma unroll
  for (int r = 0; r < 8; ++r)
    Y[((size_t)b * 1024 + t0 + tt0 + r) * 32 + j] = acc[r];
}

// cf_proj[b,f,j] = sum_t cos(2*pi*f*t/1024) * Y[b,t,j]  via complex rotation
__global__ void fftT_kernel(const float* __restrict__ Y, const float* __restrict__ bfft,
                            float* __restrict__ cbuf) {
  __shared__ float ys[256 * 32];
  int b = blockIdx.y, fbase = blockIdx.x * 64;
  int tid = threadIdx.x;
  int fi = tid >> 3, jg = tid & 7, j0 = jg * 4;
  int f0 = fbase + fi * 2;
  const float TWO_PI_N = 6.283185307179586476925f / 1024.0f;
  float ca0, sa0, ca1, sa1;
  sincosf(TWO_PI_N * (float)f0, &sa0, &ca0);
  sincosf(TWO_PI_N * (float)(f0 + 1), &sa1, &ca1);
  float cr0 = 1.0f, ci0 = 0.0f, cr1 = 1.0f, ci1 = 0.0f;
  float4 acc0 = make_float4(0.f, 0.f, 0.f, 0.f);
  float4 acc1 = make_float4(0.f, 0.f, 0.f, 0.f);
  for (int chk = 0; chk < 4; ++chk) {
    __syncthreads();
    const float4* Yp = (const float4*)(Y + ((size_t)b * 1024 + chk * 256) * 32);
    for (int i = tid; i < 2048; i += 256) ((float4*)ys)[i] = Yp[i];
    __syncthreads();
    for (int tl = 0; tl < 256; ++tl) {
      float4 yv = *(const float4*)&ys[tl * 32 + j0];
      acc0.x = fmaf(cr0, yv.x, acc0.x);
      acc0.y = fmaf(cr0, yv.y, acc0.y);
      acc0.z = fmaf(cr0, yv.z, acc0.z);
      acc0.w = fmaf(cr0, yv.w, acc0.w);
      acc1.x = fmaf(cr1, yv.x, acc1.x);
      acc1.y = fmaf(cr1, yv.y, acc1.y);
      acc1.z = fmaf(cr1, yv.z, acc1.z);
      acc1.w = fmaf(cr1, yv.w, acc1.w);
      float nr0 = cr0 * ca0 - ci0 * sa0;
      float ni0 = cr0 * sa0 + ci0 * ca0;
      cr0 = nr0; ci0 = ni0;
      float nr1 = cr1 * ca1 - ci1 * sa1;
      float ni1 = cr1 * sa1 + ci1 * ca1;
      cr1 = nr1; ci1 = ni1;
    }
  }
  float b0 = bfft[j0], b1 = bfft[j0 + 1], b2 = bfft[j0 + 2], b3 = bfft[j0 + 3];
  float* cc0 = cbuf + ((size_t)b * 1024 + f0) * 352 + 256 + j0;
  cc0[0] = acc0.x + b0; cc0[1] = acc0.y + b1; cc0[2] = acc0.z + b2; cc0[3] = acc0.w + b3;
  float* cc1 = cbuf + ((size_t)b * 1024 + f0 + 1) * 352 + 256 + j0;
  cc1[0] = acc1.x + b0; cc1[1] = acc1.y + b1; cc1[2] = acc1.z + b2; cc1[3] = acc1.w + b3;
}

// ---------------------------------------------------------------------------
// final: out = cbuf @ w_fc + iq, then layernorm over DM
// ---------------------------------------------------------------------------
__global__ void fc_ln_kernel(const float* __restrict__ cbuf, const float* __restrict__ wfc,
                             const float* __restrict__ iq, float* __restrict__ out) {
  __shared__ float cs[16][352];
  __shared__ float os[16][128];
  int b = blockIdx.y, t0 = blockIdx.x * 16;
  int tid = threadIdx.x;
  for (int i = tid; i < 16 * 352; i += 256) {
    int r = i / 352, col = i % 352;
    cs[r][col] = cbuf[((size_t)b * 1024 + t0 + r) * 352 + col];
  }
  __syncthreads();
  int j = tid & 127, half = tid >> 7;
  float acc[8];
  #pragma unroll
  for (int k = 0; k < 8; ++k)
    acc[k] = iq[((size_t)b * 1024 + t0 + half * 8 + k) * 128 + j];
  for (int i = 0; i < 352; ++i) {
    float wv = wfc[i * 128 + j];
    #pragma unroll
    for (int k = 0; k < 8; ++k) acc[k] += cs[half * 8 + k][i] * wv;
  }
  #pragma unroll
  for (int k = 0; k < 8; ++k) os[half * 8 + k][j] = acc[k];
  __syncthreads();
  int wid = tid >> 6, lane = tid & 63;
  for (int rr = 0; rr < 4; ++rr) {
    int r = wid * 4 + rr;
    float x0 = os[r][lane], x1 = os[r][lane + 64];
    float s1 = x0 + x1;
    float s2 = x0 * x0 + x1 * x1;
    #pragma unroll
    for (int k = 32; k > 0; k >>= 1) {
      s1 += __shfl_xor(s1, k, 64);
      s2 += __shfl_xor(s2, k, 64);
    }
    float mean = s1 * (1.0f / 128.0f);
    float var = s2 * (1.0f / 128.0f) - mean * mean;
    float rstd = 1.0f / sqrtf(var + 1e-5f);
    float* op = out + ((size_t)b * 1024 + t0 + r) * 128;
    op[lane] = (x0 - mean) * rstd;
    op[lane + 64] = (x1 - mean) * rstd;
  }
}

// ---------------------------------------------------------------------------
extern "C" void kernel_launch(void* const* d_in, const int* in_sizes, int n_in,
                              void* d_out, int out_size, void* d_ws, size_t ws_size,
                              hipStream_t stream) {
  (void)in_sizes; (void)n_in; (void)out_size; (void)ws_size;
  const float* inQ = (const float*)d_in[0];
  const float* inK = (const float*)d_in[1];
  const float* inV = (const float*)d_in[2];
  const float *wq[5], *bq[5], *wk[5], *bk[5], *wv[5], *bv[5];
  for (int br = 0; br < 5; ++br) {
    wq[br] = (const float*)d_in[3 + br * 6 + 0];
    bq[br] = (const float*)d_in[3 + br * 6 + 1];
    wk[br] = (const float*)d_in[3 + br * 6 + 2];
    bk[br] = (const float*)d_in[3 + br * 6 + 3];
    wv[br] = (const float*)d_in[3 + br * 6 + 4];
    bv[br] = (const float*)d_in[3 + br * 6 + 5];
  }
  const float* wfft = (const float*)d_in[33];
  const float* bfft = (const float*)d_in[34];
  const float* wap  = (const float*)d_in[35];
  const float* bap  = (const float*)d_in[36];
  const float* was  = (const float*)d_in[37];
  const float* bas  = (const float*)d_in[38];
  const float* wfc  = (const float*)d_in[39];
  float* out = (float*)d_out;

  char* wsb = (char*)d_ws;
  size_t off = 0;
  auto alloc = [&](size_t bytes) -> void* {
    void* p = wsb + off;
    off += (bytes + 255) & ~(size_t)255;
    return p;
  };
  int*   pidx = (int*)  alloc((size_t)35840 * 4);
  float* qbuf = (float*)alloc((size_t)16 * 65536 * 4);
  float* kbuf = (float*)alloc((size_t)16 * 65536 * 4);
  float* vbuf = (float*)alloc((size_t)16 * 65536 * 4);
  float* cbuf = (float*)alloc((size_t)16 * 1024 * 352 * 4);
  float* fpart = (float*)alloc((size_t)32 * 4 * 1024 * 34 * 4);  // ~17 MiB scratch block
  float* Mbuf = (float*)alloc((size_t)32 * 1024 * 4);
  int*   sel  = (int*)  alloc((size_t)32 * 35 * 4);
  float* mvb  = (float*)alloc((size_t)16 * 1024 * 4);
  int*   idx6 = (int*)  alloc(64);
  float* w6   = (float*)alloc((size_t)16 * 6 * 4);
  // aliases into the fpart block (timeline-disjoint):
  float* ppart = fpart;                                              // prob partials (2.4MiB)
  float* cab   = fpart;                                              // auto ca (8MiB exactly)
  float* mpart = (float*)((char*)fpart + (size_t)8 * 1024 * 1024);   // corr partials (4MiB)
  float* Ybuf  = (float*)((char*)fpart + (size_t)12 * 1024 * 1024);  // fft Y (2MiB)

  mt_kernel<<<1, 256, 0, stream>>>(pidx);

  dim3 cgrid(32, 16);
  // branch 0: full attention
  conv3_kernel<<<cgrid, 256, 0, stream>>>(inQ, wq[0], bq[0], qbuf);
  conv3_kernel<<<cgrid, 256, 0, stream>>>(inK, wk[0], bk[0], kbuf);
  conv1_kernel<<<cgrid, 256, 0, stream>>>(inV, wv[0], bv[0], vbuf);
  attn_full_part<<<dim3(4, 4, 32), 256, 0, stream>>>(qbuf, kbuf, vbuf, fpart);
  attn_full_comb<<<128, 256, 0, stream>>>(fpart, cbuf);

  // branch 1: log-sparse
  conv3_kernel<<<cgrid, 256, 0, stream>>>(inQ, wq[1], bq[1], qbuf);
  conv3_kernel<<<cgrid, 256, 0, stream>>>(inK, wk[1], bk[1], kbuf);
  conv1_kernel<<<cgrid, 256, 0, stream>>>(inV, wv[1], bv[1], vbuf);
  attn_log_kernel<<<128, 256, 0, stream>>>(qbuf, kbuf, vbuf, cbuf);

  // branch 2: local window
  conv3_kernel<<<cgrid, 256, 0, stream>>>(inQ, wq[2], bq[2], qbuf);
  conv3_kernel<<<cgrid, 256, 0, stream>>>(inK, wk[2], bk[2], kbuf);
  conv1_kernel<<<cgrid, 256, 0, stream>>>(inV, wv[2], bv[2], vbuf);
  attn_loc_kernel<<<128, 256, 0, stream>>>(qbuf, kbuf, vbuf, cbuf);

  // branch 3: prob-sparse
  conv3_kernel<<<cgrid, 256, 0, stream>>>(inQ, wq[3], bq[3], qbuf);
  conv3_kernel<<<cgrid, 256, 0, stream>>>(inK, wk[3], bk[3], kbuf);
  conv1_kernel<<<cgrid, 256, 0, stream>>>(inV, wv[3], bv[3], vbuf);
  prob_m_kernel<<<128, 256, 0, stream>>>(qbuf, kbuf, pidx, Mbuf);
  top35_kernel<<<32, 256, 0, stream>>>(Mbuf, sel);
  prob_fill_kernel<<<32, 256, 0, stream>>>(vbuf, cbuf);
  prob_part_kernel<<<dim3(16, 32), 64, 0, stream>>>(qbuf, kbuf, vbuf, sel, ppart);
  prob_comb_kernel<<<18, 64, 0, stream>>>(ppart, sel, cbuf);

  // branch 4: autocorrelation
  conv3_kernel<<<cgrid, 256, 0, stream>>>(inQ, wq[4], bq[4], qbuf);
  conv3_kernel<<<cgrid, 256, 0, stream>>>(inK, wk[4], bk[4], kbuf);
  conv1_kernel<<<cgrid, 256, 0, stream>>>(inV, wv[4], bv[4], vbuf);
  auto_mv_part<<<dim3(64, 16), 256, 0, stream>>>(qbuf, kbuf, mpart);
  auto_mv_reduce<<<64, 256, 0, stream>>>(mpart, mvb);
  auto_top6_kernel<<<1, 256, 0, stream>>>(mvb, idx6, w6);
  auto_agg_kernel<<<dim3(64, 16), 256, 0, stream>>>(vbuf, inQ, wap, bap, idx6, w6, cab);
  auto_ma_kernel<<<dim3(64, 16), 256, 0, stream>>>(cab, was, bas, cbuf);

  // FFT branch (reordered projection; reads inQ directly)
  fftY_kernel<<<dim3(16, 16), 256, 0, stream>>>(inQ, wfft, Ybuf);
  fftT_kernel<<<dim3(16, 16), 256, 0, stream>>>(Ybuf, bfft, cbuf);

  // final projection + layernorm
  fc_ln_kernel<<<dim3(64, 16), 256, 0, stream>>>(cbuf, wfc, inQ, out);
}

// Round 4
// 1016.057 us; speedup vs baseline: 1.3567x; 1.0442x over previous
//
#include <hip/hip_runtime.h>
#include <hip/hip_bf16.h>
#include <math.h>

#define B_   16
#define L_   1024
#define SCALE_ 0.17677669529663687f   // 1/sqrt(32)

// ---------------------------------------------------------------------------
// MT19937 -> PROB_IDX (35840 draws of genrand_int32() & 1023, seed 0)
// ---------------------------------------------------------------------------
__global__ void mt_kernel(int* __restrict__ pidx) {
  __shared__ unsigned int mt[624];
  int tid = threadIdx.x;
  if (tid == 0) {
    unsigned int s = 0u;
    for (int i = 0; i < 624; ++i) {
      mt[i] = s;
      s = 1812433253u * (s ^ (s >> 30)) + (unsigned)(i + 1);
    }
  }
  __syncthreads();
  for (int blk = 0; blk < 58; ++blk) {
    unsigned int v = 0; bool act = tid < 227;
    if (act) {
      unsigned int y = (mt[tid] & 0x80000000u) | (mt[tid + 1] & 0x7fffffffu);
      v = mt[tid + 397] ^ (y >> 1) ^ ((y & 1u) ? 0x9908b0dfu : 0u);
    }
    __syncthreads();
    if (act) mt[tid] = v;
    __syncthreads();
    if (act) {
      int kk = 227 + tid;
      unsigned int y = (mt[kk] & 0x80000000u) | (mt[kk + 1] & 0x7fffffffu);
      v = mt[kk - 227] ^ (y >> 1) ^ ((y & 1u) ? 0x9908b0dfu : 0u);
    }
    __syncthreads();
    if (act) mt[227 + tid] = v;
    __syncthreads();
    bool act3 = tid < 169;
    if (act3) {
      int kk = 454 + tid;
      unsigned int y = (mt[kk] & 0x80000000u) | (mt[kk + 1] & 0x7fffffffu);
      v = mt[kk - 227] ^ (y >> 1) ^ ((y & 1u) ? 0x9908b0dfu : 0u);
    }
    __syncthreads();
    if (act3) mt[454 + tid] = v;
    __syncthreads();
    if (tid == 0) {
      unsigned int y = (mt[623] & 0x80000000u) | (mt[0] & 0x7fffffffu);
      mt[623] = mt[396] ^ (y >> 1) ^ ((y & 1u) ? 0x9908b0dfu : 0u);
    }
    __syncthreads();
    for (int i = tid; i < 624; i += 256) {
      int g = blk * 624 + i;
      if (g < 35840) {
        unsigned int y = mt[i];
        y ^= y >> 11;
        y ^= (y << 7) & 0x9d2c5680u;
        y ^= (y << 15) & 0xefc60000u;
        y ^= y >> 18;
        pidx[g] = (int)(y & 1023u);
      }
    }
    __syncthreads();
  }
}

// ---------------------------------------------------------------------------
// conv k=3, left pad 2. OUTPUT CHANNEL-MAJOR: out[b, c*1024 + t]
// ---------------------------------------------------------------------------
__global__ void conv3_kernel(const float* __restrict__ x, const float* __restrict__ w,
                             const float* __restrict__ bias, float* __restrict__ out) {
  __shared__ float xs[34][128];
  __shared__ float ws[64][97];
  int b = blockIdx.y, t0 = blockIdx.x * 32;
  int tid = threadIdx.x;
  for (int i = tid; i < 34 * 128; i += 256) {
    int r = i >> 7, d = i & 127;
    int t = t0 - 2 + r;
    xs[r][d] = (t >= 0) ? x[(size_t)b * 131072 + (size_t)t * 128 + d] : 0.0f;
  }
  int c = tid & 63, tt0 = (tid >> 6) * 8;
  float acc[8];
  float bvv = bias[c];
  #pragma unroll
  for (int j = 0; j < 8; ++j) acc[j] = bvv;
  for (int dc = 0; dc < 128; dc += 32) {
    __syncthreads();
    for (int i = tid; i < 64 * 96; i += 256) {
      int cc = i / 96, jj = i % 96;
      ws[cc][jj] = w[cc * 384 + dc * 3 + jj];
    }
    __syncthreads();
    for (int d0 = dc; d0 < dc + 32; d0 += 4) {
      float4 xr[10];
      #pragma unroll
      for (int r = 0; r < 10; ++r) xr[r] = *(const float4*)&xs[tt0 + r][d0];
      float wreg[12];
      #pragma unroll
      for (int jj = 0; jj < 12; ++jj) wreg[jj] = ws[c][(d0 - dc) * 3 + jj];
      #pragma unroll
      for (int j = 0; j < 8; ++j) {
        float a = acc[j];
        #pragma unroll
        for (int k = 0; k < 3; ++k) {
          float4 xv = xr[j + k];
          a = fmaf(wreg[0 + k], xv.x, a);
          a = fmaf(wreg[3 + k], xv.y, a);
          a = fmaf(wreg[6 + k], xv.z, a);
          a = fmaf(wreg[9 + k], xv.w, a);
        }
        acc[j] = a;
      }
    }
  }
  float* op = out + (size_t)b * 65536 + (size_t)c * 1024 + t0 + tt0;
  #pragma unroll
  for (int j = 0; j < 8; ++j) op[j] = acc[j];
}

// conv k=1. OUTPUT CHANNEL-MAJOR.
__global__ void conv1_kernel(const float* __restrict__ x, const float* __restrict__ w,
                             const float* __restrict__ bias, float* __restrict__ out) {
  __shared__ float xs[32][128];
  __shared__ float ws[64][129];
  int b = blockIdx.y, t0 = blockIdx.x * 32;
  int tid = threadIdx.x;
  for (int i = tid; i < 32 * 128; i += 256) {
    int r = i >> 7, d = i & 127;
    xs[r][d] = x[(size_t)b * 131072 + (size_t)(t0 + r) * 128 + d];
  }
  for (int i = tid; i < 64 * 128; i += 256) {
    ws[i >> 7][i & 127] = w[i];
  }
  __syncthreads();
  int c = tid & 63, tt0 = (tid >> 6) * 8;
  float acc[8];
  float bvv = bias[c];
  #pragma unroll
  for (int j = 0; j < 8; ++j) acc[j] = bvv;
  for (int d0 = 0; d0 < 128; d0 += 4) {
    float w0 = ws[c][d0], w1 = ws[c][d0 + 1], w2 = ws[c][d0 + 2], w3 = ws[c][d0 + 3];
    #pragma unroll
    for (int j = 0; j < 8; ++j) {
      float4 xv = *(const float4*)&xs[tt0 + j][d0];
      float a = acc[j];
      a = fmaf(w0, xv.x, a);
      a = fmaf(w1, xv.y, a);
      a = fmaf(w2, xv.z, a);
      a = fmaf(w3, xv.w, a);
      acc[j] = a;
    }
  }
  float* op = out + (size_t)b * 65536 + (size_t)c * 1024 + t0 + tt0;
  #pragma unroll
  for (int j = 0; j < 8; ++j) op[j] = acc[j];
}

// ---------------------------------------------------------------------------
// full attention, split-K partials, no-max softmax (scores bounded ~1)
// partial record: 36 floats (o[32], ssum, pad) for 16B alignment
// ---------------------------------------------------------------------------
__global__ void attn_full_part(const float* __restrict__ Q, const float* __restrict__ K,
                               const float* __restrict__ V, float* __restrict__ part,
                               int stile, int nstage) {
  __shared__ float Ks[128][32];
  __shared__ float Vs[128][32];
  int bh = blockIdx.z, b = bh >> 1, h = bh & 1;
  int l = blockIdx.x * 256 + threadIdx.x;
  int s0 = blockIdx.y * stile;
  const float* Kb = K + (size_t)b * 65536 + h * 32;
  const float* Vb = V + (size_t)b * 65536 + h * 32;
  const float* Qb = Q + (size_t)b * 65536 + h * 32 + (size_t)l * 64;
  float q[32];
  #pragma unroll
  for (int i = 0; i < 8; ++i) {
    float4 v4 = ((const float4*)Qb)[i];
    q[4*i] = v4.x; q[4*i+1] = v4.y; q[4*i+2] = v4.z; q[4*i+3] = v4.w;
  }
  float o[32];
  #pragma unroll
  for (int d = 0; d < 32; ++d) o[d] = 0.0f;
  float ssum = 0.0f;
  for (int st = 0; st < nstage; ++st) {
    __syncthreads();
    int sb = s0 + st * 128;
    for (int i = threadIdx.x; i < 1024; i += 256) {
      int r = i >> 3, d4 = i & 7;
      ((float4*)&Ks[r][0])[d4] = *(const float4*)(Kb + (size_t)(sb + r) * 64 + d4 * 4);
      ((float4*)&Vs[r][0])[d4] = *(const float4*)(Vb + (size_t)(sb + r) * 64 + d4 * 4);
    }
    __syncthreads();
    for (int s = 0; s < 128; ++s) {
      float a0 = 0, a1 = 0, a2 = 0, a3 = 0;
      const float4* kp = (const float4*)&Ks[s][0];
      #pragma unroll
      for (int i = 0; i < 8; ++i) {
        float4 kv = kp[i];
        a0 = fmaf(q[4*i], kv.x, a0);
        a1 = fmaf(q[4*i+1], kv.y, a1);
        a2 = fmaf(q[4*i+2], kv.z, a2);
        a3 = fmaf(q[4*i+3], kv.w, a3);
      }
      float p = __expf(((a0 + a1) + (a2 + a3)) * SCALE_);
      ssum += p;
      const float4* vp = (const float4*)&Vs[s][0];
      #pragma unroll
      for (int i = 0; i < 8; ++i) {
        float4 vv = vp[i];
        o[4*i]   = fmaf(p, vv.x, o[4*i]);
        o[4*i+1] = fmaf(p, vv.y, o[4*i+1]);
        o[4*i+2] = fmaf(p, vv.z, o[4*i+2]);
        o[4*i+3] = fmaf(p, vv.w, o[4*i+3]);
      }
    }
  }
  float* pp = part + (((size_t)bh * gridDim.y + blockIdx.y) * 1024 + l) * 36;
  #pragma unroll
  for (int i = 0; i < 8; ++i)
    ((float4*)pp)[i] = make_float4(o[4*i], o[4*i+1], o[4*i+2], o[4*i+3]);
  pp[32] = ssum;
}

__global__ void attn_full_comb(const float* __restrict__ part, float* __restrict__ cbuf,
                               int nsplit) {
  int idx = blockIdx.x * 256 + threadIdx.x;
  int bh = idx >> 10, l = idx & 1023;
  int b = bh >> 1, h = bh & 1;
  float S = 0.0f;
  float o[32];
  #pragma unroll
  for (int d = 0; d < 32; ++d) o[d] = 0.0f;
  for (int j = 0; j < nsplit; ++j) {
    const float* pp = part + (((size_t)bh * nsplit + j) * 1024 + l) * 36;
    S += pp[32];
    #pragma unroll
    for (int i = 0; i < 8; ++i) {
      float4 v4 = ((const float4*)pp)[i];
      o[4*i] += v4.x; o[4*i+1] += v4.y; o[4*i+2] += v4.z; o[4*i+3] += v4.w;
    }
  }
  float inv = 1.0f / S;
  float* cc = cbuf + ((size_t)b * 1024 + l) * 352 + 0 + h * 32;
  #pragma unroll
  for (int d = 0; d < 32; ++d) cc[d] = o[d] * inv;
}

// ---------------------------------------------------------------------------
// log-sparse attention, single-pass no-max
// ---------------------------------------------------------------------------
__global__ void attn_log_kernel(const float* __restrict__ Q, const float* __restrict__ K,
                                const float* __restrict__ V, float* __restrict__ cbuf) {
  int idx = blockIdx.x * 256 + threadIdx.x;
  int bh = idx >> 10, l = idx & 1023;
  int b = bh >> 1, h = bh & 1;
  const float* Qb = Q + (size_t)b * 65536 + h * 32;
  const float* Kb = K + (size_t)b * 65536 + h * 32;
  const float* Vb = V + (size_t)b * 65536 + h * 32;
  float q[32];
  #pragma unroll
  for (int i = 0; i < 8; ++i) {
    float4 v4 = ((const float4*)(Qb + (size_t)l * 64))[i];
    q[4*i] = v4.x; q[4*i+1] = v4.y; q[4*i+2] = v4.z; q[4*i+3] = v4.w;
  }
  float o[32];
  #pragma unroll
  for (int d = 0; d < 32; ++d) o[d] = 0.0f;
  float ssum = 0.0f;
  #pragma unroll
  for (int j = 0; j < 11; ++j) {
    int off = (j == 0) ? 0 : (1 << (j - 1));
    if (off <= l) {
      int s = l - off;
      const float4* kp = (const float4*)(Kb + (size_t)s * 64);
      float a0 = 0, a1 = 0, a2 = 0, a3 = 0;
      #pragma unroll
      for (int i = 0; i < 8; ++i) {
        float4 kv = kp[i];
        a0 = fmaf(q[4*i], kv.x, a0);
        a1 = fmaf(q[4*i+1], kv.y, a1);
        a2 = fmaf(q[4*i+2], kv.z, a2);
        a3 = fmaf(q[4*i+3], kv.w, a3);
      }
      float p = __expf(((a0 + a1) + (a2 + a3)) * SCALE_);
      ssum += p;
      const float4* vp = (const float4*)(Vb + (size_t)s * 64);
      #pragma unroll
      for (int i = 0; i < 8; ++i) {
        float4 vv = vp[i];
        o[4*i]   = fmaf(p, vv.x, o[4*i]);
        o[4*i+1] = fmaf(p, vv.y, o[4*i+1]);
        o[4*i+2] = fmaf(p, vv.z, o[4*i+2]);
        o[4*i+3] = fmaf(p, vv.w, o[4*i+3]);
      }
    }
  }
  float inv = 1.0f / ssum;
  float* cc = cbuf + ((size_t)b * 1024 + l) * 352 + 64 + h * 32;
  #pragma unroll
  for (int d = 0; d < 32; ++d) cc[d] = o[d] * inv;
}

// local-window attention, single-pass no-max
__global__ void attn_loc_kernel(const float* __restrict__ Q, const float* __restrict__ K,
                                const float* __restrict__ V, float* __restrict__ cbuf) {
  int idx = blockIdx.x * 256 + threadIdx.x;
  int bh = idx >> 10, l = idx & 1023;
  int b = bh >> 1, h = bh & 1;
  const float* Qb = Q + (size_t)b * 65536 + h * 32;
  const float* Kb = K + (size_t)b * 65536 + h * 32;
  const float* Vb = V + (size_t)b * 65536 + h * 32;
  float q[32];
  #pragma unroll
  for (int i = 0; i < 8; ++i) {
    float4 v4 = ((const float4*)(Qb + (size_t)l * 64))[i];
    q[4*i] = v4.x; q[4*i+1] = v4.y; q[4*i+2] = v4.z; q[4*i+3] = v4.w;
  }
  float o[32];
  #pragma unroll
  for (int d = 0; d < 32; ++d) o[d] = 0.0f;
  float ssum = 0.0f;
  int jlo = (l >= 31) ? 0 : (31 - l);
  for (int j = jlo; j < 32; ++j) {
    int s = l - 31 + j;
    const float4* kp = (const float4*)(Kb + (size_t)s * 64);
    float a0 = 0, a1 = 0, a2 = 0, a3 = 0;
    #pragma unroll
    for (int i = 0; i < 8; ++i) {
      float4 kv = kp[i];
      a0 = fmaf(q[4*i], kv.x, a0);
      a1 = fmaf(q[4*i+1], kv.y, a1);
      a2 = fmaf(q[4*i+2], kv.z, a2);
      a3 = fmaf(q[4*i+3], kv.w, a3);
    }
    float p = __expf(((a0 + a1) + (a2 + a3)) * SCALE_);
    ssum += p;
    const float4* vp = (const float4*)(Vb + (size_t)s * 64);
    #pragma unroll
    for (int i = 0; i < 8; ++i) {
      float4 vv = vp[i];
      o[4*i]   = fmaf(p, vv.x, o[4*i]);
      o[4*i+1] = fmaf(p, vv.y, o[4*i+1]);
      o[4*i+2] = fmaf(p, vv.z, o[4*i+2]);
      o[4*i+3] = fmaf(p, vv.w, o[4*i+3]);
    }
  }
  float inv = 1.0f / ssum;
  float* cc = cbuf + ((size_t)b * 1024 + l) * 352 + 128 + h * 32;
  #pragma unroll
  for (int d = 0; d < 32; ++d) cc[d] = o[d] * inv;
}

// ---------------------------------------------------------------------------
// prob-sparse attention
// ---------------------------------------------------------------------------
__global__ void prob_m_kernel(const float* __restrict__ Q, const float* __restrict__ K,
                              const int* __restrict__ pidx, float* __restrict__ Mbuf) {
  int idx = blockIdx.x * 256 + threadIdx.x;
  int bh = idx >> 10, l = idx & 1023;
  int b = bh >> 1, h = bh & 1;
  const float* Qb = Q + (size_t)b * 65536 + h * 32;
  const float* Kb = K + (size_t)b * 65536 + h * 32;
  float q[32];
  #pragma unroll
  for (int i = 0; i < 8; ++i) {
    float4 v4 = ((const float4*)(Qb + (size_t)l * 64))[i];
    q[4*i] = v4.x; q[4*i+1] = v4.y; q[4*i+2] = v4.z; q[4*i+3] = v4.w;
  }
  float mx = -1e30f, sm = 0.0f;
  for (int u = 0; u < 35; ++u) {
    int ki = pidx[l * 35 + u];
    const float4* kp = (const float4*)(Kb + (size_t)ki * 64);
    float a0 = 0, a1 = 0, a2 = 0, a3 = 0;
    #pragma unroll
    for (int i = 0; i < 8; ++i) {
      float4 kv = kp[i];
      a0 = fmaf(q[4*i], kv.x, a0);
      a1 = fmaf(q[4*i+1], kv.y, a1);
      a2 = fmaf(q[4*i+2], kv.z, a2);
      a3 = fmaf(q[4*i+3], kv.w, a3);
    }
    float s = (a0 + a1) + (a2 + a3);
    mx = fmaxf(mx, s);
    sm += s;
  }
  Mbuf[(size_t)bh * 1024 + l] = mx - sm * (1.0f / 1024.0f);
}

// single-wave register-resident top-35 (no barriers)
__global__ void top35_kernel(const float* __restrict__ Mbuf, int* __restrict__ sel) {
  int bh = blockIdx.x;
  int lane = threadIdx.x;        // 64 threads
  float v[16];
  const float* Mb = Mbuf + (size_t)bh * 1024 + lane * 16;
  #pragma unroll
  for (int k = 0; k < 16; ++k) v[k] = Mb[k];
  for (int it = 0; it < 35; ++it) {
    float bv = -1e30f; int bi = 0;
    #pragma unroll
    for (int k = 0; k < 16; ++k)
      if (v[k] > bv) { bv = v[k]; bi = k; }
    int gidx = lane * 16 + bi;
    #pragma unroll
    for (int off = 32; off > 0; off >>= 1) {
      float ov = __shfl_down(bv, off, 64);
      int og = __shfl_down(gidx, off, 64);
      if (ov > bv || (ov == bv && og < gidx)) { bv = ov; gidx = og; }
    }
    gidx = __shfl(gidx, 0, 64);
    if (lane == 0) sel[bh * 35 + it] = gidx;
    if ((gidx >> 4) == lane) {
      int kk = gidx & 15;
      #pragma unroll
      for (int k = 0; k < 16; ++k)
        if (k == kk) v[k] = -1e30f;
    }
  }
}

__global__ void prob_fill_kernel(const float* __restrict__ V, float* __restrict__ cbuf) {
  __shared__ float red[256];
  __shared__ float vm[32];
  int bh = blockIdx.x, b = bh >> 1, h = bh & 1;
  int tid = threadIdx.x;
  int d = tid & 31, ch = tid >> 5;
  const float* Vb = V + (size_t)b * 65536 + h * 32;
  float s = 0.0f;
  for (int ss = ch * 128; ss < ch * 128 + 128; ++ss) s += Vb[(size_t)ss * 64 + d];
  red[tid] = s;
  __syncthreads();
  if (ch == 0) {
    float t = 0.0f;
    for (int c = 0; c < 8; ++c) t += red[c * 32 + d];
    vm[d] = t * (1.0f / 1024.0f);
  }
  __syncthreads();
  for (int i = tid; i < 1024 * 32; i += 256) {
    int l = i >> 5, dd = i & 31;
    cbuf[((size_t)b * 1024 + l) * 352 + 192 + h * 32 + dd] = vm[dd];
  }
}

__global__ void prob_part_kernel(const float* __restrict__ Q, const float* __restrict__ K,
                                 const float* __restrict__ V, const int* __restrict__ sel,
                                 float* __restrict__ ppart) {
  int bh = blockIdx.y, b = bh >> 1, h = bh & 1;
  int sc0 = blockIdx.x * 64;
  int u = threadIdx.x;
  int uu = (u < 35) ? u : 34;
  int l = sel[bh * 35 + uu];
  const float* Qb = Q + (size_t)b * 65536 + h * 32;
  const float* Kb = K + (size_t)b * 65536 + h * 32;
  const float* Vb = V + (size_t)b * 65536 + h * 32;
  float q[32];
  #pragma unroll
  for (int i = 0; i < 8; ++i) {
    float4 v4 = ((const float4*)(Qb + (size_t)l * 64))[i];
    q[4*i] = v4.x; q[4*i+1] = v4.y; q[4*i+2] = v4.z; q[4*i+3] = v4.w;
  }
  float o[32];
  #pragma unroll
  for (int dd = 0; dd < 32; ++dd) o[dd] = 0.0f;
  float ssum = 0.0f;
  for (int s = sc0; s < sc0 + 64; ++s) {
    const float4* kp = (const float4*)(Kb + (size_t)s * 64);
    float a0 = 0, a1 = 0, a2 = 0, a3 = 0;
    #pragma unroll
    for (int i = 0; i < 8; ++i) {
      float4 kv = kp[i];
      a0 = fmaf(q[4*i], kv.x, a0);
      a1 = fmaf(q[4*i+1], kv.y, a1);
      a2 = fmaf(q[4*i+2], kv.z, a2);
      a3 = fmaf(q[4*i+3], kv.w, a3);
    }
    float p = __expf(((a0 + a1) + (a2 + a3)) * SCALE_);
    ssum += p;
    const float4* vp = (const float4*)(Vb + (size_t)s * 64);
    #pragma unroll
    for (int i = 0; i < 8; ++i) {
      float4 vv = vp[i];
      o[4*i]   = fmaf(p, vv.x, o[4*i]);
      o[4*i+1] = fmaf(p, vv.y, o[4*i+1]);
      o[4*i+2] = fmaf(p, vv.z, o[4*i+2]);
      o[4*i+3] = fmaf(p, vv.w, o[4*i+3]);
    }
  }
  if (u < 35) {
    float* pp = ppart + (((size_t)bh * 16 + blockIdx.x) * 35 + u) * 36;
    #pragma unroll
    for (int i = 0; i < 8; ++i)
      ((float4*)pp)[i] = make_float4(o[4*i], o[4*i+1], o[4*i+2], o[4*i+3]);
    pp[32] = ssum;
  }
}

__global__ void prob_comb_kernel(const float* __restrict__ ppart, const int* __restrict__ sel,
                                 float* __restrict__ cbuf) {
  int t = blockIdx.x * 64 + threadIdx.x;
  if (t >= 32 * 35) return;
  int bh = t / 35, u = t % 35;
  int b = bh >> 1, h = bh & 1;
  int l = sel[bh * 35 + u];
  float S = 0.0f;
  float o[32];
  #pragma unroll
  for (int d = 0; d < 32; ++d) o[d] = 0.0f;
  for (int j = 0; j < 16; ++j) {
    const float* pp = ppart + (((size_t)bh * 16 + j) * 35 + u) * 36;
    S += pp[32];
    #pragma unroll
    for (int i = 0; i < 8; ++i) {
      float4 v4 = ((const float4*)pp)[i];
      o[4*i] += v4.x; o[4*i+1] += v4.y; o[4*i+2] += v4.z; o[4*i+3] += v4.w;
    }
  }
  float inv = 1.0f / S;
  float* cc = cbuf + ((size_t)b * 1024 + l) * 352 + 192 + h * 32;
  #pragma unroll
  for (int d = 0; d < 32; ++d) cc[d] = o[d] * inv;
}

// ---------------------------------------------------------------------------
// autocorrelation: mv[b,tau] = (1/64) sum_{c,t} K[b,c,t] * Q[b,c,(t+tau)%1024]
// ---------------------------------------------------------------------------
__global__ void auto_mv_part(const float* __restrict__ Qa, const float* __restrict__ Ka,
                             float* __restrict__ part) {
  __shared__ float ks[1024];
  __shared__ float qs[2048];
  int c = blockIdx.x, b = blockIdx.y;
  int tid = threadIdx.x;
  const float* Qb = Qa + (size_t)b * 65536 + (size_t)c * 1024;
  const float* Kb = Ka + (size_t)b * 65536 + (size_t)c * 1024;
  ((float4*)ks)[tid] = ((const float4*)Kb)[tid];
  {
    float4 qv = ((const float4*)Qb)[tid];
    ((float4*)qs)[tid] = qv;
    ((float4*)qs)[tid + 256] = qv;
  }
  __syncthreads();
  int tau0 = tid * 4;
  float a0 = 0, a1 = 0, a2 = 0, a3 = 0;
  for (int t = 0; t < 1024; t += 8) {
    float4 q0 = *(const float4*)&ks[t];
    float4 q1 = *(const float4*)&ks[t + 4];
    const float* kp = &qs[t + tau0];
    float4 k0 = *(const float4*)(kp);
    float4 k1 = *(const float4*)(kp + 4);
    float4 k2 = *(const float4*)(kp + 8);
    a0 = fmaf(q0.x, k0.x, a0); a1 = fmaf(q0.x, k0.y, a1); a2 = fmaf(q0.x, k0.z, a2); a3 = fmaf(q0.x, k0.w, a3);
    a0 = fmaf(q0.y, k0.y, a0); a1 = fmaf(q0.y, k0.z, a1); a2 = fmaf(q0.y, k0.w, a2); a3 = fmaf(q0.y, k1.x, a3);
    a0 = fmaf(q0.z, k0.z, a0); a1 = fmaf(q0.z, k0.w, a1); a2 = fmaf(q0.z, k1.x, a2); a3 = fmaf(q0.z, k1.y, a3);
    a0 = fmaf(q0.w, k0.w, a0); a1 = fmaf(q0.w, k1.x, a1); a2 = fmaf(q0.w, k1.y, a2); a3 = fmaf(q0.w, k1.z, a3);
    a0 = fmaf(q1.x, k1.x, a0); a1 = fmaf(q1.x, k1.y, a1); a2 = fmaf(q1.x, k1.z, a2); a3 = fmaf(q1.x, k1.w, a3);
    a0 = fmaf(q1.y, k1.y, a0); a1 = fmaf(q1.y, k1.z, a1); a2 = fmaf(q1.y, k1.w, a2); a3 = fmaf(q1.y, k2.x, a3);
    a0 = fmaf(q1.z, k1.z, a0); a1 = fmaf(q1.z, k1.w, a1); a2 = fmaf(q1.z, k2.x, a2); a3 = fmaf(q1.z, k2.y, a3);
    a0 = fmaf(q1.w, k1.w, a0); a1 = fmaf(q1.w, k2.x, a1); a2 = fmaf(q1.w, k2.y, a2); a3 = fmaf(q1.w, k2.z, a3);
  }
  *(float4*)&part[(((size_t)b * 64 + c) << 10) + tau0] = make_float4(a0, a1, a2, a3);
}

__global__ void auto_mv_reduce(const float* __restrict__ part, float* __restrict__ mv) {
  int idx = blockIdx.x * 256 + threadIdx.x;
  int b = idx >> 10, tau = idx & 1023;
  float s = 0.0f;
  for (int c = 0; c < 64; ++c) s += part[(((size_t)b * 64 + c) << 10) + tau];
  mv[(size_t)b * 1024 + tau] = s * (1.0f / 64.0f);
}

// single-wave top-6 + per-batch softmax weights
__global__ void auto_top6_kernel(const float* __restrict__ mv, int* __restrict__ idx6,
                                 float* __restrict__ w6) {
  __shared__ int id6s[6];
  int lane = threadIdx.x;     // 64 threads
  float v[16];
  #pragma unroll
  for (int k = 0; k < 16; ++k) {
    int i = lane * 16 + k;
    float s = 0.0f;
    for (int b = 0; b < 16; ++b) s += mv[(size_t)b * 1024 + i];
    v[k] = s;
  }
  for (int it = 0; it < 6; ++it) {
    float bv = -1e30f; int bi = 0;
    #pragma unroll
    for (int k = 0; k < 16; ++k)
      if (v[k] > bv) { bv = v[k]; bi = k; }
    int gidx = lane * 16 + bi;
    #pragma unroll
    for (int off = 32; off > 0; off >>= 1) {
      float ov = __shfl_down(bv, off, 64);
      int og = __shfl_down(gidx, off, 64);
      if (ov > bv || (ov == bv && og < gidx)) { bv = ov; gidx = og; }
    }
    gidx = __shfl(gidx, 0, 64);
    if (lane == 0) { idx6[it] = gidx; id6s[it] = gidx; }
    if ((gidx >> 4) == lane) {
      int kk = gidx & 15;
      #pragma unroll
      for (int k = 0; k < 16; ++k)
        if (k == kk) v[k] = -1e30f;
    }
  }
  __syncthreads();
  if (lane < 16) {
    int b = lane;
    float vals[6]; float mx = -1e30f;
    #pragma unroll
    for (int j = 0; j < 6; ++j) { vals[j] = mv[(size_t)b * 1024 + id6s[j]]; mx = fmaxf(mx, vals[j]); }
    float s = 0.0f;
    #pragma unroll
    for (int j = 0; j < 6; ++j) { vals[j] = __expf(vals[j] - mx); s += vals[j]; }
    #pragma unroll
    for (int j = 0; j < 6; ++j) w6[b * 6 + j] = vals[j] / s;
  }
}

__global__ void auto_agg_kernel(const float* __restrict__ Va, const float* __restrict__ iq,
                                const float* __restrict__ wap, const float* __restrict__ bap,
                                const int* __restrict__ idx6, const float* __restrict__ w6,
                                float* __restrict__ ca) {
  __shared__ float aggs[16][64];
  __shared__ float w6s[6];
  __shared__ int id6[6];
  int b = blockIdx.y, t0 = blockIdx.x * 16;
  int tid = threadIdx.x;
  if (tid < 6) { w6s[tid] = w6[b * 6 + tid]; id6[tid] = idx6[tid]; }
  __syncthreads();
  const float* Vb = Va + (size_t)b * 65536;
  for (int i = tid; i < 1024; i += 256) {
    int tl = i >> 6, c = i & 63;
    int t = t0 + tl;
    float s = 0.0f;
    #pragma unroll
    for (int j = 0; j < 6; ++j)
      s += w6s[j] * Vb[(size_t)((t + id6[j]) & 1023) * 64 + c];
    aggs[tl][c] = s;
  }
  __syncthreads();
  int dm = tid & 127, tp = tid >> 7;
  float acc[8];
  #pragma unroll
  for (int r = 0; r < 8; ++r) {
    int t = t0 + tp * 8 + r;
    acc[r] = bap[dm] + iq[((size_t)b * 1024 + t) * 128 + dm];
  }
  for (int c = 0; c < 64; ++c) {
    float wv = wap[c * 128 + dm];
    #pragma unroll
    for (int r = 0; r < 8; ++r) acc[r] += aggs[tp * 8 + r][c] * wv;
  }
  #pragma unroll
  for (int r = 0; r < 8; ++r)
    ca[((size_t)b * 1024 + t0 + tp * 8 + r) * 128 + dm] = acc[r];
}

// moving-average detrend (k=25, edge-replicate, running window) + asize proj
__global__ void auto_ma_kernel(const float* __restrict__ ca, const float* __restrict__ was,
                               const float* __restrict__ bas, float* __restrict__ cbuf) {
  __shared__ float cas[40][128];
  __shared__ float diff[16][128];
  int b = blockIdx.y, t0 = blockIdx.x * 16;
  int tid = threadIdx.x;
  for (int i = tid; i < 40 * 128; i += 256) {
    int r = i >> 7, d = i & 127;
    int t = t0 - 12 + r;
    t = (t < 0) ? 0 : ((t > 1023) ? 1023 : t);
    cas[r][d] = ca[((size_t)b * 1024 + t) * 128 + d];
  }
  __syncthreads();
  int d = tid & 127, hf = tid >> 7;
  int tl0 = hf * 8;
  float s = 0.0f;
  #pragma unroll
  for (int w = 0; w < 25; ++w) s += cas[tl0 + w][d];
  #pragma unroll
  for (int k = 0; k < 8; ++k) {
    int tl = tl0 + k;
    diff[tl][d] = cas[tl + 12][d] - s * (1.0f / 25.0f);
    if (k < 7) s += cas[tl + 25][d] - cas[tl][d];
  }
  __syncthreads();
  int j = tid & 63, tq = tid >> 6;
  float acc[4];
  #pragma unroll
  for (int r = 0; r < 4; ++r) acc[r] = bas[j];
  for (int dd = 0; dd < 128; ++dd) {
    float wv = was[dd * 64 + j];
    #pragma unroll
    for (int r = 0; r < 4; ++r) acc[r] += diff[tq * 4 + r][dd] * wv;
  }
  #pragma unroll
  for (int r = 0; r < 4; ++r)
    cbuf[((size_t)b * 1024 + t0 + tq * 4 + r) * 352 + 288 + j] = acc[r];
}

// ---------------------------------------------------------------------------
// FFT branch: Y = X @ wfft, then cf_proj[f] = sum_t cos(2pi f t/1024) Y[t]
// symmetry: cf[1024-f] == cf[f]  ->  compute f=0..511 + f=512, mirror rest
// ---------------------------------------------------------------------------
__global__ void fftY_kernel(const float* __restrict__ x, const float* __restrict__ wfft,
                            float* __restrict__ Y) {
  __shared__ float xs[64][128];
  __shared__ float ws[32][129];
  int b = blockIdx.y, t0 = blockIdx.x * 64;
  int tid = threadIdx.x;
  for (int i = tid; i < 64 * 128; i += 256) {
    int r = i >> 7, d = i & 127;
    xs[r][d] = x[(size_t)b * 131072 + (size_t)(t0 + r) * 128 + d];
  }
  for (int i = tid; i < 4096; i += 256) {
    int d = i >> 5, j = i & 31;
    ws[j][d] = wfft[i];
  }
  __syncthreads();
  int j = tid & 31, tt0 = (tid >> 5) * 8;
  float acc[8];
  #pragma unroll
  for (int r = 0; r < 8; ++r) acc[r] = 0.0f;
  for (int d0 = 0; d0 < 128; d0 += 4) {
    float w0 = ws[j][d0], w1 = ws[j][d0 + 1], w2 = ws[j][d0 + 2], w3 = ws[j][d0 + 3];
    #pragma unroll
    for (int r = 0; r < 8; ++r) {
      float4 xv = *(const float4*)&xs[tt0 + r][d0];
      float a = acc[r];
      a = fmaf(w0, xv.x, a);
      a = fmaf(w1, xv.y, a);
      a = fmaf(w2, xv.z, a);
      a = fmaf(w3, xv.w, a);
      acc[r] = a;
    }
  }
  #pragma unroll
  for (int r = 0; r < 8; ++r)
    Y[((size_t)b * 1024 + t0 + tt0 + r) * 32 + j] = acc[r];
}

__global__ void fftT_kernel(const float* __restrict__ Y, const float* __restrict__ bfft,
                            float* __restrict__ cbuf) {
  __shared__ float ys[256 * 32];
  int b = blockIdx.y, fbase = blockIdx.x * 64;
  int tid = threadIdx.x;
  int fi = tid >> 3, jg = tid & 7, j0 = jg * 4;
  int f0 = fbase + fi * 2;
  const float TWO_PI_N = 6.283185307179586476925f / 1024.0f;
  float ca0, sa0, ca1, sa1;
  sincosf(TWO_PI_N * (float)f0, &sa0, &ca0);
  sincosf(TWO_PI_N * (float)(f0 + 1), &sa1, &ca1);
  float cr0 = 1.0f, ci0 = 0.0f, cr1 = 1.0f, ci1 = 0.0f;
  float4 acc0 = make_float4(0.f, 0.f, 0.f, 0.f);
  float4 acc1 = make_float4(0.f, 0.f, 0.f, 0.f);
  for (int chk = 0; chk < 4; ++chk) {
    __syncthreads();
    const float4* Yp = (const float4*)(Y + ((size_t)b * 1024 + chk * 256) * 32);
    for (int i = tid; i < 2048; i += 256) ((float4*)ys)[i] = Yp[i];
    __syncthreads();
    for (int tl = 0; tl < 256; ++tl) {
      float4 yv = *(const float4*)&ys[tl * 32 + j0];
      acc0.x = fmaf(cr0, yv.x, acc0.x);
      acc0.y = fmaf(cr0, yv.y, acc0.y);
      acc0.z = fmaf(cr0, yv.z, acc0.z);
      acc0.w = fmaf(cr0, yv.w, acc0.w);
      acc1.x = fmaf(cr1, yv.x, acc1.x);
      acc1.y = fmaf(cr1, yv.y, acc1.y);
      acc1.z = fmaf(cr1, yv.z, acc1.z);
      acc1.w = fmaf(cr1, yv.w, acc1.w);
      float nr0 = cr0 * ca0 - ci0 * sa0;
      float ni0 = cr0 * sa0 + ci0 * ca0;
      cr0 = nr0; ci0 = ni0;
      float nr1 = cr1 * ca1 - ci1 * sa1;
      float ni1 = cr1 * sa1 + ci1 * ca1;
      cr1 = nr1; ci1 = ni1;
    }
  }
  float b0 = bfft[j0], b1 = bfft[j0 + 1], b2 = bfft[j0 + 2], b3 = bfft[j0 + 3];
  float* cc0 = cbuf + ((size_t)b * 1024 + f0) * 352 + 256 + j0;
  cc0[0] = acc0.x + b0; cc0[1] = acc0.y + b1; cc0[2] = acc0.z + b2; cc0[3] = acc0.w + b3;
  float* cc1 = cbuf + ((size_t)b * 1024 + f0 + 1) * 352 + 256 + j0;
  cc1[0] = acc1.x + b0; cc1[1] = acc1.y + b1; cc1[2] = acc1.z + b2; cc1[3] = acc1.w + b3;
  if (f0 > 0) {
    float* cm0 = cbuf + ((size_t)b * 1024 + (1024 - f0)) * 352 + 256 + j0;
    cm0[0] = acc0.x + b0; cm0[1] = acc0.y + b1; cm0[2] = acc0.z + b2; cm0[3] = acc0.w + b3;
  }
  {
    float* cm1 = cbuf + ((size_t)b * 1024 + (1024 - f0 - 1)) * 352 + 256 + j0;
    cm1[0] = acc1.x + b0; cm1[1] = acc1.y + b1; cm1[2] = acc1.z + b2; cm1[3] = acc1.w + b3;
  }
}

// f=512: cos(pi t) = (-1)^t
__global__ void fft512_kernel(const float* __restrict__ Y, const float* __restrict__ bfft,
                              float* __restrict__ cbuf) {
  __shared__ float red[8][32];
  int b = blockIdx.x;
  int tid = threadIdx.x;
  int tc = tid >> 5, j = tid & 31;
  float s = 0.0f;
  for (int t = tc * 128; t < tc * 128 + 128; ++t) {
    float y = Y[((size_t)b * 1024 + t) * 32 + j];
    s += (t & 1) ? -y : y;
  }
  red[tc][j] = s;
  __syncthreads();
  if (tc == 0) {
    float t = 0.0f;
    for (int c = 0; c < 8; ++c) t += red[c][j];
    cbuf[((size_t)b * 1024 + 512) * 352 + 256 + j] = t + bfft[j];
  }
}

// ---------------------------------------------------------------------------
// final: out = cbuf @ w_fc + iq, then layernorm over DM
// ---------------------------------------------------------------------------
__global__ void fc_ln_kernel(const float* __restrict__ cbuf, const float* __restrict__ wfc,
                             const float* __restrict__ iq, float* __restrict__ out) {
  __shared__ float cs[16][352];
  __shared__ float os[16][128];
  int b = blockIdx.y, t0 = blockIdx.x * 16;
  int tid = threadIdx.x;
  for (int i = tid; i < 16 * 352; i += 256) {
    int r = i / 352, col = i % 352;
    cs[r][col] = cbuf[((size_t)b * 1024 + t0 + r) * 352 + col];
  }
  __syncthreads();
  int j = tid & 127, half = tid >> 7;
  float acc[8];
  #pragma unroll
  for (int k = 0; k < 8; ++k)
    acc[k] = iq[((size_t)b * 1024 + t0 + half * 8 + k) * 128 + j];
  for (int i = 0; i < 352; ++i) {
    float wv = wfc[i * 128 + j];
    #pragma unroll
    for (int k = 0; k < 8; ++k) acc[k] += cs[half * 8 + k][i] * wv;
  }
  #pragma unroll
  for (int k = 0; k < 8; ++k) os[half * 8 + k][j] = acc[k];
  __syncthreads();
  int wid = tid >> 6, lane = tid & 63;
  for (int rr = 0; rr < 4; ++rr) {
    int r = wid * 4 + rr;
    float x0 = os[r][lane], x1 = os[r][lane + 64];
    float s1 = x0 + x1;
    float s2 = x0 * x0 + x1 * x1;
    #pragma unroll
    for (int k = 32; k > 0; k >>= 1) {
      s1 += __shfl_xor(s1, k, 64);
      s2 += __shfl_xor(s2, k, 64);
    }
    float mean = s1 * (1.0f / 128.0f);
    float var = s2 * (1.0f / 128.0f) - mean * mean;
    float rstd = 1.0f / sqrtf(var + 1e-5f);
    float* op = out + ((size_t)b * 1024 + t0 + r) * 128;
    op[lane] = (x0 - mean) * rstd;
    op[lane + 64] = (x1 - mean) * rstd;
  }
}

// ---------------------------------------------------------------------------
extern "C" void kernel_launch(void* const* d_in, const int* in_sizes, int n_in,
                              void* d_out, int out_size, void* d_ws, size_t ws_size,
                              hipStream_t stream) {
  (void)in_sizes; (void)n_in; (void)out_size;
  const float* inQ = (const float*)d_in[0];
  const float* inK = (const float*)d_in[1];
  const float* inV = (const float*)d_in[2];
  const float *wq[5], *bq[5], *wk[5], *bk[5], *wv[5], *bv[5];
  for (int br = 0; br < 5; ++br) {
    wq[br] = (const float*)d_in[3 + br * 6 + 0];
    bq[br] = (const float*)d_in[3 + br * 6 + 1];
    wk[br] = (const float*)d_in[3 + br * 6 + 2];
    bk[br] = (const float*)d_in[3 + br * 6 + 3];
    wv[br] = (const float*)d_in[3 + br * 6 + 4];
    bv[br] = (const float*)d_in[3 + br * 6 + 5];
  }
  const float* wfft = (const float*)d_in[33];
  const float* bfft = (const float*)d_in[34];
  const float* wap  = (const float*)d_in[35];
  const float* bap  = (const float*)d_in[36];
  const float* was  = (const float*)d_in[37];
  const float* bas  = (const float*)d_in[38];
  const float* wfc  = (const float*)d_in[39];
  float* out = (float*)d_out;

  // full-attn split factor: 8 if workspace allows (~74 MiB), else proven 4
  int nsplit = (ws_size >= (size_t)76 * 1024 * 1024) ? 8 : 4;
  int stile = 1024 / nsplit;
  int nstage = stile / 128;

  char* wsb = (char*)d_ws;
  size_t off = 0;
  auto alloc = [&](size_t bytes) -> void* {
    void* p = wsb + off;
    off += (bytes + 255) & ~(size_t)255;
    return p;
  };
  int*   pidx = (int*)  alloc((size_t)35840 * 4);
  float* qbuf = (float*)alloc((size_t)16 * 65536 * 4);
  float* kbuf = (float*)alloc((size_t)16 * 65536 * 4);
  float* vbuf = (float*)alloc((size_t)16 * 65536 * 4);
  float* cbuf = (float*)alloc((size_t)16 * 1024 * 352 * 4);
  float* fpart = (float*)alloc((size_t)32 * nsplit * 1024 * 36 * 4);
  float* Mbuf = (float*)alloc((size_t)32 * 1024 * 4);
  int*   sel  = (int*)  alloc((size_t)32 * 35 * 4);
  float* mvb  = (float*)alloc((size_t)16 * 1024 * 4);
  int*   idx6 = (int*)  alloc(64);
  float* w6   = (float*)alloc((size_t)16 * 6 * 4);
  // aliases into fpart (timeline-disjoint):
  float* ppart = fpart;                                              // prob partials (2.6MiB)
  float* cab   = fpart;                                              // auto ca (8MiB)
  float* mpart = (float*)((char*)fpart + (size_t)8 * 1024 * 1024);   // corr partials (4MiB)
  float* Ybuf  = (float*)((char*)fpart + (size_t)12 * 1024 * 1024);  // fft Y (2MiB)

  mt_kernel<<<1, 256, 0, stream>>>(pidx);

  dim3 cgrid(32, 16);
  // branch 0: full attention
  conv3_kernel<<<cgrid, 256, 0, stream>>>(inQ, wq[0], bq[0], qbuf);
  conv3_kernel<<<cgrid, 256, 0, stream>>>(inK, wk[0], bk[0], kbuf);
  conv1_kernel<<<cgrid, 256, 0, stream>>>(inV, wv[0], bv[0], vbuf);
  attn_full_part<<<dim3(4, nsplit, 32), 256, 0, stream>>>(qbuf, kbuf, vbuf, fpart, stile, nstage);
  attn_full_comb<<<128, 256, 0, stream>>>(fpart, cbuf, nsplit);

  // branch 1: log-sparse
  conv3_kernel<<<cgrid, 256, 0, stream>>>(inQ, wq[1], bq[1], qbuf);
  conv3_kernel<<<cgrid, 256, 0, stream>>>(inK, wk[1], bk[1], kbuf);
  conv1_kernel<<<cgrid, 256, 0, stream>>>(inV, wv[1], bv[1], vbuf);
  attn_log_kernel<<<128, 256, 0, stream>>>(qbuf, kbuf, vbuf, cbuf);

  // branch 2: local window
  conv3_kernel<<<cgrid, 256, 0, stream>>>(inQ, wq[2], bq[2], qbuf);
  conv3_kernel<<<cgrid, 256, 0, stream>>>(inK, wk[2], bk[2], kbuf);
  conv1_kernel<<<cgrid, 256, 0, stream>>>(inV, wv[2], bv[2], vbuf);
  attn_loc_kernel<<<128, 256, 0, stream>>>(qbuf, kbuf, vbuf, cbuf);

  // branch 3: prob-sparse
  conv3_kernel<<<cgrid, 256, 0, stream>>>(inQ, wq[3], bq[3], qbuf);
  conv3_kernel<<<cgrid, 256, 0, stream>>>(inK, wk[3], bk[3], kbuf);
  conv1_kernel<<<cgrid, 256, 0, stream>>>(inV, wv[3], bv[3], vbuf);
  prob_m_kernel<<<128, 256, 0, stream>>>(qbuf, kbuf, pidx, Mbuf);
  top35_kernel<<<32, 64, 0, stream>>>(Mbuf, sel);
  prob_fill_kernel<<<32, 256, 0, stream>>>(vbuf, cbuf);
  prob_part_kernel<<<dim3(16, 32), 64, 0, stream>>>(qbuf, kbuf, vbuf, sel, ppart);
  prob_comb_kernel<<<18, 64, 0, stream>>>(ppart, sel, cbuf);

  // branch 4: autocorrelation
  conv3_kernel<<<cgrid, 256, 0, stream>>>(inQ, wq[4], bq[4], qbuf);
  conv3_kernel<<<cgrid, 256, 0, stream>>>(inK, wk[4], bk[4], kbuf);
  conv1_kernel<<<cgrid, 256, 0, stream>>>(inV, wv[4], bv[4], vbuf);
  auto_mv_part<<<dim3(64, 16), 256, 0, stream>>>(qbuf, kbuf, mpart);
  auto_mv_reduce<<<64, 256, 0, stream>>>(mpart, mvb);
  auto_top6_kernel<<<1, 64, 0, stream>>>(mvb, idx6, w6);
  auto_agg_kernel<<<dim3(64, 16), 256, 0, stream>>>(vbuf, inQ, wap, bap, idx6, w6, cab);
  auto_ma_kernel<<<dim3(64, 16), 256, 0, stream>>>(cab, was, bas, cbuf);

  // FFT branch (mirror symmetry: compute f=0..512 only)
  fftY_kernel<<<dim3(16, 16), 256, 0, stream>>>(inQ, wfft, Ybuf);
  fftT_kernel<<<dim3(8, 16), 256, 0, stream>>>(Ybuf, bfft, cbuf);
  fft512_kernel<<<16, 256, 0, stream>>>(Ybuf, bfft, cbuf);

  // final projection + layernorm
  fc_ln_kernel<<<dim3(64, 16), 256, 0, stream>>>(cbuf, wfc, inQ, out);
}

// Round 5
// 956.532 us; speedup vs baseline: 1.4411x; 1.0622x over previous
//
#include <hip/hip_runtime.h>
#include <hip/hip_bf16.h>
#include <math.h>

#define B_   16
#define L_   1024
#define SCALE_ 0.17677669529663687f   // 1/sqrt(32)

// ---------------------------------------------------------------------------
// MT19937 -> PROB_IDX (35840 draws of genrand_int32() & 1023, seed 0)
// register-chain twist: new[k]=new[k-227]^g(old[k],old[k+1]); 3 barriers/block
// ---------------------------------------------------------------------------
__global__ void mt_kernel(int* __restrict__ pidx) {
  __shared__ unsigned int mt[624];
  int tid = threadIdx.x;   // 256
  if (tid == 0) {
    unsigned int s = 0u;
    for (int i = 0; i < 624; ++i) {
      mt[i] = s;
      s = 1812433253u * (s ^ (s >> 30)) + (unsigned)(i + 1);
    }
  }
  __syncthreads();
  const unsigned int HI = 0x80000000u, LO = 0x7fffffffu, MM = 0x9908b0dfu;
  for (int blk = 0; blk < 58; ++blk) {
    unsigned int n0 = 0, n1 = 0, n2 = 0, old623 = 0;
    bool a0 = tid < 227, a2 = tid < 169;
    if (a0) {
      unsigned int y0 = (mt[tid] & HI) | (mt[tid + 1] & LO);
      n0 = mt[tid + 397] ^ (y0 >> 1) ^ ((y0 & 1u) ? MM : 0u);
      unsigned int y1 = (mt[tid + 227] & HI) | (mt[tid + 228] & LO);
      n1 = n0 ^ (y1 >> 1) ^ ((y1 & 1u) ? MM : 0u);
      if (a2) {
        unsigned int y2 = (mt[tid + 454] & HI) | (mt[tid + 455] & LO);
        n2 = n1 ^ (y2 >> 1) ^ ((y2 & 1u) ? MM : 0u);
      }
      if (tid == 169) old623 = mt[623];
    }
    __syncthreads();   // B1: all old-state reads complete
    if (a0) {
      mt[tid] = n0;
      mt[tid + 227] = n1;
      if (a2) mt[tid + 454] = n2;
    }
    __syncthreads();   // B2: new[0..623) visible
    if (tid == 169) {  // k=623: new[623] = new[396] ^ g(old[623], new[0]); n1 == new[396]
      unsigned int y = (old623 & HI) | (mt[0] & LO);
      mt[623] = n1 ^ (y >> 1) ^ ((y & 1u) ? MM : 0u);
    }
    __syncthreads();   // B3
    for (int i = tid; i < 624; i += 256) {
      int g = blk * 624 + i;
      if (g < 35840) {
        unsigned int y = mt[i];
        y ^= y >> 11;
        y ^= (y << 7) & 0x9d2c5680u;
        y ^= (y << 15) & 0xefc60000u;
        y ^= y >> 18;
        pidx[g] = (int)(y & 1023u);
      }
    }
    // no barrier needed: next iteration's writes happen only after its own B1,
    // which every thread reaches only after finishing these reads
  }
}

// ---------------------------------------------------------------------------
// conv k=3, left pad 2. OUTPUT CHANNEL-MAJOR: out[b, c*1024 + t]
// ---------------------------------------------------------------------------
__global__ void conv3_kernel(const float* __restrict__ x, const float* __restrict__ w,
                             const float* __restrict__ bias, float* __restrict__ out) {
  __shared__ float xs[34][128];
  __shared__ float ws[64][97];
  int b = blockIdx.y, t0 = blockIdx.x * 32;
  int tid = threadIdx.x;
  for (int i = tid; i < 34 * 128; i += 256) {
    int r = i >> 7, d = i & 127;
    int t = t0 - 2 + r;
    xs[r][d] = (t >= 0) ? x[(size_t)b * 131072 + (size_t)t * 128 + d] : 0.0f;
  }
  int c = tid & 63, tt0 = (tid >> 6) * 8;
  float acc[8];
  float bvv = bias[c];
  #pragma unroll
  for (int j = 0; j < 8; ++j) acc[j] = bvv;
  for (int dc = 0; dc < 128; dc += 32) {
    __syncthreads();
    for (int i = tid; i < 64 * 96; i += 256) {
      int cc = i / 96, jj = i % 96;
      ws[cc][jj] = w[cc * 384 + dc * 3 + jj];
    }
    __syncthreads();
    for (int d0 = dc; d0 < dc + 32; d0 += 4) {
      float4 xr[10];
      #pragma unroll
      for (int r = 0; r < 10; ++r) xr[r] = *(const float4*)&xs[tt0 + r][d0];
      float wreg[12];
      #pragma unroll
      for (int jj = 0; jj < 12; ++jj) wreg[jj] = ws[c][(d0 - dc) * 3 + jj];
      #pragma unroll
      for (int j = 0; j < 8; ++j) {
        float a = acc[j];
        #pragma unroll
        for (int k = 0; k < 3; ++k) {
          float4 xv = xr[j + k];
          a = fmaf(wreg[0 + k], xv.x, a);
          a = fmaf(wreg[3 + k], xv.y, a);
          a = fmaf(wreg[6 + k], xv.z, a);
          a = fmaf(wreg[9 + k], xv.w, a);
        }
        acc[j] = a;
      }
    }
  }
  float* op = out + (size_t)b * 65536 + (size_t)c * 1024 + t0 + tt0;
  #pragma unroll
  for (int j = 0; j < 8; ++j) op[j] = acc[j];
}

// conv k=1. OUTPUT CHANNEL-MAJOR.
__global__ void conv1_kernel(const float* __restrict__ x, const float* __restrict__ w,
                             const float* __restrict__ bias, float* __restrict__ out) {
  __shared__ float xs[32][128];
  __shared__ float ws[64][129];
  int b = blockIdx.y, t0 = blockIdx.x * 32;
  int tid = threadIdx.x;
  for (int i = tid; i < 32 * 128; i += 256) {
    int r = i >> 7, d = i & 127;
    xs[r][d] = x[(size_t)b * 131072 + (size_t)(t0 + r) * 128 + d];
  }
  for (int i = tid; i < 64 * 128; i += 256) {
    ws[i >> 7][i & 127] = w[i];
  }
  __syncthreads();
  int c = tid & 63, tt0 = (tid >> 6) * 8;
  float acc[8];
  float bvv = bias[c];
  #pragma unroll
  for (int j = 0; j < 8; ++j) acc[j] = bvv;
  for (int d0 = 0; d0 < 128; d0 += 4) {
    float w0 = ws[c][d0], w1 = ws[c][d0 + 1], w2 = ws[c][d0 + 2], w3 = ws[c][d0 + 3];
    #pragma unroll
    for (int j = 0; j < 8; ++j) {
      float4 xv = *(const float4*)&xs[tt0 + j][d0];
      float a = acc[j];
      a = fmaf(w0, xv.x, a);
      a = fmaf(w1, xv.y, a);
      a = fmaf(w2, xv.z, a);
      a = fmaf(w3, xv.w, a);
      acc[j] = a;
    }
  }
  float* op = out + (size_t)b * 65536 + (size_t)c * 1024 + t0 + tt0;
  #pragma unroll
  for (int j = 0; j < 8; ++j) op[j] = acc[j];
}

// ---------------------------------------------------------------------------
// full attention, split-K partials, no-max softmax (scores bounded ~1)
// ---------------------------------------------------------------------------
__global__ void attn_full_part(const float* __restrict__ Q, const float* __restrict__ K,
                               const float* __restrict__ V, float* __restrict__ part,
                               int stile, int nstage) {
  __shared__ float Ks[128][32];
  __shared__ float Vs[128][32];
  int bh = blockIdx.z, b = bh >> 1, h = bh & 1;
  int l = blockIdx.x * 256 + threadIdx.x;
  int s0 = blockIdx.y * stile;
  const float* Kb = K + (size_t)b * 65536 + h * 32;
  const float* Vb = V + (size_t)b * 65536 + h * 32;
  const float* Qb = Q + (size_t)b * 65536 + h * 32 + (size_t)l * 64;
  float q[32];
  #pragma unroll
  for (int i = 0; i < 8; ++i) {
    float4 v4 = ((const float4*)Qb)[i];
    q[4*i] = v4.x; q[4*i+1] = v4.y; q[4*i+2] = v4.z; q[4*i+3] = v4.w;
  }
  float o[32];
  #pragma unroll
  for (int d = 0; d < 32; ++d) o[d] = 0.0f;
  float ssum = 0.0f;
  for (int st = 0; st < nstage; ++st) {
    __syncthreads();
    int sb = s0 + st * 128;
    for (int i = threadIdx.x; i < 1024; i += 256) {
      int r = i >> 3, d4 = i & 7;
      ((float4*)&Ks[r][0])[d4] = *(const float4*)(Kb + (size_t)(sb + r) * 64 + d4 * 4);
      ((float4*)&Vs[r][0])[d4] = *(const float4*)(Vb + (size_t)(sb + r) * 64 + d4 * 4);
    }
    __syncthreads();
    for (int s = 0; s < 128; ++s) {
      float a0 = 0, a1 = 0, a2 = 0, a3 = 0;
      const float4* kp = (const float4*)&Ks[s][0];
      #pragma unroll
      for (int i = 0; i < 8; ++i) {
        float4 kv = kp[i];
        a0 = fmaf(q[4*i], kv.x, a0);
        a1 = fmaf(q[4*i+1], kv.y, a1);
        a2 = fmaf(q[4*i+2], kv.z, a2);
        a3 = fmaf(q[4*i+3], kv.w, a3);
      }
      float p = __expf(((a0 + a1) + (a2 + a3)) * SCALE_);
      ssum += p;
      const float4* vp = (const float4*)&Vs[s][0];
      #pragma unroll
      for (int i = 0; i < 8; ++i) {
        float4 vv = vp[i];
        o[4*i]   = fmaf(p, vv.x, o[4*i]);
        o[4*i+1] = fmaf(p, vv.y, o[4*i+1]);
        o[4*i+2] = fmaf(p, vv.z, o[4*i+2]);
        o[4*i+3] = fmaf(p, vv.w, o[4*i+3]);
      }
    }
  }
  float* pp = part + (((size_t)bh * gridDim.y + blockIdx.y) * 1024 + l) * 36;
  #pragma unroll
  for (int i = 0; i < 8; ++i)
    ((float4*)pp)[i] = make_float4(o[4*i], o[4*i+1], o[4*i+2], o[4*i+3]);
  pp[32] = ssum;
}

__global__ void attn_full_comb(const float* __restrict__ part, float* __restrict__ cbuf,
                               int nsplit) {
  int idx = blockIdx.x * 128 + threadIdx.x;
  int bh = idx >> 10, l = idx & 1023;
  int b = bh >> 1, h = bh & 1;
  float S = 0.0f;
  float o[32];
  #pragma unroll
  for (int d = 0; d < 32; ++d) o[d] = 0.0f;
  for (int j = 0; j < nsplit; ++j) {
    const float* pp = part + (((size_t)bh * nsplit + j) * 1024 + l) * 36;
    S += pp[32];
    #pragma unroll
    for (int i = 0; i < 8; ++i) {
      float4 v4 = ((const float4*)pp)[i];
      o[4*i] += v4.x; o[4*i+1] += v4.y; o[4*i+2] += v4.z; o[4*i+3] += v4.w;
    }
  }
  float inv = 1.0f / S;
  float* cc = cbuf + ((size_t)b * 1024 + l) * 352 + 0 + h * 32;
  #pragma unroll
  for (int d = 0; d < 32; ++d) cc[d] = o[d] * inv;
}

// ---------------------------------------------------------------------------
// log-sparse attention, single-pass no-max
// ---------------------------------------------------------------------------
__global__ void attn_log_kernel(const float* __restrict__ Q, const float* __restrict__ K,
                                const float* __restrict__ V, float* __restrict__ cbuf) {
  int idx = blockIdx.x * 128 + threadIdx.x;
  int bh = idx >> 10, l = idx & 1023;
  int b = bh >> 1, h = bh & 1;
  const float* Qb = Q + (size_t)b * 65536 + h * 32;
  const float* Kb = K + (size_t)b * 65536 + h * 32;
  const float* Vb = V + (size_t)b * 65536 + h * 32;
  float q[32];
  #pragma unroll
  for (int i = 0; i < 8; ++i) {
    float4 v4 = ((const float4*)(Qb + (size_t)l * 64))[i];
    q[4*i] = v4.x; q[4*i+1] = v4.y; q[4*i+2] = v4.z; q[4*i+3] = v4.w;
  }
  float o[32];
  #pragma unroll
  for (int d = 0; d < 32; ++d) o[d] = 0.0f;
  float ssum = 0.0f;
  #pragma unroll
  for (int j = 0; j < 11; ++j) {
    int off = (j == 0) ? 0 : (1 << (j - 1));
    if (off <= l) {
      int s = l - off;
      const float4* kp = (const float4*)(Kb + (size_t)s * 64);
      float a0 = 0, a1 = 0, a2 = 0, a3 = 0;
      #pragma unroll
      for (int i = 0; i < 8; ++i) {
        float4 kv = kp[i];
        a0 = fmaf(q[4*i], kv.x, a0);
        a1 = fmaf(q[4*i+1], kv.y, a1);
        a2 = fmaf(q[4*i+2], kv.z, a2);
        a3 = fmaf(q[4*i+3], kv.w, a3);
      }
      float p = __expf(((a0 + a1) + (a2 + a3)) * SCALE_);
      ssum += p;
      const float4* vp = (const float4*)(Vb + (size_t)s * 64);
      #pragma unroll
      for (int i = 0; i < 8; ++i) {
        float4 vv = vp[i];
        o[4*i]   = fmaf(p, vv.x, o[4*i]);
        o[4*i+1] = fmaf(p, vv.y, o[4*i+1]);
        o[4*i+2] = fmaf(p, vv.z, o[4*i+2]);
        o[4*i+3] = fmaf(p, vv.w, o[4*i+3]);
      }
    }
  }
  float inv = 1.0f / ssum;
  float* cc = cbuf + ((size_t)b * 1024 + l) * 352 + 64 + h * 32;
  #pragma unroll
  for (int d = 0; d < 32; ++d) cc[d] = o[d] * inv;
}

// local-window attention, single-pass no-max
__global__ void attn_loc_kernel(const float* __restrict__ Q, const float* __restrict__ K,
                                const float* __restrict__ V, float* __restrict__ cbuf) {
  int idx = blockIdx.x * 128 + threadIdx.x;
  int bh = idx >> 10, l = idx & 1023;
  int b = bh >> 1, h = bh & 1;
  const float* Qb = Q + (size_t)b * 65536 + h * 32;
  const float* Kb = K + (size_t)b * 65536 + h * 32;
  const float* Vb = V + (size_t)b * 65536 + h * 32;
  float q[32];
  #pragma unroll
  for (int i = 0; i < 8; ++i) {
    float4 v4 = ((const float4*)(Qb + (size_t)l * 64))[i];
    q[4*i] = v4.x; q[4*i+1] = v4.y; q[4*i+2] = v4.z; q[4*i+3] = v4.w;
  }
  float o[32];
  #pragma unroll
  for (int d = 0; d < 32; ++d) o[d] = 0.0f;
  float ssum = 0.0f;
  int jlo = (l >= 31) ? 0 : (31 - l);
  for (int j = jlo; j < 32; ++j) {
    int s = l - 31 + j;
    const float4* kp = (const float4*)(Kb + (size_t)s * 64);
    float a0 = 0, a1 = 0, a2 = 0, a3 = 0;
    #pragma unroll
    for (int i = 0; i < 8; ++i) {
      float4 kv = kp[i];
      a0 = fmaf(q[4*i], kv.x, a0);
      a1 = fmaf(q[4*i+1], kv.y, a1);
      a2 = fmaf(q[4*i+2], kv.z, a2);
      a3 = fmaf(q[4*i+3], kv.w, a3);
    }
    float p = __expf(((a0 + a1) + (a2 + a3)) * SCALE_);
    ssum += p;
    const float4* vp = (const float4*)(Vb + (size_t)s * 64);
    #pragma unroll
    for (int i = 0; i < 8; ++i) {
      float4 vv = vp[i];
      o[4*i]   = fmaf(p, vv.x, o[4*i]);
      o[4*i+1] = fmaf(p, vv.y, o[4*i+1]);
      o[4*i+2] = fmaf(p, vv.z, o[4*i+2]);
      o[4*i+3] = fmaf(p, vv.w, o[4*i+3]);
    }
  }
  float inv = 1.0f / ssum;
  float* cc = cbuf + ((size_t)b * 1024 + l) * 352 + 128 + h * 32;
  #pragma unroll
  for (int d = 0; d < 32; ++d) cc[d] = o[d] * inv;
}

// ---------------------------------------------------------------------------
// prob-sparse attention
// ---------------------------------------------------------------------------
__global__ void prob_m_kernel(const float* __restrict__ Q, const float* __restrict__ K,
                              const int* __restrict__ pidx, float* __restrict__ Mbuf) {
  int idx = blockIdx.x * 128 + threadIdx.x;
  int bh = idx >> 10, l = idx & 1023;
  int b = bh >> 1, h = bh & 1;
  const float* Qb = Q + (size_t)b * 65536 + h * 32;
  const float* Kb = K + (size_t)b * 65536 + h * 32;
  float q[32];
  #pragma unroll
  for (int i = 0; i < 8; ++i) {
    float4 v4 = ((const float4*)(Qb + (size_t)l * 64))[i];
    q[4*i] = v4.x; q[4*i+1] = v4.y; q[4*i+2] = v4.z; q[4*i+3] = v4.w;
  }
  float mx = -1e30f, sm = 0.0f;
  for (int u = 0; u < 35; ++u) {
    int ki = pidx[l * 35 + u];
    const float4* kp = (const float4*)(Kb + (size_t)ki * 64);
    float a0 = 0, a1 = 0, a2 = 0, a3 = 0;
    #pragma unroll
    for (int i = 0; i < 8; ++i) {
      float4 kv = kp[i];
      a0 = fmaf(q[4*i], kv.x, a0);
      a1 = fmaf(q[4*i+1], kv.y, a1);
      a2 = fmaf(q[4*i+2], kv.z, a2);
      a3 = fmaf(q[4*i+3], kv.w, a3);
    }
    float s = (a0 + a1) + (a2 + a3);
    mx = fmaxf(mx, s);
    sm += s;
  }
  Mbuf[(size_t)bh * 1024 + l] = mx - sm * (1.0f / 1024.0f);
}

// single-wave register-resident top-35 (no barriers)
__global__ void top35_kernel(const float* __restrict__ Mbuf, int* __restrict__ sel) {
  int bh = blockIdx.x;
  int lane = threadIdx.x;        // 64 threads
  float v[16];
  const float* Mb = Mbuf + (size_t)bh * 1024 + lane * 16;
  #pragma unroll
  for (int k = 0; k < 16; ++k) v[k] = Mb[k];
  for (int it = 0; it < 35; ++it) {
    float bv = -1e30f; int bi = 0;
    #pragma unroll
    for (int k = 0; k < 16; ++k)
      if (v[k] > bv) { bv = v[k]; bi = k; }
    int gidx = lane * 16 + bi;
    #pragma unroll
    for (int off = 32; off > 0; off >>= 1) {
      float ov = __shfl_down(bv, off, 64);
      int og = __shfl_down(gidx, off, 64);
      if (ov > bv || (ov == bv && og < gidx)) { bv = ov; gidx = og; }
    }
    gidx = __shfl(gidx, 0, 64);
    if (lane == 0) sel[bh * 35 + it] = gidx;
    if ((gidx >> 4) == lane) {
      int kk = gidx & 15;
      #pragma unroll
      for (int k = 0; k < 16; ++k)
        if (k == kk) v[k] = -1e30f;
    }
  }
}

__global__ void prob_fill_kernel(const float* __restrict__ V, float* __restrict__ cbuf) {
  __shared__ float red[256];
  __shared__ float vm[32];
  int bh = blockIdx.x, b = bh >> 1, h = bh & 1;
  int tid = threadIdx.x;
  int d = tid & 31, ch = tid >> 5;
  const float* Vb = V + (size_t)b * 65536 + h * 32;
  float s = 0.0f;
  for (int ss = ch * 128; ss < ch * 128 + 128; ++ss) s += Vb[(size_t)ss * 64 + d];
  red[tid] = s;
  __syncthreads();
  if (ch == 0) {
    float t = 0.0f;
    for (int c = 0; c < 8; ++c) t += red[c * 32 + d];
    vm[d] = t * (1.0f / 1024.0f);
  }
  __syncthreads();
  for (int i = tid; i < 1024 * 32; i += 256) {
    int l = i >> 5, dd = i & 31;
    cbuf[((size_t)b * 1024 + l) * 352 + 192 + h * 32 + dd] = vm[dd];
  }
}

__global__ void prob_part_kernel(const float* __restrict__ Q, const float* __restrict__ K,
                                 const float* __restrict__ V, const int* __restrict__ sel,
                                 float* __restrict__ ppart) {
  int bh = blockIdx.y, b = bh >> 1, h = bh & 1;
  int sc0 = blockIdx.x * 64;
  int u = threadIdx.x;
  int uu = (u < 35) ? u : 34;
  int l = sel[bh * 35 + uu];
  const float* Qb = Q + (size_t)b * 65536 + h * 32;
  const float* Kb = K + (size_t)b * 65536 + h * 32;
  const float* Vb = V + (size_t)b * 65536 + h * 32;
  float q[32];
  #pragma unroll
  for (int i = 0; i < 8; ++i) {
    float4 v4 = ((const float4*)(Qb + (size_t)l * 64))[i];
    q[4*i] = v4.x; q[4*i+1] = v4.y; q[4*i+2] = v4.z; q[4*i+3] = v4.w;
  }
  float o[32];
  #pragma unroll
  for (int dd = 0; dd < 32; ++dd) o[dd] = 0.0f;
  float ssum = 0.0f;
  for (int s = sc0; s < sc0 + 64; ++s) {
    const float4* kp = (const float4*)(Kb + (size_t)s * 64);
    float a0 = 0, a1 = 0, a2 = 0, a3 = 0;
    #pragma unroll
    for (int i = 0; i < 8; ++i) {
      float4 kv = kp[i];
      a0 = fmaf(q[4*i], kv.x, a0);
      a1 = fmaf(q[4*i+1], kv.y, a1);
      a2 = fmaf(q[4*i+2], kv.z, a2);
      a3 = fmaf(q[4*i+3], kv.w, a3);
    }
    float p = __expf(((a0 + a1) + (a2 + a3)) * SCALE_);
    ssum += p;
    const float4* vp = (const float4*)(Vb + (size_t)s * 64);
    #pragma unroll
    for (int i = 0; i < 8; ++i) {
      float4 vv = vp[i];
      o[4*i]   = fmaf(p, vv.x, o[4*i]);
      o[4*i+1] = fmaf(p, vv.y, o[4*i+1]);
      o[4*i+2] = fmaf(p, vv.z, o[4*i+2]);
      o[4*i+3] = fmaf(p, vv.w, o[4*i+3]);
    }
  }
  if (u < 35) {
    float* pp = ppart + (((size_t)bh * 16 + blockIdx.x) * 35 + u) * 36;
    #pragma unroll
    for (int i = 0; i < 8; ++i)
      ((float4*)pp)[i] = make_float4(o[4*i], o[4*i+1], o[4*i+2], o[4*i+3]);
    pp[32] = ssum;
  }
}

__global__ void prob_comb_kernel(const float* __restrict__ ppart, const int* __restrict__ sel,
                                 float* __restrict__ cbuf) {
  int t = blockIdx.x * 64 + threadIdx.x;
  if (t >= 32 * 35) return;
  int bh = t / 35, u = t % 35;
  int b = bh >> 1, h = bh & 1;
  int l = sel[bh * 35 + u];
  float S = 0.0f;
  float o[32];
  #pragma unroll
  for (int d = 0; d < 32; ++d) o[d] = 0.0f;
  for (int j = 0; j < 16; ++j) {
    const float* pp = ppart + (((size_t)bh * 16 + j) * 35 + u) * 36;
    S += pp[32];
    #pragma unroll
    for (int i = 0; i < 8; ++i) {
      float4 v4 = ((const float4*)pp)[i];
      o[4*i] += v4.x; o[4*i+1] += v4.y; o[4*i+2] += v4.z; o[4*i+3] += v4.w;
    }
  }
  float inv = 1.0f / S;
  float* cc = cbuf + ((size_t)b * 1024 + l) * 352 + 192 + h * 32;
  #pragma unroll
  for (int d = 0; d < 32; ++d) cc[d] = o[d] * inv;
}

// ---------------------------------------------------------------------------
// autocorrelation: mv[b,tau] = (1/64) sum_{c,t} K[b,c,t] * Q[b,c,(t+tau)%1024]
// XOR-swizzled 16B blocks in qs: p(blk) = blk ^ ((blk>>3)&7) -> conflict-free
// ---------------------------------------------------------------------------
__global__ void auto_mv_part(const float* __restrict__ Qa, const float* __restrict__ Ka,
                             float* __restrict__ part) {
  __shared__ float ks[1024];
  __shared__ float qs[2048];
  int c = blockIdx.x, b = blockIdx.y;
  int tid = threadIdx.x;
  const float* Qb = Qa + (size_t)b * 65536 + (size_t)c * 1024;
  const float* Kb = Ka + (size_t)b * 65536 + (size_t)c * 1024;
  float4* qs4 = (float4*)qs;
  float4* ks4 = (float4*)ks;
  ks4[tid] = ((const float4*)Kb)[tid];
  {
    float4 qv = ((const float4*)Qb)[tid];
    int b1 = tid, b2 = tid + 256;
    qs4[b1 ^ ((b1 >> 3) & 7)] = qv;
    qs4[b2 ^ ((b2 >> 3) & 7)] = qv;
  }
  __syncthreads();
  float a0 = 0, a1 = 0, a2 = 0, a3 = 0;
  for (int t = 0; t < 1024; t += 8) {
    float4 q0 = ks4[t >> 2];          // broadcast
    float4 q1 = ks4[(t >> 2) + 1];    // broadcast
    int b0 = (t >> 2) + tid;
    int b1 = b0 + 1, b2 = b0 + 2;
    float4 k0 = qs4[b0 ^ ((b0 >> 3) & 7)];
    float4 k1 = qs4[b1 ^ ((b1 >> 3) & 7)];
    float4 k2 = qs4[b2 ^ ((b2 >> 3) & 7)];
    a0 = fmaf(q0.x, k0.x, a0); a1 = fmaf(q0.x, k0.y, a1); a2 = fmaf(q0.x, k0.z, a2); a3 = fmaf(q0.x, k0.w, a3);
    a0 = fmaf(q0.y, k0.y, a0); a1 = fmaf(q0.y, k0.z, a1); a2 = fmaf(q0.y, k0.w, a2); a3 = fmaf(q0.y, k1.x, a3);
    a0 = fmaf(q0.z, k0.z, a0); a1 = fmaf(q0.z, k0.w, a1); a2 = fmaf(q0.z, k1.x, a2); a3 = fmaf(q0.z, k1.y, a3);
    a0 = fmaf(q0.w, k0.w, a0); a1 = fmaf(q0.w, k1.x, a1); a2 = fmaf(q0.w, k1.y, a2); a3 = fmaf(q0.w, k1.z, a3);
    a0 = fmaf(q1.x, k1.x, a0); a1 = fmaf(q1.x, k1.y, a1); a2 = fmaf(q1.x, k1.z, a2); a3 = fmaf(q1.x, k1.w, a3);
    a0 = fmaf(q1.y, k1.y, a0); a1 = fmaf(q1.y, k1.z, a1); a2 = fmaf(q1.y, k1.w, a2); a3 = fmaf(q1.y, k2.x, a3);
    a0 = fmaf(q1.z, k1.z, a0); a1 = fmaf(q1.z, k1.w, a1); a2 = fmaf(q1.z, k2.x, a2); a3 = fmaf(q1.z, k2.y, a3);
    a0 = fmaf(q1.w, k1.w, a0); a1 = fmaf(q1.w, k2.x, a1); a2 = fmaf(q1.w, k2.y, a2); a3 = fmaf(q1.w, k2.z, a3);
  }
  *(float4*)&part[(((size_t)b * 64 + c) << 10) + tid * 4] = make_float4(a0, a1, a2, a3);
}

__global__ void auto_mv_reduce(const float* __restrict__ part, float* __restrict__ mv) {
  int idx = blockIdx.x * 256 + threadIdx.x;
  int b = idx >> 10, tau = idx & 1023;
  float s = 0.0f;
  for (int c = 0; c < 64; ++c) s += part[(((size_t)b * 64 + c) << 10) + tau];
  mv[(size_t)b * 1024 + tau] = s * (1.0f / 64.0f);
}

// single-wave top-6 + per-batch softmax weights
__global__ void auto_top6_kernel(const float* __restrict__ mv, int* __restrict__ idx6,
                                 float* __restrict__ w6) {
  __shared__ int id6s[6];
  int lane = threadIdx.x;     // 64 threads
  float v[16];
  #pragma unroll
  for (int k = 0; k < 16; ++k) {
    int i = lane * 16 + k;
    float s = 0.0f;
    for (int b = 0; b < 16; ++b) s += mv[(size_t)b * 1024 + i];
    v[k] = s;
  }
  for (int it = 0; it < 6; ++it) {
    float bv = -1e30f; int bi = 0;
    #pragma unroll
    for (int k = 0; k < 16; ++k)
      if (v[k] > bv) { bv = v[k]; bi = k; }
    int gidx = lane * 16 + bi;
    #pragma unroll
    for (int off = 32; off > 0; off >>= 1) {
      float ov = __shfl_down(bv, off, 64);
      int og = __shfl_down(gidx, off, 64);
      if (ov > bv || (ov == bv && og < gidx)) { bv = ov; gidx = og; }
    }
    gidx = __shfl(gidx, 0, 64);
    if (lane == 0) { idx6[it] = gidx; id6s[it] = gidx; }
    if ((gidx >> 4) == lane) {
      int kk = gidx & 15;
      #pragma unroll
      for (int k = 0; k < 16; ++k)
        if (k == kk) v[k] = -1e30f;
    }
  }
  __syncthreads();
  if (lane < 16) {
    int b = lane;
    float vals[6]; float mx = -1e30f;
    #pragma unroll
    for (int j = 0; j < 6; ++j) { vals[j] = mv[(size_t)b * 1024 + id6s[j]]; mx = fmaxf(mx, vals[j]); }
    float s = 0.0f;
    #pragma unroll
    for (int j = 0; j < 6; ++j) { vals[j] = __expf(vals[j] - mx); s += vals[j]; }
    #pragma unroll
    for (int j = 0; j < 6; ++j) w6[b * 6 + j] = vals[j] / s;
  }
}

__global__ void auto_agg_kernel(const float* __restrict__ Va, const float* __restrict__ iq,
                                const float* __restrict__ wap, const float* __restrict__ bap,
                                const int* __restrict__ idx6, const float* __restrict__ w6,
                                float* __restrict__ ca) {
  __shared__ float aggs[16][64];
  __shared__ float w6s[6];
  __shared__ int id6[6];
  int b = blockIdx.y, t0 = blockIdx.x * 16;
  int tid = threadIdx.x;
  if (tid < 6) { w6s[tid] = w6[b * 6 + tid]; id6[tid] = idx6[tid]; }
  __syncthreads();
  const float* Vb = Va + (size_t)b * 65536;
  for (int i = tid; i < 1024; i += 256) {
    int tl = i >> 6, c = i & 63;
    int t = t0 + tl;
    float s = 0.0f;
    #pragma unroll
    for (int j = 0; j < 6; ++j)
      s += w6s[j] * Vb[(size_t)((t + id6[j]) & 1023) * 64 + c];
    aggs[tl][c] = s;
  }
  __syncthreads();
  int dm = tid & 127, tp = tid >> 7;
  float acc[8];
  #pragma unroll
  for (int r = 0; r < 8; ++r) {
    int t = t0 + tp * 8 + r;
    acc[r] = bap[dm] + iq[((size_t)b * 1024 + t) * 128 + dm];
  }
  for (int c = 0; c < 64; ++c) {
    float wv = wap[c * 128 + dm];
    #pragma unroll
    for (int r = 0; r < 8; ++r) acc[r] += aggs[tp * 8 + r][c] * wv;
  }
  #pragma unroll
  for (int r = 0; r < 8; ++r)
    ca[((size_t)b * 1024 + t0 + tp * 8 + r) * 128 + dm] = acc[r];
}

// moving-average detrend (k=25, edge-replicate, running window) + asize proj
__global__ void auto_ma_kernel(const float* __restrict__ ca, const float* __restrict__ was,
                               const float* __restrict__ bas, float* __restrict__ cbuf) {
  __shared__ float cas[40][128];
  __shared__ float diff[16][128];
  int b = blockIdx.y, t0 = blockIdx.x * 16;
  int tid = threadIdx.x;
  for (int i = tid; i < 40 * 128; i += 256) {
    int r = i >> 7, d = i & 127;
    int t = t0 - 12 + r;
    t = (t < 0) ? 0 : ((t > 1023) ? 1023 : t);
    cas[r][d] = ca[((size_t)b * 1024 + t) * 128 + d];
  }
  __syncthreads();
  int d = tid & 127, hf = tid >> 7;
  int tl0 = hf * 8;
  float s = 0.0f;
  #pragma unroll
  for (int w = 0; w < 25; ++w) s += cas[tl0 + w][d];
  #pragma unroll
  for (int k = 0; k < 8; ++k) {
    int tl = tl0 + k;
    diff[tl][d] = cas[tl + 12][d] - s * (1.0f / 25.0f);
    if (k < 7) s += cas[tl + 25][d] - cas[tl][d];
  }
  __syncthreads();
  int j = tid & 63, tq = tid >> 6;
  float acc[4];
  #pragma unroll
  for (int r = 0; r < 4; ++r) acc[r] = bas[j];
  for (int dd = 0; dd < 128; ++dd) {
    float wv = was[dd * 64 + j];
    #pragma unroll
    for (int r = 0; r < 4; ++r) acc[r] += diff[tq * 4 + r][dd] * wv;
  }
  #pragma unroll
  for (int r = 0; r < 4; ++r)
    cbuf[((size_t)b * 1024 + t0 + tq * 4 + r) * 352 + 288 + j] = acc[r];
}

// ---------------------------------------------------------------------------
// FFT branch: Y = X @ wfft, then cf_proj[f] = sum_t cos(2pi f t/1024) Y[t]
// symmetry: cf[1024-f] == cf[f]  ->  compute f=0..511 + f=512, mirror rest
// ---------------------------------------------------------------------------
__global__ void fftY_kernel(const float* __restrict__ x, const float* __restrict__ wfft,
                            float* __restrict__ Y) {
  __shared__ float xs[64][128];
  __shared__ float ws[32][129];
  int b = blockIdx.y, t0 = blockIdx.x * 64;
  int tid = threadIdx.x;
  for (int i = tid; i < 64 * 128; i += 256) {
    int r = i >> 7, d = i & 127;
    xs[r][d] = x[(size_t)b * 131072 + (size_t)(t0 + r) * 128 + d];
  }
  for (int i = tid; i < 4096; i += 256) {
    int d = i >> 5, j = i & 31;
    ws[j][d] = wfft[i];
  }
  __syncthreads();
  int j = tid & 31, tt0 = (tid >> 5) * 8;
  float acc[8];
  #pragma unroll
  for (int r = 0; r < 8; ++r) acc[r] = 0.0f;
  for (int d0 = 0; d0 < 128; d0 += 4) {
    float w0 = ws[j][d0], w1 = ws[j][d0 + 1], w2 = ws[j][d0 + 2], w3 = ws[j][d0 + 3];
    #pragma unroll
    for (int r = 0; r < 8; ++r) {
      float4 xv = *(const float4*)&xs[tt0 + r][d0];
      float a = acc[r];
      a = fmaf(w0, xv.x, a);
      a = fmaf(w1, xv.y, a);
      a = fmaf(w2, xv.z, a);
      a = fmaf(w3, xv.w, a);
      acc[r] = a;
    }
  }
  #pragma unroll
  for (int r = 0; r < 8; ++r)
    Y[((size_t)b * 1024 + t0 + tt0 + r) * 32 + j] = acc[r];
}

// lane map: fi = tid&31 (f-pairs), jg = tid>>5 (j-group) -> LDS reads become
// two broadcast groups per wave (conflict-free)
__global__ void fftT_kernel(const float* __restrict__ Y, const float* __restrict__ bfft,
                            float* __restrict__ cbuf) {
  __shared__ float ys[256 * 32];
  int b = blockIdx.y, fbase = blockIdx.x * 64;
  int tid = threadIdx.x;
  int fi = tid & 31, jg = tid >> 5, j0 = jg * 4;
  int f0 = fbase + fi * 2;
  const float TWO_PI_N = 6.283185307179586476925f / 1024.0f;
  float ca0, sa0, ca1, sa1;
  sincosf(TWO_PI_N * (float)f0, &sa0, &ca0);
  sincosf(TWO_PI_N * (float)(f0 + 1), &sa1, &ca1);
  float cr0 = 1.0f, ci0 = 0.0f, cr1 = 1.0f, ci1 = 0.0f;
  float4 acc0 = make_float4(0.f, 0.f, 0.f, 0.f);
  float4 acc1 = make_float4(0.f, 0.f, 0.f, 0.f);
  for (int chk = 0; chk < 4; ++chk) {
    __syncthreads();
    const float4* Yp = (const float4*)(Y + ((size_t)b * 1024 + chk * 256) * 32);
    for (int i = tid; i < 2048; i += 256) ((float4*)ys)[i] = Yp[i];
    __syncthreads();
    for (int tl = 0; tl < 256; ++tl) {
      float4 yv = *(const float4*)&ys[tl * 32 + j0];
      acc0.x = fmaf(cr0, yv.x, acc0.x);
      acc0.y = fmaf(cr0, yv.y, acc0.y);
      acc0.z = fmaf(cr0, yv.z, acc0.z);
      acc0.w = fmaf(cr0, yv.w, acc0.w);
      acc1.x = fmaf(cr1, yv.x, acc1.x);
      acc1.y = fmaf(cr1, yv.y, acc1.y);
      acc1.z = fmaf(cr1, yv.z, acc1.z);
      acc1.w = fmaf(cr1, yv.w, acc1.w);
      float nr0 = cr0 * ca0 - ci0 * sa0;
      float ni0 = cr0 * sa0 + ci0 * ca0;
      cr0 = nr0; ci0 = ni0;
      float nr1 = cr1 * ca1 - ci1 * sa1;
      float ni1 = cr1 * sa1 + ci1 * ca1;
      cr1 = nr1; ci1 = ni1;
    }
  }
  float b0 = bfft[j0], b1 = bfft[j0 + 1], b2 = bfft[j0 + 2], b3 = bfft[j0 + 3];
  float* cc0 = cbuf + ((size_t)b * 1024 + f0) * 352 + 256 + j0;
  cc0[0] = acc0.x + b0; cc0[1] = acc0.y + b1; cc0[2] = acc0.z + b2; cc0[3] = acc0.w + b3;
  float* cc1 = cbuf + ((size_t)b * 1024 + f0 + 1) * 352 + 256 + j0;
  cc1[0] = acc1.x + b0; cc1[1] = acc1.y + b1; cc1[2] = acc1.z + b2; cc1[3] = acc1.w + b3;
  if (f0 > 0) {
    float* cm0 = cbuf + ((size_t)b * 1024 + (1024 - f0)) * 352 + 256 + j0;
    cm0[0] = acc0.x + b0; cm0[1] = acc0.y + b1; cm0[2] = acc0.z + b2; cm0[3] = acc0.w + b3;
  }
  {
    float* cm1 = cbuf + ((size_t)b * 1024 + (1024 - f0 - 1)) * 352 + 256 + j0;
    cm1[0] = acc1.x + b0; cm1[1] = acc1.y + b1; cm1[2] = acc1.z + b2; cm1[3] = acc1.w + b3;
  }
}

// f=512: cos(pi t) = (-1)^t
__global__ void fft512_kernel(const float* __restrict__ Y, const float* __restrict__ bfft,
                              float* __restrict__ cbuf) {
  __shared__ float red[8][32];
  int b = blockIdx.x;
  int tid = threadIdx.x;
  int tc = tid >> 5, j = tid & 31;
  float s = 0.0f;
  for (int t = tc * 128; t < tc * 128 + 128; ++t) {
    float y = Y[((size_t)b * 1024 + t) * 32 + j];
    s += (t & 1) ? -y : y;
  }
  red[tc][j] = s;
  __syncthreads();
  if (tc == 0) {
    float t = 0.0f;
    for (int c = 0; c < 8; ++c) t += red[c][j];
    cbuf[((size_t)b * 1024 + 512) * 352 + 256 + j] = t + bfft[j];
  }
}

// ---------------------------------------------------------------------------
// final: out = cbuf @ w_fc + iq, then layernorm over DM
// ---------------------------------------------------------------------------
__global__ void fc_ln_kernel(const float* __restrict__ cbuf, const float* __restrict__ wfc,
                             const float* __restrict__ iq, float* __restrict__ out) {
  __shared__ float cs[16][352];
  __shared__ float os[16][128];
  int b = blockIdx.y, t0 = blockIdx.x * 16;
  int tid = threadIdx.x;
  for (int i = tid; i < 16 * 352; i += 256) {
    int r = i / 352, col = i % 352;
    cs[r][col] = cbuf[((size_t)b * 1024 + t0 + r) * 352 + col];
  }
  __syncthreads();
  int j = tid & 127, half = tid >> 7;
  float acc[8];
  #pragma unroll
  for (int k = 0; k < 8; ++k)
    acc[k] = iq[((size_t)b * 1024 + t0 + half * 8 + k) * 128 + j];
  for (int i = 0; i < 352; ++i) {
    float wv = wfc[i * 128 + j];
    #pragma unroll
    for (int k = 0; k < 8; ++k) acc[k] += cs[half * 8 + k][i] * wv;
  }
  #pragma unroll
  for (int k = 0; k < 8; ++k) os[half * 8 + k][j] = acc[k];
  __syncthreads();
  int wid = tid >> 6, lane = tid & 63;
  for (int rr = 0; rr < 4; ++rr) {
    int r = wid * 4 + rr;
    float x0 = os[r][lane], x1 = os[r][lane + 64];
    float s1 = x0 + x1;
    float s2 = x0 * x0 + x1 * x1;
    #pragma unroll
    for (int k = 32; k > 0; k >>= 1) {
      s1 += __shfl_xor(s1, k, 64);
      s2 += __shfl_xor(s2, k, 64);
    }
    float mean = s1 * (1.0f / 128.0f);
    float var = s2 * (1.0f / 128.0f) - mean * mean;
    float rstd = 1.0f / sqrtf(var + 1e-5f);
    float* op = out + ((size_t)b * 1024 + t0 + r) * 128;
    op[lane] = (x0 - mean) * rstd;
    op[lane + 64] = (x1 - mean) * rstd;
  }
}

// ---------------------------------------------------------------------------
extern "C" void kernel_launch(void* const* d_in, const int* in_sizes, int n_in,
                              void* d_out, int out_size, void* d_ws, size_t ws_size,
                              hipStream_t stream) {
  (void)in_sizes; (void)n_in; (void)out_size;
  const float* inQ = (const float*)d_in[0];
  const float* inK = (const float*)d_in[1];
  const float* inV = (const float*)d_in[2];
  const float *wq[5], *bq[5], *wk[5], *bk[5], *wv[5], *bv[5];
  for (int br = 0; br < 5; ++br) {
    wq[br] = (const float*)d_in[3 + br * 6 + 0];
    bq[br] = (const float*)d_in[3 + br * 6 + 1];
    wk[br] = (const float*)d_in[3 + br * 6 + 2];
    bk[br] = (const float*)d_in[3 + br * 6 + 3];
    wv[br] = (const float*)d_in[3 + br * 6 + 4];
    bv[br] = (const float*)d_in[3 + br * 6 + 5];
  }
  const float* wfft = (const float*)d_in[33];
  const float* bfft = (const float*)d_in[34];
  const float* wap  = (const float*)d_in[35];
  const float* bap  = (const float*)d_in[36];
  const float* was  = (const float*)d_in[37];
  const float* bas  = (const float*)d_in[38];
  const float* wfc  = (const float*)d_in[39];
  float* out = (float*)d_out;

  // full-attn split factor: 8 if workspace allows (~76 MiB), else proven 4
  int nsplit = (ws_size >= (size_t)76 * 1024 * 1024) ? 8 : 4;
  int stile = 1024 / nsplit;
  int nstage = stile / 128;

  char* wsb = (char*)d_ws;
  size_t off = 0;
  auto alloc = [&](size_t bytes) -> void* {
    void* p = wsb + off;
    off += (bytes + 255) & ~(size_t)255;
    return p;
  };
  int*   pidx = (int*)  alloc((size_t)35840 * 4);
  float* qbuf = (float*)alloc((size_t)16 * 65536 * 4);
  float* kbuf = (float*)alloc((size_t)16 * 65536 * 4);
  float* vbuf = (float*)alloc((size_t)16 * 65536 * 4);
  float* cbuf = (float*)alloc((size_t)16 * 1024 * 352 * 4);
  float* fpart = (float*)alloc((size_t)32 * nsplit * 1024 * 36 * 4);
  float* Mbuf = (float*)alloc((size_t)32 * 1024 * 4);
  int*   sel  = (int*)  alloc((size_t)32 * 35 * 4);
  float* mvb  = (float*)alloc((size_t)16 * 1024 * 4);
  int*   idx6 = (int*)  alloc(64);
  float* w6   = (float*)alloc((size_t)16 * 6 * 4);
  // aliases into fpart (timeline-disjoint):
  float* ppart = fpart;                                              // prob partials (2.6MiB)
  float* cab   = fpart;                                              // auto ca (8MiB)
  float* mpart = (float*)((char*)fpart + (size_t)8 * 1024 * 1024);   // corr partials (4MiB)
  float* Ybuf  = (float*)((char*)fpart + (size_t)12 * 1024 * 1024);  // fft Y (2MiB)

  mt_kernel<<<1, 256, 0, stream>>>(pidx);

  dim3 cgrid(32, 16);
  // branch 0: full attention
  conv3_kernel<<<cgrid, 256, 0, stream>>>(inQ, wq[0], bq[0], qbuf);
  conv3_kernel<<<cgrid, 256, 0, stream>>>(inK, wk[0], bk[0], kbuf);
  conv1_kernel<<<cgrid, 256, 0, stream>>>(inV, wv[0], bv[0], vbuf);
  attn_full_part<<<dim3(4, nsplit, 32), 256, 0, stream>>>(qbuf, kbuf, vbuf, fpart, stile, nstage);
  attn_full_comb<<<256, 128, 0, stream>>>(fpart, cbuf, nsplit);

  // branch 1: log-sparse
  conv3_kernel<<<cgrid, 256, 0, stream>>>(inQ, wq[1], bq[1], qbuf);
  conv3_kernel<<<cgrid, 256, 0, stream>>>(inK, wk[1], bk[1], kbuf);
  conv1_kernel<<<cgrid, 256, 0, stream>>>(inV, wv[1], bv[1], vbuf);
  attn_log_kernel<<<256, 128, 0, stream>>>(qbuf, kbuf, vbuf, cbuf);

  // branch 2: local window
  conv3_kernel<<<cgrid, 256, 0, stream>>>(inQ, wq[2], bq[2], qbuf);
  conv3_kernel<<<cgrid, 256, 0, stream>>>(inK, wk[2], bk[2], kbuf);
  conv1_kernel<<<cgrid, 256, 0, stream>>>(inV, wv[2], bv[2], vbuf);
  attn_loc_kernel<<<256, 128, 0, stream>>>(qbuf, kbuf, vbuf, cbuf);

  // branch 3: prob-sparse
  conv3_kernel<<<cgrid, 256, 0, stream>>>(inQ, wq[3], bq[3], qbuf);
  conv3_kernel<<<cgrid, 256, 0, stream>>>(inK, wk[3], bk[3], kbuf);
  conv1_kernel<<<cgrid, 256, 0, stream>>>(inV, wv[3], bv[3], vbuf);
  prob_m_kernel<<<256, 128, 0, stream>>>(qbuf, kbuf, pidx, Mbuf);
  top35_kernel<<<32, 64, 0, stream>>>(Mbuf, sel);
  prob_fill_kernel<<<32, 256, 0, stream>>>(vbuf, cbuf);
  prob_part_kernel<<<dim3(16, 32), 64, 0, stream>>>(qbuf, kbuf, vbuf, sel, ppart);
  prob_comb_kernel<<<18, 64, 0, stream>>>(ppart, sel, cbuf);

  // branch 4: autocorrelation
  conv3_kernel<<<cgrid, 256, 0, stream>>>(inQ, wq[4], bq[4], qbuf);
  conv3_kernel<<<cgrid, 256, 0, stream>>>(inK, wk[4], bk[4], kbuf);
  conv1_kernel<<<cgrid, 256, 0, stream>>>(inV, wv[4], bv[4], vbuf);
  auto_mv_part<<<dim3(64, 16), 256, 0, stream>>>(qbuf, kbuf, mpart);
  auto_mv_reduce<<<64, 256, 0, stream>>>(mpart, mvb);
  auto_top6_kernel<<<1, 64, 0, stream>>>(mvb, idx6, w6);
  auto_agg_kernel<<<dim3(64, 16), 256, 0, stream>>>(vbuf, inQ, wap, bap, idx6, w6, cab);
  auto_ma_kernel<<<dim3(64, 16), 256, 0, stream>>>(cab, was, bas, cbuf);

  // FFT branch (mirror symmetry: compute f=0..512 only)
  fftY_kernel<<<dim3(16, 16), 256, 0, stream>>>(inQ, wfft, Ybuf);
  fftT_kernel<<<dim3(8, 16), 256, 0, stream>>>(Ybuf, bfft, cbuf);
  fft512_kernel<<<16, 256, 0, stream>>>(Ybuf, bfft, cbuf);

  // final projection + layernorm
  fc_ln_kernel<<<dim3(64, 16), 256, 0, stream>>>(cbuf, wfc, inQ, out);
}

// Round 6
// 877.361 us; speedup vs baseline: 1.5712x; 1.0902x over previous
//
#include <hip/hip_runtime.h>
#include <hip/hip_bf16.h>
#include <math.h>

#define B_   16
#define L_   1024
#define SCALE_ 0.17677669529663687f   // 1/sqrt(32)

// ---------------------------------------------------------------------------
// MT19937 -> PROB_IDX (35840 draws of genrand_int32() & 1023, seed 0)
// ---------------------------------------------------------------------------
__global__ void mt_kernel(int* __restrict__ pidx) {
  __shared__ unsigned int mt[624];
  int tid = threadIdx.x;   // 256
  if (tid == 0) {
    unsigned int s = 0u;
    for (int i = 0; i < 624; ++i) {
      mt[i] = s;
      s = 1812433253u * (s ^ (s >> 30)) + (unsigned)(i + 1);
    }
  }
  __syncthreads();
  const unsigned int HI = 0x80000000u, LO = 0x7fffffffu, MM = 0x9908b0dfu;
  for (int blk = 0; blk < 58; ++blk) {
    unsigned int n0 = 0, n1 = 0, n2 = 0, old623 = 0;
    bool a0 = tid < 227, a2 = tid < 169;
    if (a0) {
      unsigned int y0 = (mt[tid] & HI) | (mt[tid + 1] & LO);
      n0 = mt[tid + 397] ^ (y0 >> 1) ^ ((y0 & 1u) ? MM : 0u);
      unsigned int y1 = (mt[tid + 227] & HI) | (mt[tid + 228] & LO);
      n1 = n0 ^ (y1 >> 1) ^ ((y1 & 1u) ? MM : 0u);
      if (a2) {
        unsigned int y2 = (mt[tid + 454] & HI) | (mt[tid + 455] & LO);
        n2 = n1 ^ (y2 >> 1) ^ ((y2 & 1u) ? MM : 0u);
      }
      if (tid == 169) old623 = mt[623];
    }
    __syncthreads();
    if (a0) {
      mt[tid] = n0;
      mt[tid + 227] = n1;
      if (a2) mt[tid + 454] = n2;
    }
    __syncthreads();
    if (tid == 169) {
      unsigned int y = (old623 & HI) | (mt[0] & LO);
      mt[623] = n1 ^ (y >> 1) ^ ((y & 1u) ? MM : 0u);
    }
    __syncthreads();
    for (int i = tid; i < 624; i += 256) {
      int g = blk * 624 + i;
      if (g < 35840) {
        unsigned int y = mt[i];
        y ^= y >> 11;
        y ^= (y << 7) & 0x9d2c5680u;
        y ^= (y << 15) & 0xefc60000u;
        y ^= y >> 18;
        pidx[g] = (int)(y & 1023u);
      }
    }
  }
}

// ---------------------------------------------------------------------------
// merged Q/K/V conv for one branch. z=0: Q conv3, z=1: K conv3, z=2: V conv1
// OUTPUT CHANNEL-MAJOR: out[b, c*1024 + t]
// ---------------------------------------------------------------------------
__global__ void qkv_conv_kernel(const float* __restrict__ xq, const float* __restrict__ xk,
                                const float* __restrict__ xv,
                                const float* __restrict__ wq, const float* __restrict__ bq,
                                const float* __restrict__ wk, const float* __restrict__ bk,
                                const float* __restrict__ wv, const float* __restrict__ bv,
                                float* __restrict__ qo, float* __restrict__ ko,
                                float* __restrict__ vo) {
  __shared__ float smem[12544];   // conv1: xs 4096 + ws 8256; conv3: xs 4352 + ws 6208
  int which = blockIdx.z;
  const float* x = (which == 0) ? xq : (which == 1) ? xk : xv;
  const float* w = (which == 0) ? wq : (which == 1) ? wk : wv;
  const float* bias = (which == 0) ? bq : (which == 1) ? bk : bv;
  float* out = (which == 0) ? qo : (which == 1) ? ko : vo;
  int b = blockIdx.y, t0 = blockIdx.x * 32;
  int tid = threadIdx.x;
  int c = tid & 63, tt0 = (tid >> 6) * 8;
  float acc[8];
  float bvv = bias[c];
  #pragma unroll
  for (int j = 0; j < 8; ++j) acc[j] = bvv;

  if (which < 2) {
    // ---- conv k=3, left pad 2 ----
    float* xs = smem;            // [34][128]
    float* ws = smem + 4352;     // [64][97] (96 used, pad 1)
    for (int i = tid; i < 34 * 128; i += 256) {
      int r = i >> 7, d = i & 127;
      int t = t0 - 2 + r;
      xs[r * 128 + d] = (t >= 0) ? x[(size_t)b * 131072 + (size_t)t * 128 + d] : 0.0f;
    }
    for (int dc = 0; dc < 128; dc += 32) {
      __syncthreads();
      for (int i = tid; i < 64 * 96; i += 256) {
        int cc = i / 96, jj = i % 96;
        ws[cc * 97 + jj] = w[cc * 384 + dc * 3 + jj];
      }
      __syncthreads();
      for (int d0 = dc; d0 < dc + 32; d0 += 4) {
        float4 xr[10];
        #pragma unroll
        for (int r = 0; r < 10; ++r) xr[r] = *(const float4*)&xs[(tt0 + r) * 128 + d0];
        float wreg[12];
        #pragma unroll
        for (int jj = 0; jj < 12; ++jj) wreg[jj] = ws[c * 97 + (d0 - dc) * 3 + jj];
        #pragma unroll
        for (int j = 0; j < 8; ++j) {
          float a = acc[j];
          #pragma unroll
          for (int k = 0; k < 3; ++k) {
            float4 xv4 = xr[j + k];
            a = fmaf(wreg[0 + k], xv4.x, a);
            a = fmaf(wreg[3 + k], xv4.y, a);
            a = fmaf(wreg[6 + k], xv4.z, a);
            a = fmaf(wreg[9 + k], xv4.w, a);
          }
          acc[j] = a;
        }
      }
    }
  } else {
    // ---- conv k=1 ----
    float* xs = smem;            // [32][128]
    float* ws = smem + 4096;     // [64][129] (pad 1)
    for (int i = tid; i < 32 * 128; i += 256) {
      int r = i >> 7, d = i & 127;
      xs[r * 128 + d] = x[(size_t)b * 131072 + (size_t)(t0 + r) * 128 + d];
    }
    for (int i = tid; i < 64 * 128; i += 256) {
      ws[(i >> 7) * 129 + (i & 127)] = w[i];
    }
    __syncthreads();
    for (int d0 = 0; d0 < 128; d0 += 4) {
      float w0 = ws[c * 129 + d0], w1 = ws[c * 129 + d0 + 1];
      float w2 = ws[c * 129 + d0 + 2], w3 = ws[c * 129 + d0 + 3];
      #pragma unroll
      for (int j = 0; j < 8; ++j) {
        float4 xv4 = *(const float4*)&xs[(tt0 + j) * 128 + d0];
        float a = acc[j];
        a = fmaf(w0, xv4.x, a);
        a = fmaf(w1, xv4.y, a);
        a = fmaf(w2, xv4.z, a);
        a = fmaf(w3, xv4.w, a);
        acc[j] = a;
      }
    }
  }
  float* op = out + (size_t)b * 65536 + (size_t)c * 1024 + t0 + tt0;
  #pragma unroll
  for (int j = 0; j < 8; ++j) op[j] = acc[j];
}

// ---------------------------------------------------------------------------
// full attention, split-K partials, no-max softmax (scores bounded ~1)
// ---------------------------------------------------------------------------
__global__ void attn_full_part(const float* __restrict__ Q, const float* __restrict__ K,
                               const float* __restrict__ V, float* __restrict__ part,
                               int stile, int nstage) {
  __shared__ float Ks[128][32];
  __shared__ float Vs[128][32];
  int bh = blockIdx.z, b = bh >> 1, h = bh & 1;
  int l = blockIdx.x * 256 + threadIdx.x;
  int s0 = blockIdx.y * stile;
  const float* Kb = K + (size_t)b * 65536 + h * 32;
  const float* Vb = V + (size_t)b * 65536 + h * 32;
  const float* Qb = Q + (size_t)b * 65536 + h * 32 + (size_t)l * 64;
  float q[32];
  #pragma unroll
  for (int i = 0; i < 8; ++i) {
    float4 v4 = ((const float4*)Qb)[i];
    q[4*i] = v4.x; q[4*i+1] = v4.y; q[4*i+2] = v4.z; q[4*i+3] = v4.w;
  }
  float o[32];
  #pragma unroll
  for (int d = 0; d < 32; ++d) o[d] = 0.0f;
  float ssum = 0.0f;
  for (int st = 0; st < nstage; ++st) {
    __syncthreads();
    int sb = s0 + st * 128;
    for (int i = threadIdx.x; i < 1024; i += 256) {
      int r = i >> 3, d4 = i & 7;
      ((float4*)&Ks[r][0])[d4] = *(const float4*)(Kb + (size_t)(sb + r) * 64 + d4 * 4);
      ((float4*)&Vs[r][0])[d4] = *(const float4*)(Vb + (size_t)(sb + r) * 64 + d4 * 4);
    }
    __syncthreads();
    for (int s = 0; s < 128; ++s) {
      float a0 = 0, a1 = 0, a2 = 0, a3 = 0;
      const float4* kp = (const float4*)&Ks[s][0];
      #pragma unroll
      for (int i = 0; i < 8; ++i) {
        float4 kv = kp[i];
        a0 = fmaf(q[4*i], kv.x, a0);
        a1 = fmaf(q[4*i+1], kv.y, a1);
        a2 = fmaf(q[4*i+2], kv.z, a2);
        a3 = fmaf(q[4*i+3], kv.w, a3);
      }
      float p = __expf(((a0 + a1) + (a2 + a3)) * SCALE_);
      ssum += p;
      const float4* vp = (const float4*)&Vs[s][0];
      #pragma unroll
      for (int i = 0; i < 8; ++i) {
        float4 vv = vp[i];
        o[4*i]   = fmaf(p, vv.x, o[4*i]);
        o[4*i+1] = fmaf(p, vv.y, o[4*i+1]);
        o[4*i+2] = fmaf(p, vv.z, o[4*i+2]);
        o[4*i+3] = fmaf(p, vv.w, o[4*i+3]);
      }
    }
  }
  float* pp = part + (((size_t)bh * gridDim.y + blockIdx.y) * 1024 + l) * 36;
  #pragma unroll
  for (int i = 0; i < 8; ++i)
    ((float4*)pp)[i] = make_float4(o[4*i], o[4*i+1], o[4*i+2], o[4*i+3]);
  pp[32] = ssum;
}

__global__ void attn_full_comb(const float* __restrict__ part, float* __restrict__ cbuf,
                               int nsplit) {
  int idx = blockIdx.x * 128 + threadIdx.x;
  int bh = idx >> 10, l = idx & 1023;
  int b = bh >> 1, h = bh & 1;
  float S = 0.0f;
  float o[32];
  #pragma unroll
  for (int d = 0; d < 32; ++d) o[d] = 0.0f;
  for (int j = 0; j < nsplit; ++j) {
    const float* pp = part + (((size_t)bh * nsplit + j) * 1024 + l) * 36;
    S += pp[32];
    #pragma unroll
    for (int i = 0; i < 8; ++i) {
      float4 v4 = ((const float4*)pp)[i];
      o[4*i] += v4.x; o[4*i+1] += v4.y; o[4*i+2] += v4.z; o[4*i+3] += v4.w;
    }
  }
  float inv = 1.0f / S;
  float* cc = cbuf + ((size_t)b * 1024 + l) * 352 + 0 + h * 32;
  #pragma unroll
  for (int d = 0; d < 32; ++d) cc[d] = o[d] * inv;
}

// ---------------------------------------------------------------------------
// log-sparse attention, single-pass no-max
// ---------------------------------------------------------------------------
__global__ void attn_log_kernel(const float* __restrict__ Q, const float* __restrict__ K,
                                const float* __restrict__ V, float* __restrict__ cbuf) {
  int idx = blockIdx.x * 128 + threadIdx.x;
  int bh = idx >> 10, l = idx & 1023;
  int b = bh >> 1, h = bh & 1;
  const float* Qb = Q + (size_t)b * 65536 + h * 32;
  const float* Kb = K + (size_t)b * 65536 + h * 32;
  const float* Vb = V + (size_t)b * 65536 + h * 32;
  float q[32];
  #pragma unroll
  for (int i = 0; i < 8; ++i) {
    float4 v4 = ((const float4*)(Qb + (size_t)l * 64))[i];
    q[4*i] = v4.x; q[4*i+1] = v4.y; q[4*i+2] = v4.z; q[4*i+3] = v4.w;
  }
  float o[32];
  #pragma unroll
  for (int d = 0; d < 32; ++d) o[d] = 0.0f;
  float ssum = 0.0f;
  #pragma unroll
  for (int j = 0; j < 11; ++j) {
    int off = (j == 0) ? 0 : (1 << (j - 1));
    if (off <= l) {
      int s = l - off;
      const float4* kp = (const float4*)(Kb + (size_t)s * 64);
      float a0 = 0, a1 = 0, a2 = 0, a3 = 0;
      #pragma unroll
      for (int i = 0; i < 8; ++i) {
        float4 kv = kp[i];
        a0 = fmaf(q[4*i], kv.x, a0);
        a1 = fmaf(q[4*i+1], kv.y, a1);
        a2 = fmaf(q[4*i+2], kv.z, a2);
        a3 = fmaf(q[4*i+3], kv.w, a3);
      }
      float p = __expf(((a0 + a1) + (a2 + a3)) * SCALE_);
      ssum += p;
      const float4* vp = (const float4*)(Vb + (size_t)s * 64);
      #pragma unroll
      for (int i = 0; i < 8; ++i) {
        float4 vv = vp[i];
        o[4*i]   = fmaf(p, vv.x, o[4*i]);
        o[4*i+1] = fmaf(p, vv.y, o[4*i+1]);
        o[4*i+2] = fmaf(p, vv.z, o[4*i+2]);
        o[4*i+3] = fmaf(p, vv.w, o[4*i+3]);
      }
    }
  }
  float inv = 1.0f / ssum;
  float* cc = cbuf + ((size_t)b * 1024 + l) * 352 + 64 + h * 32;
  #pragma unroll
  for (int d = 0; d < 32; ++d) cc[d] = o[d] * inv;
}

// local-window attention, single-pass no-max
__global__ void attn_loc_kernel(const float* __restrict__ Q, const float* __restrict__ K,
                                const float* __restrict__ V, float* __restrict__ cbuf) {
  int idx = blockIdx.x * 128 + threadIdx.x;
  int bh = idx >> 10, l = idx & 1023;
  int b = bh >> 1, h = bh & 1;
  const float* Qb = Q + (size_t)b * 65536 + h * 32;
  const float* Kb = K + (size_t)b * 65536 + h * 32;
  const float* Vb = V + (size_t)b * 65536 + h * 32;
  float q[32];
  #pragma unroll
  for (int i = 0; i < 8; ++i) {
    float4 v4 = ((const float4*)(Qb + (size_t)l * 64))[i];
    q[4*i] = v4.x; q[4*i+1] = v4.y; q[4*i+2] = v4.z; q[4*i+3] = v4.w;
  }
  float o[32];
  #pragma unroll
  for (int d = 0; d < 32; ++d) o[d] = 0.0f;
  float ssum = 0.0f;
  int jlo = (l >= 31) ? 0 : (31 - l);
  for (int j = jlo; j < 32; ++j) {
    int s = l - 31 + j;
    const float4* kp = (const float4*)(Kb + (size_t)s * 64);
    float a0 = 0, a1 = 0, a2 = 0, a3 = 0;
    #pragma unroll
    for (int i = 0; i < 8; ++i) {
      float4 kv = kp[i];
      a0 = fmaf(q[4*i], kv.x, a0);
      a1 = fmaf(q[4*i+1], kv.y, a1);
      a2 = fmaf(q[4*i+2], kv.z, a2);
      a3 = fmaf(q[4*i+3], kv.w, a3);
    }
    float p = __expf(((a0 + a1) + (a2 + a3)) * SCALE_);
    ssum += p;
    const float4* vp = (const float4*)(Vb + (size_t)s * 64);
    #pragma unroll
    for (int i = 0; i < 8; ++i) {
      float4 vv = vp[i];
      o[4*i]   = fmaf(p, vv.x, o[4*i]);
      o[4*i+1] = fmaf(p, vv.y, o[4*i+1]);
      o[4*i+2] = fmaf(p, vv.z, o[4*i+2]);
      o[4*i+3] = fmaf(p, vv.w, o[4*i+3]);
    }
  }
  float inv = 1.0f / ssum;
  float* cc = cbuf + ((size_t)b * 1024 + l) * 352 + 128 + h * 32;
  #pragma unroll
  for (int d = 0; d < 32; ++d) cc[d] = o[d] * inv;
}

// ---------------------------------------------------------------------------
// prob-sparse attention
// ---------------------------------------------------------------------------
__global__ void prob_m_kernel(const float* __restrict__ Q, const float* __restrict__ K,
                              const int* __restrict__ pidx, float* __restrict__ Mbuf) {
  int idx = blockIdx.x * 128 + threadIdx.x;
  int bh = idx >> 10, l = idx & 1023;
  int b = bh >> 1, h = bh & 1;
  const float* Qb = Q + (size_t)b * 65536 + h * 32;
  const float* Kb = K + (size_t)b * 65536 + h * 32;
  float q[32];
  #pragma unroll
  for (int i = 0; i < 8; ++i) {
    float4 v4 = ((const float4*)(Qb + (size_t)l * 64))[i];
    q[4*i] = v4.x; q[4*i+1] = v4.y; q[4*i+2] = v4.z; q[4*i+3] = v4.w;
  }
  float mx = -1e30f, sm = 0.0f;
  for (int u = 0; u < 35; ++u) {
    int ki = pidx[l * 35 + u];
    const float4* kp = (const float4*)(Kb + (size_t)ki * 64);
    float a0 = 0, a1 = 0, a2 = 0, a3 = 0;
    #pragma unroll
    for (int i = 0; i < 8; ++i) {
      float4 kv = kp[i];
      a0 = fmaf(q[4*i], kv.x, a0);
      a1 = fmaf(q[4*i+1], kv.y, a1);
      a2 = fmaf(q[4*i+2], kv.z, a2);
      a3 = fmaf(q[4*i+3], kv.w, a3);
    }
    float s = (a0 + a1) + (a2 + a3);
    mx = fmaxf(mx, s);
    sm += s;
  }
  Mbuf[(size_t)bh * 1024 + l] = mx - sm * (1.0f / 1024.0f);
}

// single-wave register-resident top-35 (no barriers)
__global__ void top35_kernel(const float* __restrict__ Mbuf, int* __restrict__ sel) {
  int bh = blockIdx.x;
  int lane = threadIdx.x;        // 64 threads
  float v[16];
  const float* Mb = Mbuf + (size_t)bh * 1024 + lane * 16;
  #pragma unroll
  for (int k = 0; k < 16; ++k) v[k] = Mb[k];
  for (int it = 0; it < 35; ++it) {
    float bv = -1e30f; int bi = 0;
    #pragma unroll
    for (int k = 0; k < 16; ++k)
      if (v[k] > bv) { bv = v[k]; bi = k; }
    int gidx = lane * 16 + bi;
    #pragma unroll
    for (int off = 32; off > 0; off >>= 1) {
      float ov = __shfl_down(bv, off, 64);
      int og = __shfl_down(gidx, off, 64);
      if (ov > bv || (ov == bv && og < gidx)) { bv = ov; gidx = og; }
    }
    gidx = __shfl(gidx, 0, 64);
    if (lane == 0) sel[bh * 35 + it] = gidx;
    if ((gidx >> 4) == lane) {
      int kk = gidx & 15;
      #pragma unroll
      for (int k = 0; k < 16; ++k)
        if (k == kk) v[k] = -1e30f;
    }
  }
}

__global__ void prob_fill_kernel(const float* __restrict__ V, float* __restrict__ cbuf) {
  __shared__ float red[256];
  __shared__ float vm[32];
  int bh = blockIdx.x, b = bh >> 1, h = bh & 1;
  int tid = threadIdx.x;
  int d = tid & 31, ch = tid >> 5;
  const float* Vb = V + (size_t)b * 65536 + h * 32;
  float s = 0.0f;
  for (int ss = ch * 128; ss < ch * 128 + 128; ++ss) s += Vb[(size_t)ss * 64 + d];
  red[tid] = s;
  __syncthreads();
  if (ch == 0) {
    float t = 0.0f;
    for (int c = 0; c < 8; ++c) t += red[c * 32 + d];
    vm[d] = t * (1.0f / 1024.0f);
  }
  __syncthreads();
  for (int i = tid; i < 1024 * 32; i += 256) {
    int l = i >> 5, dd = i & 31;
    cbuf[((size_t)b * 1024 + l) * 352 + 192 + h * 32 + dd] = vm[dd];
  }
}

__global__ void prob_part_kernel(const float* __restrict__ Q, const float* __restrict__ K,
                                 const float* __restrict__ V, const int* __restrict__ sel,
                                 float* __restrict__ ppart) {
  int bh = blockIdx.y, b = bh >> 1, h = bh & 1;
  int sc0 = blockIdx.x * 64;
  int u = threadIdx.x;
  int uu = (u < 35) ? u : 34;
  int l = sel[bh * 35 + uu];
  const float* Qb = Q + (size_t)b * 65536 + h * 32;
  const float* Kb = K + (size_t)b * 65536 + h * 32;
  const float* Vb = V + (size_t)b * 65536 + h * 32;
  float q[32];
  #pragma unroll
  for (int i = 0; i < 8; ++i) {
    float4 v4 = ((const float4*)(Qb + (size_t)l * 64))[i];
    q[4*i] = v4.x; q[4*i+1] = v4.y; q[4*i+2] = v4.z; q[4*i+3] = v4.w;
  }
  float o[32];
  #pragma unroll
  for (int dd = 0; dd < 32; ++dd) o[dd] = 0.0f;
  float ssum = 0.0f;
  for (int s = sc0; s < sc0 + 64; ++s) {
    const float4* kp = (const float4*)(Kb + (size_t)s * 64);
    float a0 = 0, a1 = 0, a2 = 0, a3 = 0;
    #pragma unroll
    for (int i = 0; i < 8; ++i) {
      float4 kv = kp[i];
      a0 = fmaf(q[4*i], kv.x, a0);
      a1 = fmaf(q[4*i+1], kv.y, a1);
      a2 = fmaf(q[4*i+2], kv.z, a2);
      a3 = fmaf(q[4*i+3], kv.w, a3);
    }
    float p = __expf(((a0 + a1) + (a2 + a3)) * SCALE_);
    ssum += p;
    const float4* vp = (const float4*)(Vb + (size_t)s * 64);
    #pragma unroll
    for (int i = 0; i < 8; ++i) {
      float4 vv = vp[i];
      o[4*i]   = fmaf(p, vv.x, o[4*i]);
      o[4*i+1] = fmaf(p, vv.y, o[4*i+1]);
      o[4*i+2] = fmaf(p, vv.z, o[4*i+2]);
      o[4*i+3] = fmaf(p, vv.w, o[4*i+3]);
    }
  }
  if (u < 35) {
    float* pp = ppart + (((size_t)bh * 16 + blockIdx.x) * 35 + u) * 36;
    #pragma unroll
    for (int i = 0; i < 8; ++i)
      ((float4*)pp)[i] = make_float4(o[4*i], o[4*i+1], o[4*i+2], o[4*i+3]);
    pp[32] = ssum;
  }
}

__global__ void prob_comb_kernel(const float* __restrict__ ppart, const int* __restrict__ sel,
                                 float* __restrict__ cbuf) {
  int t = blockIdx.x * 64 + threadIdx.x;
  if (t >= 32 * 35) return;
  int bh = t / 35, u = t % 35;
  int b = bh >> 1, h = bh & 1;
  int l = sel[bh * 35 + u];
  float S = 0.0f;
  float o[32];
  #pragma unroll
  for (int d = 0; d < 32; ++d) o[d] = 0.0f;
  for (int j = 0; j < 16; ++j) {
    const float* pp = ppart + (((size_t)bh * 16 + j) * 35 + u) * 36;
    S += pp[32];
    #pragma unroll
    for (int i = 0; i < 8; ++i) {
      float4 v4 = ((const float4*)pp)[i];
      o[4*i] += v4.x; o[4*i+1] += v4.y; o[4*i+2] += v4.z; o[4*i+3] += v4.w;
    }
  }
  float inv = 1.0f / S;
  float* cc = cbuf + ((size_t)b * 1024 + l) * 352 + 192 + h * 32;
  #pragma unroll
  for (int d = 0; d < 32; ++d) cc[d] = o[d] * inv;
}

// ---------------------------------------------------------------------------
// autocorrelation: mv[b,tau] = (1/64) sum_{c,t} K[b,c,t] * Q[b,c,(t+tau)%1024]
// lane = tau (stride-1 b32 LDS reads, conflict-free); k via wave-uniform
// global loads (scalarized). grid (64 c, 4 tau-quarters, 16 b).
// ---------------------------------------------------------------------------
__global__ void auto_mv_part(const float* __restrict__ Qa, const float* __restrict__ Ka,
                             float* __restrict__ part) {
  __shared__ float qs[1280];
  int c = blockIdx.x, tq = blockIdx.y, b = blockIdx.z;
  int tid = threadIdx.x;
  int tau0 = tq * 256;
  const float* Qb = Qa + (size_t)b * 65536 + (size_t)c * 1024;
  const float* Kb = Ka + (size_t)b * 65536 + (size_t)c * 1024;
  for (int i = tid; i < 1280; i += 256) qs[i] = Qb[(tau0 + i) & 1023];
  __syncthreads();
  float a0 = 0, a1 = 0, a2 = 0, a3 = 0;
  for (int t = 0; t < 1024; t += 8) {
    float4 k0 = *(const float4*)(Kb + t);      // wave-uniform -> s_load
    float4 k1 = *(const float4*)(Kb + t + 4);
    const float* qp = &qs[t + tid];            // per-lane b32, stride-1
    a0 = fmaf(k0.x, qp[0], a0);
    a1 = fmaf(k0.y, qp[1], a1);
    a2 = fmaf(k0.z, qp[2], a2);
    a3 = fmaf(k0.w, qp[3], a3);
    a0 = fmaf(k1.x, qp[4], a0);
    a1 = fmaf(k1.y, qp[5], a1);
    a2 = fmaf(k1.z, qp[6], a2);
    a3 = fmaf(k1.w, qp[7], a3);
  }
  part[(((size_t)b * 64 + c) << 10) + tau0 + tid] = (a0 + a1) + (a2 + a3);
}

__global__ void auto_mv_reduce(const float* __restrict__ part, float* __restrict__ mv) {
  int idx = blockIdx.x * 256 + threadIdx.x;
  int b = idx >> 10, tau = idx & 1023;
  float s = 0.0f;
  for (int c = 0; c < 64; ++c) s += part[(((size_t)b * 64 + c) << 10) + tau];
  mv[(size_t)b * 1024 + tau] = s * (1.0f / 64.0f);
}

// single-wave top-6 + per-batch softmax weights
__global__ void auto_top6_kernel(const float* __restrict__ mv, int* __restrict__ idx6,
                                 float* __restrict__ w6) {
  __shared__ int id6s[6];
  int lane = threadIdx.x;     // 64 threads
  float v[16];
  #pragma unroll
  for (int k = 0; k < 16; ++k) {
    int i = lane * 16 + k;
    float s = 0.0f;
    for (int b = 0; b < 16; ++b) s += mv[(size_t)b * 1024 + i];
    v[k] = s;
  }
  for (int it = 0; it < 6; ++it) {
    float bv = -1e30f; int bi = 0;
    #pragma unroll
    for (int k = 0; k < 16; ++k)
      if (v[k] > bv) { bv = v[k]; bi = k; }
    int gidx = lane * 16 + bi;
    #pragma unroll
    for (int off = 32; off > 0; off >>= 1) {
      float ov = __shfl_down(bv, off, 64);
      int og = __shfl_down(gidx, off, 64);
      if (ov > bv || (ov == bv && og < gidx)) { bv = ov; gidx = og; }
    }
    gidx = __shfl(gidx, 0, 64);
    if (lane == 0) { idx6[it] = gidx; id6s[it] = gidx; }
    if ((gidx >> 4) == lane) {
      int kk = gidx & 15;
      #pragma unroll
      for (int k = 0; k < 16; ++k)
        if (k == kk) v[k] = -1e30f;
    }
  }
  __syncthreads();
  if (lane < 16) {
    int b = lane;
    float vals[6]; float mx = -1e30f;
    #pragma unroll
    for (int j = 0; j < 6; ++j) { vals[j] = mv[(size_t)b * 1024 + id6s[j]]; mx = fmaxf(mx, vals[j]); }
    float s = 0.0f;
    #pragma unroll
    for (int j = 0; j < 6; ++j) { vals[j] = __expf(vals[j] - mx); s += vals[j]; }
    #pragma unroll
    for (int j = 0; j < 6; ++j) w6[b * 6 + j] = vals[j] / s;
  }
}

__global__ void auto_agg_kernel(const float* __restrict__ Va, const float* __restrict__ iq,
                                const float* __restrict__ wap, const float* __restrict__ bap,
                                const int* __restrict__ idx6, const float* __restrict__ w6,
                                float* __restrict__ ca) {
  __shared__ float aggs[16][64];
  __shared__ float w6s[6];
  __shared__ int id6[6];
  int b = blockIdx.y, t0 = blockIdx.x * 16;
  int tid = threadIdx.x;
  if (tid < 6) { w6s[tid] = w6[b * 6 + tid]; id6[tid] = idx6[tid]; }
  __syncthreads();
  const float* Vb = Va + (size_t)b * 65536;
  for (int i = tid; i < 1024; i += 256) {
    int tl = i >> 6, c = i & 63;
    int t = t0 + tl;
    float s = 0.0f;
    #pragma unroll
    for (int j = 0; j < 6; ++j)
      s += w6s[j] * Vb[(size_t)((t + id6[j]) & 1023) * 64 + c];
    aggs[tl][c] = s;
  }
  __syncthreads();
  int dm = tid & 127, tp = tid >> 7;
  float acc[8];
  #pragma unroll
  for (int r = 0; r < 8; ++r) {
    int t = t0 + tp * 8 + r;
    acc[r] = bap[dm] + iq[((size_t)b * 1024 + t) * 128 + dm];
  }
  for (int c = 0; c < 64; ++c) {
    float wv = wap[c * 128 + dm];
    #pragma unroll
    for (int r = 0; r < 8; ++r) acc[r] += aggs[tp * 8 + r][c] * wv;
  }
  #pragma unroll
  for (int r = 0; r < 8; ++r)
    ca[((size_t)b * 1024 + t0 + tp * 8 + r) * 128 + dm] = acc[r];
}

// moving-average detrend (k=25, edge-replicate, running window) + asize proj
__global__ void auto_ma_kernel(const float* __restrict__ ca, const float* __restrict__ was,
                               const float* __restrict__ bas, float* __restrict__ cbuf) {
  __shared__ float cas[40][128];
  __shared__ float diff[16][128];
  int b = blockIdx.y, t0 = blockIdx.x * 16;
  int tid = threadIdx.x;
  for (int i = tid; i < 40 * 128; i += 256) {
    int r = i >> 7, d = i & 127;
    int t = t0 - 12 + r;
    t = (t < 0) ? 0 : ((t > 1023) ? 1023 : t);
    cas[r][d] = ca[((size_t)b * 1024 + t) * 128 + d];
  }
  __syncthreads();
  int d = tid & 127, hf = tid >> 7;
  int tl0 = hf * 8;
  float s = 0.0f;
  #pragma unroll
  for (int w = 0; w < 25; ++w) s += cas[tl0 + w][d];
  #pragma unroll
  for (int k = 0; k < 8; ++k) {
    int tl = tl0 + k;
    diff[tl][d] = cas[tl + 12][d] - s * (1.0f / 25.0f);
    if (k < 7) s += cas[tl + 25][d] - cas[tl][d];
  }
  __syncthreads();
  int j = tid & 63, tq = tid >> 6;
  float acc[4];
  #pragma unroll
  for (int r = 0; r < 4; ++r) acc[r] = bas[j];
  for (int dd = 0; dd < 128; ++dd) {
    float wv = was[dd * 64 + j];
    #pragma unroll
    for (int r = 0; r < 4; ++r) acc[r] += diff[tq * 4 + r][dd] * wv;
  }
  #pragma unroll
  for (int r = 0; r < 4; ++r)
    cbuf[((size_t)b * 1024 + t0 + tq * 4 + r) * 352 + 288 + j] = acc[r];
}

// ---------------------------------------------------------------------------
// FFT branch: Y = X @ wfft, then cf_proj[f] = sum_t cos(2pi f t/1024) Y[t]
// symmetry: cf[1024-f] == cf[f]  ->  compute f=0..511 + f=512, mirror rest
// ---------------------------------------------------------------------------
__global__ void fftY_kernel(const float* __restrict__ x, const float* __restrict__ wfft,
                            float* __restrict__ Y) {
  __shared__ float xs[64][128];
  __shared__ float ws[32][129];
  int b = blockIdx.y, t0 = blockIdx.x * 64;
  int tid = threadIdx.x;
  for (int i = tid; i < 64 * 128; i += 256) {
    int r = i >> 7, d = i & 127;
    xs[r][d] = x[(size_t)b * 131072 + (size_t)(t0 + r) * 128 + d];
  }
  for (int i = tid; i < 4096; i += 256) {
    int d = i >> 5, j = i & 31;
    ws[j][d] = wfft[i];
  }
  __syncthreads();
  int j = tid & 31, tt0 = (tid >> 5) * 8;
  float acc[8];
  #pragma unroll
  for (int r = 0; r < 8; ++r) acc[r] = 0.0f;
  for (int d0 = 0; d0 < 128; d0 += 4) {
    float w0 = ws[j][d0], w1 = ws[j][d0 + 1], w2 = ws[j][d0 + 2], w3 = ws[j][d0 + 3];
    #pragma unroll
    for (int r = 0; r < 8; ++r) {
      float4 xv = *(const float4*)&xs[tt0 + r][d0];
      float a = acc[r];
      a = fmaf(w0, xv.x, a);
      a = fmaf(w1, xv.y, a);
      a = fmaf(w2, xv.z, a);
      a = fmaf(w3, xv.w, a);
      acc[r] = a;
    }
  }
  #pragma unroll
  for (int r = 0; r < 8; ++r)
    Y[((size_t)b * 1024 + t0 + tt0 + r) * 32 + j] = acc[r];
}

__global__ void fftT_kernel(const float* __restrict__ Y, const float* __restrict__ bfft,
                            float* __restrict__ cbuf) {
  __shared__ float ys[256 * 32];
  int b = blockIdx.y, fbase = blockIdx.x * 64;
  int tid = threadIdx.x;
  int fi = tid & 31, jg = tid >> 5, j0 = jg * 4;
  int f0 = fbase + fi * 2;
  const float TWO_PI_N = 6.283185307179586476925f / 1024.0f;
  float ca0, sa0, ca1, sa1;
  sincosf(TWO_PI_N * (float)f0, &sa0, &ca0);
  sincosf(TWO_PI_N * (float)(f0 + 1), &sa1, &ca1);
  float cr0 = 1.0f, ci0 = 0.0f, cr1 = 1.0f, ci1 = 0.0f;
  float4 acc0 = make_float4(0.f, 0.f, 0.f, 0.f);
  float4 acc1 = make_float4(0.f, 0.f, 0.f, 0.f);
  for (int chk = 0; chk < 4; ++chk) {
    __syncthreads();
    const float4* Yp = (const float4*)(Y + ((size_t)b * 1024 + chk * 256) * 32);
    for (int i = tid; i < 2048; i += 256) ((float4*)ys)[i] = Yp[i];
    __syncthreads();
    for (int tl = 0; tl < 256; ++tl) {
      float4 yv = *(const float4*)&ys[tl * 32 + j0];
      acc0.x = fmaf(cr0, yv.x, acc0.x);
      acc0.y = fmaf(cr0, yv.y, acc0.y);
      acc0.z = fmaf(cr0, yv.z, acc0.z);
      acc0.w = fmaf(cr0, yv.w, acc0.w);
      acc1.x = fmaf(cr1, yv.x, acc1.x);
      acc1.y = fmaf(cr1, yv.y, acc1.y);
      acc1.z = fmaf(cr1, yv.z, acc1.z);
      acc1.w = fmaf(cr1, yv.w, acc1.w);
      float nr0 = cr0 * ca0 - ci0 * sa0;
      float ni0 = cr0 * sa0 + ci0 * ca0;
      cr0 = nr0; ci0 = ni0;
      float nr1 = cr1 * ca1 - ci1 * sa1;
      float ni1 = cr1 * sa1 + ci1 * ca1;
      cr1 = nr1; ci1 = ni1;
    }
  }
  float b0 = bfft[j0], b1 = bfft[j0 + 1], b2 = bfft[j0 + 2], b3 = bfft[j0 + 3];
  float* cc0 = cbuf + ((size_t)b * 1024 + f0) * 352 + 256 + j0;
  cc0[0] = acc0.x + b0; cc0[1] = acc0.y + b1; cc0[2] = acc0.z + b2; cc0[3] = acc0.w + b3;
  float* cc1 = cbuf + ((size_t)b * 1024 + f0 + 1) * 352 + 256 + j0;
  cc1[0] = acc1.x + b0; cc1[1] = acc1.y + b1; cc1[2] = acc1.z + b2; cc1[3] = acc1.w + b3;
  if (f0 > 0) {
    float* cm0 = cbuf + ((size_t)b * 1024 + (1024 - f0)) * 352 + 256 + j0;
    cm0[0] = acc0.x + b0; cm0[1] = acc0.y + b1; cm0[2] = acc0.z + b2; cm0[3] = acc0.w + b3;
  }
  {
    float* cm1 = cbuf + ((size_t)b * 1024 + (1024 - f0 - 1)) * 352 + 256 + j0;
    cm1[0] = acc1.x + b0; cm1[1] = acc1.y + b1; cm1[2] = acc1.z + b2; cm1[3] = acc1.w + b3;
  }
}

// f=512: cos(pi t) = (-1)^t
__global__ void fft512_kernel(const float* __restrict__ Y, const float* __restrict__ bfft,
                              float* __restrict__ cbuf) {
  __shared__ float red[8][32];
  int b = blockIdx.x;
  int tid = threadIdx.x;
  int tc = tid >> 5, j = tid & 31;
  float s = 0.0f;
  for (int t = tc * 128; t < tc * 128 + 128; ++t) {
    float y = Y[((size_t)b * 1024 + t) * 32 + j];
    s += (t & 1) ? -y : y;
  }
  red[tc][j] = s;
  __syncthreads();
  if (tc == 0) {
    float t = 0.0f;
    for (int c = 0; c < 8; ++c) t += red[c][j];
    cbuf[((size_t)b * 1024 + 512) * 352 + 256 + j] = t + bfft[j];
  }
}

// ---------------------------------------------------------------------------
// final: out = cbuf @ w_fc + iq, then layernorm over DM
// ---------------------------------------------------------------------------
__global__ void fc_ln_kernel(const float* __restrict__ cbuf, const float* __restrict__ wfc,
                             const float* __restrict__ iq, float* __restrict__ out) {
  __shared__ float cs[16][352];
  __shared__ float os[16][128];
  int b = blockIdx.y, t0 = blockIdx.x * 16;
  int tid = threadIdx.x;
  for (int i = tid; i < 16 * 352; i += 256) {
    int r = i / 352, col = i % 352;
    cs[r][col] = cbuf[((size_t)b * 1024 + t0 + r) * 352 + col];
  }
  __syncthreads();
  int j = tid & 127, half = tid >> 7;
  float acc[8];
  #pragma unroll
  for (int k = 0; k < 8; ++k)
    acc[k] = iq[((size_t)b * 1024 + t0 + half * 8 + k) * 128 + j];
  for (int i = 0; i < 352; ++i) {
    float wv = wfc[i * 128 + j];
    #pragma unroll
    for (int k = 0; k < 8; ++k) acc[k] += cs[half * 8 + k][i] * wv;
  }
  #pragma unroll
  for (int k = 0; k < 8; ++k) os[half * 8 + k][j] = acc[k];
  __syncthreads();
  int wid = tid >> 6, lane = tid & 63;
  for (int rr = 0; rr < 4; ++rr) {
    int r = wid * 4 + rr;
    float x0 = os[r][lane], x1 = os[r][lane + 64];
    float s1 = x0 + x1;
    float s2 = x0 * x0 + x1 * x1;
    #pragma unroll
    for (int k = 32; k > 0; k >>= 1) {
      s1 += __shfl_xor(s1, k, 64);
      s2 += __shfl_xor(s2, k, 64);
    }
    float mean = s1 * (1.0f / 128.0f);
    float var = s2 * (1.0f / 128.0f) - mean * mean;
    float rstd = 1.0f / sqrtf(var + 1e-5f);
    float* op = out + ((size_t)b * 1024 + t0 + r) * 128;
    op[lane] = (x0 - mean) * rstd;
    op[lane + 64] = (x1 - mean) * rstd;
  }
}

// ---------------------------------------------------------------------------
extern "C" void kernel_launch(void* const* d_in, const int* in_sizes, int n_in,
                              void* d_out, int out_size, void* d_ws, size_t ws_size,
                              hipStream_t stream) {
  (void)in_sizes; (void)n_in; (void)out_size;
  const float* inQ = (const float*)d_in[0];
  const float* inK = (const float*)d_in[1];
  const float* inV = (const float*)d_in[2];
  const float *wq[5], *bq[5], *wk[5], *bk[5], *wv[5], *bv[5];
  for (int br = 0; br < 5; ++br) {
    wq[br] = (const float*)d_in[3 + br * 6 + 0];
    bq[br] = (const float*)d_in[3 + br * 6 + 1];
    wk[br] = (const float*)d_in[3 + br * 6 + 2];
    bk[br] = (const float*)d_in[3 + br * 6 + 3];
    wv[br] = (const float*)d_in[3 + br * 6 + 4];
    bv[br] = (const float*)d_in[3 + br * 6 + 5];
  }
  const float* wfft = (const float*)d_in[33];
  const float* bfft = (const float*)d_in[34];
  const float* wap  = (const float*)d_in[35];
  const float* bap  = (const float*)d_in[36];
  const float* was  = (const float*)d_in[37];
  const float* bas  = (const float*)d_in[38];
  const float* wfc  = (const float*)d_in[39];
  float* out = (float*)d_out;

  int nsplit = (ws_size >= (size_t)76 * 1024 * 1024) ? 8 : 4;
  int stile = 1024 / nsplit;
  int nstage = stile / 128;

  char* wsb = (char*)d_ws;
  size_t off = 0;
  auto alloc = [&](size_t bytes) -> void* {
    void* p = wsb + off;
    off += (bytes + 255) & ~(size_t)255;
    return p;
  };
  int*   pidx = (int*)  alloc((size_t)35840 * 4);
  float* qbuf = (float*)alloc((size_t)16 * 65536 * 4);
  float* kbuf = (float*)alloc((size_t)16 * 65536 * 4);
  float* vbuf = (float*)alloc((size_t)16 * 65536 * 4);
  float* cbuf = (float*)alloc((size_t)16 * 1024 * 352 * 4);
  float* fpart = (float*)alloc((size_t)32 * nsplit * 1024 * 36 * 4);
  float* Mbuf = (float*)alloc((size_t)32 * 1024 * 4);
  int*   sel  = (int*)  alloc((size_t)32 * 35 * 4);
  float* mvb  = (float*)alloc((size_t)16 * 1024 * 4);
  int*   idx6 = (int*)  alloc(64);
  float* w6   = (float*)alloc((size_t)16 * 6 * 4);
  float* ppart = fpart;
  float* cab   = fpart;
  float* mpart = (float*)((char*)fpart + (size_t)8 * 1024 * 1024);
  float* Ybuf  = (float*)((char*)fpart + (size_t)12 * 1024 * 1024);

  mt_kernel<<<1, 256, 0, stream>>>(pidx);

  dim3 qkvgrid(32, 16, 3);
  // branch 0: full attention
  qkv_conv_kernel<<<qkvgrid, 256, 0, stream>>>(inQ, inK, inV, wq[0], bq[0], wk[0], bk[0],
                                               wv[0], bv[0], qbuf, kbuf, vbuf);
  attn_full_part<<<dim3(4, nsplit, 32), 256, 0, stream>>>(qbuf, kbuf, vbuf, fpart, stile, nstage);
  attn_full_comb<<<256, 128, 0, stream>>>(fpart, cbuf, nsplit);

  // branch 1: log-sparse
  qkv_conv_kernel<<<qkvgrid, 256, 0, stream>>>(inQ, inK, inV, wq[1], bq[1], wk[1], bk[1],
                                               wv[1], bv[1], qbuf, kbuf, vbuf);
  attn_log_kernel<<<256, 128, 0, stream>>>(qbuf, kbuf, vbuf, cbuf);

  // branch 2: local window
  qkv_conv_kernel<<<qkvgrid, 256, 0, stream>>>(inQ, inK, inV, wq[2], bq[2], wk[2], bk[2],
                                               wv[2], bv[2], qbuf, kbuf, vbuf);
  attn_loc_kernel<<<256, 128, 0, stream>>>(qbuf, kbuf, vbuf, cbuf);

  // branch 3: prob-sparse
  qkv_conv_kernel<<<qkvgrid, 256, 0, stream>>>(inQ, inK, inV, wq[3], bq[3], wk[3], bk[3],
                                               wv[3], bv[3], qbuf, kbuf, vbuf);
  prob_m_kernel<<<256, 128, 0, stream>>>(qbuf, kbuf, pidx, Mbuf);
  top35_kernel<<<32, 64, 0, stream>>>(Mbuf, sel);
  prob_fill_kernel<<<32, 256, 0, stream>>>(vbuf, cbuf);
  prob_part_kernel<<<dim3(16, 32), 64, 0, stream>>>(qbuf, kbuf, vbuf, sel, ppart);
  prob_comb_kernel<<<18, 64, 0, stream>>>(ppart, sel, cbuf);

  // branch 4: autocorrelation
  qkv_conv_kernel<<<qkvgrid, 256, 0, stream>>>(inQ, inK, inV, wq[4], bq[4], wk[4], bk[4],
                                               wv[4], bv[4], qbuf, kbuf, vbuf);
  auto_mv_part<<<dim3(64, 4, 16), 256, 0, stream>>>(qbuf, kbuf, mpart);
  auto_mv_reduce<<<64, 256, 0, stream>>>(mpart, mvb);
  auto_top6_kernel<<<1, 64, 0, stream>>>(mvb, idx6, w6);
  auto_agg_kernel<<<dim3(64, 16), 256, 0, stream>>>(vbuf, inQ, wap, bap, idx6, w6, cab);
  auto_ma_kernel<<<dim3(64, 16), 256, 0, stream>>>(cab, was, bas, cbuf);

  // FFT branch (mirror symmetry: compute f=0..512 only)
  fftY_kernel<<<dim3(16, 16), 256, 0, stream>>>(inQ, wfft, Ybuf);
  fftT_kernel<<<dim3(8, 16), 256, 0, stream>>>(Ybuf, bfft, cbuf);
  fft512_kernel<<<16, 256, 0, stream>>>(Ybuf, bfft, cbuf);

  // final projection + layernorm
  fc_ln_kernel<<<dim3(64, 16), 256, 0, stream>>>(cbuf, wfc, inQ, out);
}